// Round 6
// baseline (520.626 us; speedup 1.0000x reference)
//
#include <hip/hip_runtime.h>
#include <cstdint>
#include <cstddef>
#include <math.h>

#define N_NODES 40000
#define N_RELS  474
#define E0      100000
#define EN      30000
#define NE      130000
#define NB      8192
#define LRALPHA 0.2f

#define KP1 128   // padded K for layer-1 GEMM (K=100)
#define KP2 256   // padded K for layer-2 GEMM (K=200)
// Pcat cols: [0:200) Pt interleaved (2f=h0,2f+1=h1) | [200:400) Ps interleaved |
//            [400:600) entW natural | [600:604) dots (u_t0,u_s0,u_t1,u_s1) | pad
#define LD1 608
// Qcat cols: [0:200) Qt | [200:400) Qs | 400 dqt | 401 dqs | pad
#define LD2 416

typedef __attribute__((ext_vector_type(8))) short short8;
typedef __attribute__((ext_vector_type(4))) float floatx4;

static __device__ __forceinline__ unsigned short f2bf(float f) {
    union { float f; uint32_t u; } v; v.f = f;
    uint32_t r = v.u + 0x7fff + ((v.u >> 16) & 1);
    return (unsigned short)(r >> 16);
}
static __device__ __forceinline__ float bf2f(unsigned short h) {
    union { uint32_t u; float f; } v; v.u = ((uint32_t)h) << 16;
    return v.f;
}
static __device__ __forceinline__ float bflo(uint32_t u) { return bf2f((unsigned short)(u & 0xffff)); }
static __device__ __forceinline__ float bfhi(uint32_t u) { return bf2f((unsigned short)(u >> 16)); }

// ---------------- l2norm rows of ent -> bf16 padded [40000][KP1] ----------------
__global__ void k_l2norm_bf16(const float* __restrict__ in, unsigned short* __restrict__ out) {
    int w = (blockIdx.x * blockDim.x + threadIdx.x) >> 6;
    int lane = threadIdx.x & 63;
    if (w >= N_NODES) return;
    const float* r = in + (size_t)w * 100;
    float v0 = r[lane];
    int j1 = lane + 64;
    float v1 = (j1 < 100) ? r[j1] : 0.f;
    float ss = v0 * v0 + v1 * v1;
#pragma unroll
    for (int o = 32; o > 0; o >>= 1) ss += __shfl_down(ss, o);
    ss = __shfl(ss, 0);
    float inv = 1.f / fmaxf(sqrtf(ss), 1e-12f);
    unsigned short* dst = out + (size_t)w * KP1;
    dst[lane] = f2bf(v0 * inv);
    dst[j1] = (j1 < 100) ? f2bf(v1 * inv) : (unsigned short)0;
}

// ---------------- bf16 MFMA GEMM, full-N strip per block, LDS-staged stores ----------------
// A: [M][KP] bf16, B: [N][KP] bf16 (N mult of 32), C: [M][ldc] bf16.
// grid: (M/64), block 256 (4 waves x 16 rows). One block covers all N.
template <int KP>
__global__ __launch_bounds__(256) void k_gemm_mfma(const unsigned short* __restrict__ A,
                                                   const unsigned short* __restrict__ B,
                                                   unsigned short* __restrict__ C,
                                                   int ldc, int N) {
    constexpr int KSTEPS = KP / 32;
    __shared__ unsigned short cbuf[4][16][128];   // 16 KB, wave-private slabs
    int wave = threadIdx.x >> 6;
    int lane = threadIdx.x & 63;
    int quad = lane >> 4;
    int l16 = lane & 15;
    int m0 = blockIdx.x * 64 + wave * 16;
    // load this wave's 16-row A strip (full K) into registers — exactly once
    short8 afrag[KSTEPS];
    const unsigned short* arow = A + (size_t)(m0 + l16) * KP + quad * 8;
#pragma unroll
    for (int ks = 0; ks < KSTEPS; ks++)
        afrag[ks] = *(const short8*)(arow + ks * 32);

    for (int nb = 0; nb < N; nb += 128) {
        int ntiles = (N - nb) >> 4;
        if (ntiles > 8) ntiles = 8;
        for (int t = 0; t < ntiles; t += 2) {   // pairs: 2 independent MFMA chains
            const unsigned short* brow0 = B + (size_t)(nb + t * 16 + l16) * KP + quad * 8;
            const unsigned short* brow1 = brow0 + (size_t)16 * KP;
            floatx4 acc0 = {0.f, 0.f, 0.f, 0.f};
            floatx4 acc1 = {0.f, 0.f, 0.f, 0.f};
#pragma unroll
            for (int ks = 0; ks < KSTEPS; ks++) {
                short8 b0 = *(const short8*)(brow0 + ks * 32);
                short8 b1 = *(const short8*)(brow1 + ks * 32);
                acc0 = __builtin_amdgcn_mfma_f32_16x16x32_bf16(afrag[ks], b0, acc0, 0, 0, 0);
                acc1 = __builtin_amdgcn_mfma_f32_16x16x32_bf16(afrag[ks], b1, acc1, 0, 0, 0);
            }
            // C/D layout: col = l16, row = quad*4 + reg  -> stage into LDS
            int r0 = quad * 4;
#pragma unroll
            for (int i = 0; i < 4; i++) {
                cbuf[wave][r0 + i][t * 16 + l16] = f2bf(acc0[i]);
                cbuf[wave][r0 + i][t * 16 + 16 + l16] = f2bf(acc1[i]);
            }
        }
        // coalesced flush: 16B per lane (same-wave LDS ops are in-order; no barrier)
        int cols8 = ntiles * 2;               // 8-col (16B) chunks per row
        int nchunks = 16 * cols8;
        for (int c = lane; c < nchunks; c += 64) {
            int row = c / cols8;
            int col8 = (c % cols8) * 8;
            *(uint4*)(C + (size_t)(m0 + row) * ldc + nb + col8) =
                *(const uint4*)&cbuf[wave][row][col8];
        }
    }
}

// ---------------- u-vectors: u = a_part^T @ a2 ----------------
// uvecs: [0:100)=u_t0 [100:200)=u_s0 [200:300)=u_t1 [300:400)=u_s1 [400:600)=u_t2 [600:800)=u_s2
__global__ void k_uvec(const float* __restrict__ att_a, const float* __restrict__ att_a2,
                       const float* __restrict__ out_a, const float* __restrict__ out_a2,
                       float* __restrict__ uvecs) {
    int tid = blockIdx.x * blockDim.x + threadIdx.x;
    if (tid >= 800) return;
    float s = 0.f;
    if (tid < 400) {
        int v = tid / 100, k = tid % 100;
        int head = v >> 1, part = v & 1;
        const float* base = att_a + head * 30000 + part * 100 + k;
        const float* a2 = att_a2 + head * 100;
        for (int n = 0; n < 100; n++) s += a2[n] * base[n * 300];
        uvecs[tid] = s;
    } else {
        int v = (tid - 400) / 200, k = (tid - 400) % 200;
        const float* base = out_a + v * 200 + k;
        for (int n = 0; n < 200; n++) s += out_a2[n] * base[n * 600];
        uvecs[400 + v * 200 + k] = s;
    }
}

// ---------------- pack layer-1 B matrix (interleaved Pt/Ps): Wcat1 [608][KP1] ----------------
__global__ void k_pack1(const float* __restrict__ att_a, const float* __restrict__ W_ent,
                        const float* __restrict__ uvecs, unsigned short* __restrict__ W) {
    int idx = blockIdx.x * blockDim.x + threadIdx.x;
    if (idx >= 608 * KP1) return;
    int r = idx >> 7, k = idx & (KP1 - 1);
    float val = 0.f;
    if (k < 100) {
        if (r < 200) {                       // Pt interleaved: col 2i+h = a_t head h row i
            int i = r >> 1, h = r & 1;
            val = att_a[h * 30000 + i * 300 + k];
        } else if (r < 400) {                // Ps interleaved
            int rr = r - 200, i = rr >> 1, h = rr & 1;
            val = att_a[h * 30000 + i * 300 + 100 + k];
        } else if (r < 600) {
            val = W_ent[k * 200 + (r - 400)];
        } else if (r < 604) {
            val = uvecs[(r - 600) * 100 + k];
        }
    }
    W[idx] = f2bf(val);
}

// ---------------- pack layer-2 B matrix (x is K-interleaved): Wcat2 [416][KP2] ----------------
__global__ void k_pack2(const float* __restrict__ out_a, const float* __restrict__ uvecs,
                        unsigned short* __restrict__ W) {
    int idx = blockIdx.x * blockDim.x + threadIdx.x;
    if (idx >= 416 * KP2) return;
    int r = idx >> 8, k = idx & (KP2 - 1);
    float val = 0.f;
    if (k < 200) {
        int klog = (k & 1) * 100 + (k >> 1);   // phys 2f=h0 feat f, 2f+1=h1 feat f
        if (r < 200)       val = out_a[r * 600 + klog];
        else if (r < 400)  val = out_a[(r - 200) * 600 + 200 + klog];
        else if (r == 400) val = uvecs[400 + klog];
        else if (r == 401) val = uvecs[600 + klog];
    }
    W[idx] = f2bf(val);
}

// ---------------- R1 interleaved projection: R1i[474][200], (R10[f],R11[f]) pairs ------------
__global__ void k_relproj1(const float* __restrict__ rel_emb, const float* __restrict__ att_a,
                           float* __restrict__ R1i) {
    int w = (blockIdx.x * blockDim.x + threadIdx.x) >> 6;
    int lane = threadIdx.x & 63;
    if (w >= N_RELS) return;
    const float* re = rel_emb + (size_t)w * 100;
    float2* dst = (float2*)(R1i + (size_t)w * 200);
    for (int f = lane; f < 100; f += 64) {
        const float* a0 = att_a + f * 300 + 200;
        const float* a1 = att_a + 30000 + f * 300 + 200;
        float s0 = 0.f, s1 = 0.f;
        for (int k = 0; k < 100; k++) {
            float rk = re[k];
            s0 += rk * a0[k];
            s1 += rk * a1[k];
        }
        dst[f] = make_float2(s0, s1);
    }
}

// dR1h[r] = R1h[r] . a2_h
__global__ void k_dR1(const float* __restrict__ R1i, const float* __restrict__ att_a2,
                      float* __restrict__ dR10, float* __restrict__ dR11) {
    int w = (blockIdx.x * blockDim.x + threadIdx.x) >> 6;
    int lane = threadIdx.x & 63;
    if (w >= N_RELS) return;
    const float2* row = (const float2*)(R1i + (size_t)w * 200);
    float s0 = 0.f, s1 = 0.f;
    for (int f = lane; f < 100; f += 64) {
        float2 v = row[f];
        s0 += v.x * att_a2[f];
        s1 += v.y * att_a2[100 + f];
    }
#pragma unroll
    for (int o = 32; o > 0; o >>= 1) {
        s0 += __shfl_down(s0, o);
        s1 += __shfl_down(s1, o);
    }
    if (lane == 0) { dR10[w] = s0; dR11[w] = s1; }
}

// ---------------- generic tiled fp32 matmul (474-row cases only) ----------------
template <bool BT>
__global__ __launch_bounds__(256) void k_mm(const float* __restrict__ A, int lda,
                                            const float* __restrict__ B, int ldb,
                                            float* __restrict__ C, int ldc,
                                            int M, int N, int K) {
    __shared__ float As[16][65];
    __shared__ float Bs[16][65];
    int tid = threadIdx.x;
    int tx = tid & 15, ty = tid >> 4;
    int m0 = blockIdx.y * 64, n0 = blockIdx.x * 64;
    float acc[4][4] = {};
    for (int k0 = 0; k0 < K; k0 += 16) {
        {
            int r = tid >> 2;
            int c4 = (tid & 3) * 4;
            int m = m0 + r;
#pragma unroll
            for (int u = 0; u < 4; u++) {
                int k = k0 + c4 + u;
                As[c4 + u][r] = (m < M && k < K) ? A[(size_t)m * lda + k] : 0.f;
            }
        }
        if (BT) {
            int r = tid >> 2;
            int c4 = (tid & 3) * 4;
            int n = n0 + r;
#pragma unroll
            for (int u = 0; u < 4; u++) {
                int k = k0 + c4 + u;
                Bs[c4 + u][r] = (n < N && k < K) ? B[(size_t)n * ldb + k] : 0.f;
            }
        } else {
            int kk = tid >> 4;
            int nn4 = (tid & 15) * 4;
            int k = k0 + kk;
#pragma unroll
            for (int u = 0; u < 4; u++) {
                int n = n0 + nn4 + u;
                Bs[kk][nn4 + u] = (k < K && n < N) ? B[(size_t)k * ldb + n] : 0.f;
            }
        }
        __syncthreads();
#pragma unroll
        for (int k = 0; k < 16; k++) {
            float a[4], b[4];
#pragma unroll
            for (int i = 0; i < 4; i++) a[i] = As[k][ty + 16 * i];
#pragma unroll
            for (int j = 0; j < 4; j++) b[j] = Bs[k][tx + 16 * j];
#pragma unroll
            for (int i = 0; i < 4; i++)
#pragma unroll
                for (int j = 0; j < 4; j++) acc[i][j] += a[i] * b[j];
        }
        __syncthreads();
    }
#pragma unroll
    for (int i = 0; i < 4; i++) {
        int m = m0 + ty + 16 * i;
        if (m >= M) continue;
#pragma unroll
        for (int j = 0; j < 4; j++) {
            int n = n0 + tx + 16 * j;
            if (n < N) C[(size_t)m * ldc + n] = acc[i][j];
        }
    }
}

// ---------------- per-row dot with vector (474-row cases) ----------------
__global__ void k_dotv(const float* __restrict__ mat, const float* __restrict__ vec,
                       float* __restrict__ out, int M, int F) {
    int w = (blockIdx.x * blockDim.x + threadIdx.x) >> 6;
    int lane = threadIdx.x & 63;
    if (w >= M) return;
    const float* r = mat + (size_t)w * F;
    float s = 0.f;
    for (int j = lane; j < F; j += 64) s += r[j] * vec[j];
#pragma unroll
    for (int o = 32; o > 0; o >>= 1) s += __shfl_down(s, o);
    if (lane == 0) out[w] = s;
}

// ---------------- CSR build ----------------
__global__ void k_hist(const int* __restrict__ tgt_el, const int* __restrict__ nhop,
                       int* __restrict__ deg) {
    int e = blockIdx.x * blockDim.x + threadIdx.x;
    if (e >= NE) return;
    int t = (e < E0) ? tgt_el[e] : nhop[(size_t)(e - E0) * 4 + 3];
    atomicAdd(&deg[t], 1);
}

__global__ void k_scan1(const int* __restrict__ deg, int* __restrict__ local,
                        int* __restrict__ bsums, int n) {
    int i = blockIdx.x * 256 + threadIdx.x;
    int v = (i < n) ? deg[i] : 0;
    int lane = threadIdx.x & 63;
    int wv = threadIdx.x >> 6;
    int x = v;
#pragma unroll
    for (int o = 1; o < 64; o <<= 1) {
        int t = __shfl_up(x, o);
        if (lane >= o) x += t;
    }
    __shared__ int wtot[4];
    if (lane == 63) wtot[wv] = x;
    __syncthreads();
    int add = 0;
    for (int k = 0; k < wv; k++) add += wtot[k];
    if (i < n) local[i] = add + x - v;
    if (threadIdx.x == 255) bsums[blockIdx.x] = add + x;
}

__global__ void k_scan2(int* __restrict__ bsums, int nb) {
    int tid = threadIdx.x;
    int v = (tid < nb) ? bsums[tid] : 0;
    int lane = tid & 63, wv = tid >> 6;
    int x = v;
#pragma unroll
    for (int o = 1; o < 64; o <<= 1) {
        int t = __shfl_up(x, o);
        if (lane >= o) x += t;
    }
    __shared__ int wtot[4];
    if (lane == 63) wtot[wv] = x;
    __syncthreads();
    int add = 0;
    for (int k = 0; k < wv; k++) add += wtot[k];
    __syncthreads();
    if (tid < nb) bsums[tid] = add + x - v;
    if (tid == 255) bsums[nb] = add + x;
}

__global__ void k_scan3(const int* __restrict__ local, const int* __restrict__ bsums,
                        int* __restrict__ rowptr, int* __restrict__ cursor, int n, int nb) {
    int i = blockIdx.x * 256 + threadIdx.x;
    if (i < n) {
        int v = local[i] + bsums[blockIdx.x];
        rowptr[i] = v;
        cursor[i] = v;
    } else if (i == n) {
        rowptr[n] = bsums[nb];
    }
}

// scatter edge payloads into CSR order
__global__ void k_scatter(const int* __restrict__ tgt_el, const int* __restrict__ src_el,
                          const int* __restrict__ etype, const int* __restrict__ nhop,
                          int* __restrict__ cursor,
                          int* __restrict__ tgts, int* __restrict__ srcs,
                          int2* __restrict__ relpk) {
    int e = blockIdx.x * blockDim.x + threadIdx.x;
    if (e >= NE) return;
    int t, s, r1, r2;
    if (e < E0) {
        t = tgt_el[e]; s = src_el[e]; r1 = etype[e]; r2 = -1;
    } else {
        const int* nh = nhop + (size_t)(e - E0) * 4;
        t = nh[3]; s = nh[0]; r1 = nh[1]; r2 = nh[2];
    }
    int p = atomicAdd(&cursor[t], 1);
    tgts[p] = t; srcs[p] = s;
    relpk[p] = make_int2(r1, r2);
}

// ---------------- per-edge attention scalars (CSR-position order) ----------------
__global__ void k_edge1(const int* __restrict__ tgts, const int* __restrict__ srcs,
                        const int2* __restrict__ relpk,
                        const unsigned short* __restrict__ Pcat,
                        const float* __restrict__ dR10, const float* __restrict__ dR11,
                        float2* __restrict__ wpair) {
    int p = blockIdx.x * blockDim.x + threadIdx.x;
    if (p >= NE) return;
    int t = tgts[p], s = srcs[p];
    int2 rp = relpk[p];
    float dr0 = dR10[rp.x], dr1 = dR11[rp.x];
    if (rp.y >= 0) { dr0 += dR10[rp.y]; dr1 += dR11[rp.y]; }
    uint2 td = *(const uint2*)(Pcat + (size_t)t * LD1 + 600);   // (u_t0,u_s0),(u_t1,u_s1)
    uint2 sd = *(const uint2*)(Pcat + (size_t)s * LD1 + 600);
    float p0 = bflo(td.x) + bfhi(sd.x) + dr0;
    float p1 = bflo(td.y) + bfhi(sd.y) + dr1;
    p0 = (p0 >= 0.f) ? p0 : LRALPHA * p0;
    p1 = (p1 >= 0.f) ? p1 : LRALPHA * p1;
    wpair[p] = make_float2(expf(-p0), expf(-p1));
}

__global__ void k_edge2(const int* __restrict__ tgts, const int* __restrict__ srcs,
                        const int2* __restrict__ relpk,
                        const unsigned short* __restrict__ Qcat,
                        const float* __restrict__ dR2, float* __restrict__ w2) {
    int p = blockIdx.x * blockDim.x + threadIdx.x;
    if (p >= NE) return;
    int t = tgts[p], s = srcs[p];
    int2 rp = relpk[p];
    float dr = dR2[rp.x];
    if (rp.y >= 0) dr += dR2[rp.y];
    uint32_t tq = *(const uint32_t*)(Qcat + (size_t)t * LD2 + 400);  // (dqt, dqs)
    uint32_t sq = *(const uint32_t*)(Qcat + (size_t)s * LD2 + 400);
    float pp = bflo(tq) + bfhi(sq) + dr;
    pp = (pp >= 0.f) ? pp : LRALPHA * pp;
    w2[p] = expf(-pp);
}

// ---------------- node aggregation layer 1 (wave/node) -> x bf16 K-interleaved --------------
__global__ void k_node1(const int* __restrict__ rowptr, const int* __restrict__ srcs,
                        const int2* __restrict__ relpk, const float2* __restrict__ wpair,
                        const unsigned short* __restrict__ Pcat,
                        const float* __restrict__ R1i,
                        unsigned short* __restrict__ x) {
    int node = (blockIdx.x * blockDim.x + threadIdx.x) >> 6;
    int lane = threadIdx.x & 63;
    if (node >= N_NODES) return;
    int f0 = lane, f1 = lane + 64;
    bool v1 = (f1 < 100);
    float b00 = 0, b01 = 0, b10 = 0, b11 = 0, rs0 = 0, rs1 = 0;
    int beg = rowptr[node], end = rowptr[node + 1];
    for (int p = beg; p < end; p++) {
        int s = srcs[p];
        int2 rp = relpk[p];
        float2 w = wpair[p];
        const float2* r1a = (const float2*)(R1i + (size_t)rp.x * 200);
        float2 ra0 = r1a[f0];
        float2 ra1 = v1 ? r1a[f1] : make_float2(0.f, 0.f);
        if (rp.y >= 0) {
            const float2* r1b = (const float2*)(R1i + (size_t)rp.y * 200);
            float2 t0 = r1b[f0];
            ra0.x += t0.x; ra0.y += t0.y;
            if (v1) { float2 t1 = r1b[f1]; ra1.x += t1.x; ra1.y += t1.y; }
        }
        const unsigned short* prow = Pcat + (size_t)s * LD1 + 200;
        uint32_t ps0 = *(const uint32_t*)(prow + 2 * f0);
        rs0 += w.x; rs1 += w.y;
        b00 += w.x * (bflo(ps0) + ra0.x);
        b01 += w.y * (bfhi(ps0) + ra0.y);
        if (v1) {
            uint32_t ps1 = *(const uint32_t*)(prow + 2 * f1);
            b10 += w.x * (bflo(ps1) + ra1.x);
            b11 += w.y * (bfhi(ps1) + ra1.y);
        }
    }
    float d0 = (rs0 == 0.f) ? 1e-12f : rs0;
    float d1 = (rs1 == 0.f) ? 1e-12f : rs1;
    const unsigned short* pn = Pcat + (size_t)node * LD1;
    unsigned short* xr = x + (size_t)node * KP2;
    {
        uint32_t pt = *(const uint32_t*)(pn + 2 * f0);
        float v = (b00 + rs0 * bflo(pt)) / d0;
        float u = (b01 + rs1 * bfhi(pt)) / d1;
        v = (v > 0.f) ? v : expm1f(v);
        u = (u > 0.f) ? u : expm1f(u);
        *(uint32_t*)(xr + 2 * f0) = (uint32_t)f2bf(v) | ((uint32_t)f2bf(u) << 16);
    }
    if (v1) {
        uint32_t pt = *(const uint32_t*)(pn + 2 * f1);
        float v = (b10 + rs0 * bflo(pt)) / d0;
        float u = (b11 + rs1 * bfhi(pt)) / d1;
        v = (v > 0.f) ? v : expm1f(v);
        u = (u > 0.f) ? u : expm1f(u);
        *(uint32_t*)(xr + 2 * f1) = (uint32_t)f2bf(v) | ((uint32_t)f2bf(u) << 16);
    }
    if (lane < (KP2 - 200) / 2) *(uint32_t*)(xr + 200 + 2 * lane) = 0;
}

// ---------------- node aggregation layer 2 + final fuse (wave/node) ----------------
__global__ void k_node2(const int* __restrict__ rowptr, const int* __restrict__ srcs,
                        const int2* __restrict__ relpk, const float* __restrict__ w2,
                        const unsigned short* __restrict__ Qcat,
                        const unsigned short* __restrict__ Pcat,
                        const float* __restrict__ R2, const float* __restrict__ mask,
                        float* __restrict__ out) {
    int node = (blockIdx.x * blockDim.x + threadIdx.x) >> 6;
    int lane = threadIdx.x & 63;
    if (node >= N_NODES) return;
    int q0 = lane, q1 = lane + 64;      // feature pairs (2q, 2q+1); 100 pairs
    bool v = (q1 < 100);
    float c00 = 0, c01 = 0, c10 = 0, c11 = 0, rs = 0;
    int beg = rowptr[node], end = rowptr[node + 1];
    for (int p = beg; p < end; p++) {
        int s = srcs[p];
        int2 rp = relpk[p];
        float W = w2[p];
        const float* r2r = R2 + (size_t)rp.x * 200;
        float2 ra = *(const float2*)(r2r + 2 * q0);
        float2 rb = v ? *(const float2*)(r2r + 2 * q1) : make_float2(0.f, 0.f);
        if (rp.y >= 0) {
            const float* r2b = R2 + (size_t)rp.y * 200;
            float2 t0 = *(const float2*)(r2b + 2 * q0);
            ra.x += t0.x; ra.y += t0.y;
            if (v) { float2 t1 = *(const float2*)(r2b + 2 * q1); rb.x += t1.x; rb.y += t1.y; }
        }
        const unsigned short* qsrow = Qcat + (size_t)s * LD2 + 200;
        uint32_t qa = *(const uint32_t*)(qsrow + 2 * q0);
        rs += W;
        c00 += W * (bflo(qa) + ra.x);
        c01 += W * (bfhi(qa) + ra.y);
        if (v) {
            uint32_t qb = *(const uint32_t*)(qsrow + 2 * q1);
            c10 += W * (bflo(qb) + rb.x);
            c11 += W * (bfhi(qb) + rb.y);
        }
    }
    float d = (rs == 0.f) ? 1e-12f : rs;
    const unsigned short* qt = Qcat + (size_t)node * LD2;
    const unsigned short* ew = Pcat + (size_t)node * LD1 + 400;
    float mk = mask[node];
    uint32_t t0 = *(const uint32_t*)(qt + 2 * q0);
    uint32_t e0 = *(const uint32_t*)(ew + 2 * q0);
    float val00 = bflo(e0) + mk * ((c00 + rs * bflo(t0)) / d);
    float val01 = bfhi(e0) + mk * ((c01 + rs * bfhi(t0)) / d);
    float val10 = 0.f, val11 = 0.f;
    if (v) {
        uint32_t t1 = *(const uint32_t*)(qt + 2 * q1);
        uint32_t e1 = *(const uint32_t*)(ew + 2 * q1);
        val10 = bflo(e1) + mk * ((c10 + rs * bflo(t1)) / d);
        val11 = bfhi(e1) + mk * ((c11 + rs * bfhi(t1)) / d);
    }
    float ss = val00 * val00 + val01 * val01 + val10 * val10 + val11 * val11;
#pragma unroll
    for (int o = 32; o > 0; o >>= 1) ss += __shfl_down(ss, o);
    ss = __shfl(ss, 0);
    float inv = 1.f / fmaxf(sqrtf(ss), 1e-12f);
    float* dst = out + (size_t)node * 200;
    *(float2*)(dst + 2 * q0) = make_float2(val00 * inv, val01 * inv);
    if (v) *(float2*)(dst + 2 * q1) = make_float2(val10 * inv, val11 * inv);
}

// ---------------- mask scatter ----------------
__global__ void k_mask(const int* __restrict__ batch, float* __restrict__ mask) {
    int i = blockIdx.x * blockDim.x + threadIdx.x;
    if (i < NB) mask[batch[(size_t)i * 3 + 2]] = 1.0f;
}

// ---------------- ortho losses: parallel partial reduction ----------------
__global__ void k_ortho_part(const float* __restrict__ att_a, const float* __restrict__ out_a,
                             float* __restrict__ accum) {
    float loc[9] = {0,0,0,0,0,0,0,0,0};
    int stride = gridDim.x * blockDim.x;
    for (int i = blockIdx.x * blockDim.x + threadIdx.x; i < 90000; i += stride) {
        int seg, li;
        const float* base;
        int L;
        if (i < 15000)      { seg = 0; li = i;          base = att_a;         L = 15000; }
        else if (i < 30000) { seg = 1; li = i - 15000;  base = att_a + 30000; L = 15000; }
        else                { seg = 2; li = i - 30000;  base = out_a;         L = 60000; }
        float a = base[li], b = base[L + li];
        loc[seg * 3 + 0] += a * a;
        loc[seg * 3 + 1] += b * b;
        loc[seg * 3 + 2] += a * b;
    }
    int lane = threadIdx.x & 63;
#pragma unroll
    for (int q = 0; q < 9; q++) {
        float s = loc[q];
#pragma unroll
        for (int o = 32; o > 0; o >>= 1) s += __shfl_down(s, o);
        if (lane == 0 && s != 0.f) atomicAdd(&accum[q], s);
    }
}

__global__ void k_ortho_fin(const float* __restrict__ accum, float* __restrict__ out_scalar) {
    if (threadIdx.x != 0 || blockIdx.x != 0) return;
    float total = 0.f;
#pragma unroll
    for (int m = 0; m < 3; m++) {
        float s0 = accum[m * 3 + 0], s1 = accum[m * 3 + 1], sc = accum[m * 3 + 2];
        float c = sc / (fmaxf(sqrtf(s0), 1e-12f) * fmaxf(sqrtf(s1), 1e-12f));
        total += 0.01f * 2.f * c * c;
    }
    out_scalar[0] = total;
}

// ---------------- launch ----------------
extern "C" void kernel_launch(void* const* d_in, const int* in_sizes, int n_in,
                              void* d_out, int out_size, void* d_ws, size_t ws_size,
                              hipStream_t stream) {
    const int* edge_list = (const int*)d_in[0];
    const int* edge_type = (const int*)d_in[1];
    const int* batch     = (const int*)d_in[2];
    const int* nhop      = (const int*)d_in[3];
    const float* ent_emb = (const float*)d_in[4];
    const float* rel_emb = (const float*)d_in[5];
    const float* W_ent   = (const float*)d_in[6];
    const float* W_rel   = (const float*)d_in[7];
    const float* att_a   = (const float*)d_in[8];
    const float* att_a2  = (const float*)d_in[9];
    const float* out_a   = (const float*)d_in[10];
    const float* out_a2  = (const float*)d_in[11];
    float* out = (float*)d_out;
    const int* tgt_el = edge_list;
    const int* src_el = edge_list + E0;

    char* ws = (char*)d_ws;
    size_t o = 0;
    auto alloc = [&](size_t nbytes) -> char* {
        char* p = ws + o;
        o += (nbytes + 255) & ~(size_t)255;
        return p;
    };
    unsigned short* ent_bf  = (unsigned short*)alloc((size_t)N_NODES * KP1 * 2);
    unsigned short* x_bf    = (unsigned short*)alloc((size_t)N_NODES * KP2 * 2);
    unsigned short* Pcat    = (unsigned short*)alloc((size_t)N_NODES * LD1 * 2);
    unsigned short* Qcat    = (unsigned short*)alloc((size_t)N_NODES * LD2 * 2);
    unsigned short* Wcat1   = (unsigned short*)alloc((size_t)608 * KP1 * 2);
    unsigned short* Wcat2   = (unsigned short*)alloc((size_t)416 * KP2 * 2);
    float* uvecs = (float*)alloc(800 * 4);
    float* R1i   = (float*)alloc(474u * 200 * 4);
    float* R2    = (float*)alloc(474u * 200 * 4);
    float* dR10  = (float*)alloc(474u * 4);
    float* dR11  = (float*)alloc(474u * 4);
    float* dR2   = (float*)alloc(474u * 4);
    float2* wpair = (float2*)alloc((size_t)NE * 8);
    float* w2    = (float*)alloc((size_t)NE * 4);
    int* rowptr  = (int*)alloc((N_NODES + 1) * 4);
    int* cursor  = (int*)alloc(N_NODES * 4);
    int* tgts    = (int*)alloc((size_t)NE * 4);
    int* srcs    = (int*)alloc((size_t)NE * 4);
    int2* relpk  = (int2*)alloc((size_t)NE * 8);
    float* mask  = (float*)alloc(N_NODES * 4);
    int* scanloc = (int*)alloc(N_NODES * 4);
    int* bsums   = (int*)alloc(260 * 4);
    float* oacc  = (float*)alloc(9 * 4);

    const int TPB = 256;
    int wave_blocks_40000 = (N_NODES * 64 + TPB - 1) / TPB;   // 10000
    int wave_blocks_474   = (N_RELS * 64 + TPB - 1) / TPB;    // 119
    int edge_blocks       = (NE + TPB - 1) / TPB;
    int scan_blocks       = (N_NODES + 255) / 256;            // 157

    hipMemsetAsync(cursor, 0, N_NODES * 4, stream);
    hipMemsetAsync(mask, 0, N_NODES * 4, stream);
    hipMemsetAsync(oacc, 0, 9 * 4, stream);

    // 1) normalize entities -> bf16 padded
    k_l2norm_bf16<<<wave_blocks_40000, TPB, 0, stream>>>(ent_emb, ent_bf);

    // 2) CSR by target, payloads in CSR order
    k_hist<<<edge_blocks, TPB, 0, stream>>>(tgt_el, nhop, cursor);
    k_scan1<<<scan_blocks, 256, 0, stream>>>(cursor, scanloc, bsums, N_NODES);
    k_scan2<<<1, 256, 0, stream>>>(bsums, scan_blocks);
    k_scan3<<<(N_NODES + 1 + 255) / 256, 256, 0, stream>>>(scanloc, bsums, rowptr, cursor, N_NODES, scan_blocks);
    k_scatter<<<edge_blocks, TPB, 0, stream>>>(tgt_el, src_el, edge_type, nhop, cursor,
                                               tgts, srcs, relpk);

    // 3) pack fused B matrices
    k_uvec<<<4, 256, 0, stream>>>(att_a, att_a2, out_a, out_a2, uvecs);
    k_pack1<<<(608 * KP1 + 255) / 256, 256, 0, stream>>>(att_a, W_ent, uvecs, Wcat1);
    k_pack2<<<(416 * KP2 + 255) / 256, 256, 0, stream>>>(out_a, uvecs, Wcat2);

    // 4) fused layer-1 GEMM (MFMA bf16, full-N strip, coalesced stores)
    k_gemm_mfma<KP1><<<625, 256, 0, stream>>>(ent_bf, Wcat1, Pcat, LD1, 608);

    // 5) relation-side projections (interleaved) + dots
    k_relproj1<<<wave_blocks_474, TPB, 0, stream>>>(rel_emb, att_a, R1i);
    k_dR1<<<wave_blocks_474, TPB, 0, stream>>>(R1i, att_a2, dR10, dR11);

    // 6) layer-1 edge weights + aggregation -> x_bf (K-interleaved)
    k_edge1<<<edge_blocks, TPB, 0, stream>>>(tgts, srcs, relpk, Pcat, dR10, dR11, wpair);
    k_node1<<<wave_blocks_40000, TPB, 0, stream>>>(rowptr, srcs, relpk, wpair, Pcat, R1i, x_bf);

    // 7) fused layer-2 GEMM (MFMA bf16)
    k_gemm_mfma<KP2><<<625, 256, 0, stream>>>(x_bf, Wcat2, Qcat, LD2, 416);

    // 8) out_relation_1 = rel_emb @ W_rel -> d_out; R2 = out_rel1 @ a_r2^T; dR2
    dim3 gor((200 + 63) / 64, (N_RELS + 63) / 64);
    k_mm<false><<<gor, TPB, 0, stream>>>(rel_emb, 100, W_rel, 200, out + 8000000, 200, N_RELS, 200, 100);
    k_mm<true><<<gor, TPB, 0, stream>>>(out + 8000000, 200, out_a + 400, 600, R2, 200, N_RELS, 200, 200);
    k_dotv<<<wave_blocks_474, TPB, 0, stream>>>(R2, out_a2, dR2, N_RELS, 200);

    // 9) layer-2 edge weights, mask, aggregation + final fuse
    k_edge2<<<edge_blocks, TPB, 0, stream>>>(tgts, srcs, relpk, Qcat, dR2, w2);
    k_mask<<<(NB + TPB - 1) / TPB, TPB, 0, stream>>>(batch, mask);
    k_node2<<<wave_blocks_40000, TPB, 0, stream>>>(rowptr, srcs, relpk, w2, Qcat, Pcat, R2, mask, out);

    // 10) ortho scalar (parallel)
    k_ortho_part<<<128, 256, 0, stream>>>(att_a, out_a, oacc);
    k_ortho_fin<<<1, 64, 0, stream>>>(oacc, out + 8094800);
}

// Round 7
// 517.688 us; speedup vs baseline: 1.0057x; 1.0057x over previous
//
#include <hip/hip_runtime.h>
#include <cstdint>
#include <cstddef>
#include <math.h>

#define N_NODES 40000
#define N_RELS  474
#define E0      100000
#define EN      30000
#define NE      130000
#define NB      8192
#define LRALPHA 0.2f

#define KP1 128   // padded K for layer-1 GEMM (K=100)
#define KP2 256   // padded K for layer-2 GEMM (K=200)
// Pcat cols: [0:200) Pt interleaved (2f=h0,2f+1=h1) | [200:400) Ps interleaved |
//            [400:600) entW natural | [600:604) dots (u_t0,u_s0,u_t1,u_s1) | pad
#define LD1 608
// Qcat cols: [0:200) Qt | [200:400) Qs | 400 dqt | 401 dqs | pad
#define LD2 416
#define NPAD1 640   // Wcat1 rows (zero-padded past 604)
#define NPAD2 448   // Wcat2 rows (zero-padded past 402)

typedef __attribute__((ext_vector_type(8))) short short8;
typedef __attribute__((ext_vector_type(4))) float floatx4;

static __device__ __forceinline__ unsigned short f2bf(float f) {
    union { float f; uint32_t u; } v; v.f = f;
    uint32_t r = v.u + 0x7fff + ((v.u >> 16) & 1);
    return (unsigned short)(r >> 16);
}
static __device__ __forceinline__ float bf2f(unsigned short h) {
    union { uint32_t u; float f; } v; v.u = ((uint32_t)h) << 16;
    return v.f;
}
static __device__ __forceinline__ float bflo(uint32_t u) { return bf2f((unsigned short)(u & 0xffff)); }
static __device__ __forceinline__ float bfhi(uint32_t u) { return bf2f((unsigned short)(u >> 16)); }

// ---------------- l2norm rows of ent -> bf16 padded [40000][KP1] ----------------
__global__ void k_l2norm_bf16(const float* __restrict__ in, unsigned short* __restrict__ out) {
    int w = (blockIdx.x * blockDim.x + threadIdx.x) >> 6;
    int lane = threadIdx.x & 63;
    if (w >= N_NODES) return;
    const float* r = in + (size_t)w * 100;
    float v0 = r[lane];
    int j1 = lane + 64;
    float v1 = (j1 < 100) ? r[j1] : 0.f;
    float ss = v0 * v0 + v1 * v1;
#pragma unroll
    for (int o = 32; o > 0; o >>= 1) ss += __shfl_down(ss, o);
    ss = __shfl(ss, 0);
    float inv = 1.f / fmaxf(sqrtf(ss), 1e-12f);
    unsigned short* dst = out + (size_t)w * KP1;
    dst[lane] = f2bf(v0 * inv);
    dst[j1] = (j1 < 100) ? f2bf(v1 * inv) : (unsigned short)0;
}

// ---------------- bf16 MFMA GEMM: N-split strips, 4-way ILP, coalesced LDS-staged stores ----
// A: [M][KP] bf16, B: [Npad][KP] bf16 (rows >= N are zero), C: [M][ldc] bf16.
// grid: (M/64, nsplits); each y handles gPerSplit groups of 64 cols.
template <int KP>
__global__ __launch_bounds__(256) void k_gemm_mfma(const unsigned short* __restrict__ A,
                                                   const unsigned short* __restrict__ B,
                                                   unsigned short* __restrict__ C,
                                                   int ldc, int N, int gPerSplit) {
    constexpr int KSTEPS = KP / 32;
    __shared__ unsigned short cbuf[4][16][64];   // 8 KB, wave-private slabs
    int wave = threadIdx.x >> 6;
    int lane = threadIdx.x & 63;
    int quad = lane >> 4;
    int l16 = lane & 15;
    int m0 = blockIdx.x * 64 + wave * 16;
    // this wave's 16-row A strip (full K) in registers — loaded once
    short8 afrag[KSTEPS];
    const unsigned short* arow = A + (size_t)(m0 + l16) * KP + quad * 8;
#pragma unroll
    for (int ks = 0; ks < KSTEPS; ks++)
        afrag[ks] = *(const short8*)(arow + ks * 32);

    int Gtot = (N + 63) >> 6;
    int g0 = blockIdx.y * gPerSplit;
    int g1 = g0 + gPerSplit;
    if (g1 > Gtot) g1 = Gtot;
    for (int g = g0; g < g1; g++) {
        int nb = g << 6;
        const unsigned short* brow = B + (size_t)(nb + l16) * KP + quad * 8;
        floatx4 a0 = {0.f, 0.f, 0.f, 0.f};
        floatx4 a1 = {0.f, 0.f, 0.f, 0.f};
        floatx4 a2 = {0.f, 0.f, 0.f, 0.f};
        floatx4 a3 = {0.f, 0.f, 0.f, 0.f};
#pragma unroll
        for (int ks = 0; ks < KSTEPS; ks++) {
            short8 b0 = *(const short8*)(brow + ks * 32);
            short8 b1 = *(const short8*)(brow + (size_t)16 * KP + ks * 32);
            short8 b2 = *(const short8*)(brow + (size_t)32 * KP + ks * 32);
            short8 b3 = *(const short8*)(brow + (size_t)48 * KP + ks * 32);
            a0 = __builtin_amdgcn_mfma_f32_16x16x32_bf16(afrag[ks], b0, a0, 0, 0, 0);
            a1 = __builtin_amdgcn_mfma_f32_16x16x32_bf16(afrag[ks], b1, a1, 0, 0, 0);
            a2 = __builtin_amdgcn_mfma_f32_16x16x32_bf16(afrag[ks], b2, a2, 0, 0, 0);
            a3 = __builtin_amdgcn_mfma_f32_16x16x32_bf16(afrag[ks], b3, a3, 0, 0, 0);
        }
        // C/D layout: col = l16, row = quad*4 + reg -> stage into LDS
        int r0 = quad * 4;
#pragma unroll
        for (int i = 0; i < 4; i++) {
            cbuf[wave][r0 + i][l16] = f2bf(a0[i]);
            cbuf[wave][r0 + i][16 + l16] = f2bf(a1[i]);
            cbuf[wave][r0 + i][32 + l16] = f2bf(a2[i]);
            cbuf[wave][r0 + i][48 + l16] = f2bf(a3[i]);
        }
        // coalesced flush, 16B/lane (same-wave LDS ops are in-order; no barrier)
        int colsA = N - nb; if (colsA > 64) colsA = 64;
        int cols8 = colsA >> 3;
        int nchunks = cols8 << 4;   // 16 rows
        for (int c = lane; c < nchunks; c += 64) {
            int row = c / cols8;
            int col8 = (c - row * cols8) * 8;
            *(uint4*)(C + (size_t)(m0 + row) * ldc + nb + col8) =
                *(const uint4*)&cbuf[wave][row][col8];
        }
    }
}

// ---------------- u-vectors: u = a_part^T @ a2 ----------------
// uvecs: [0:100)=u_t0 [100:200)=u_s0 [200:300)=u_t1 [300:400)=u_s1 [400:600)=u_t2 [600:800)=u_s2
__global__ void k_uvec(const float* __restrict__ att_a, const float* __restrict__ att_a2,
                       const float* __restrict__ out_a, const float* __restrict__ out_a2,
                       float* __restrict__ uvecs) {
    int tid = blockIdx.x * blockDim.x + threadIdx.x;
    if (tid >= 800) return;
    float s = 0.f;
    if (tid < 400) {
        int v = tid / 100, k = tid % 100;
        int head = v >> 1, part = v & 1;
        const float* base = att_a + head * 30000 + part * 100 + k;
        const float* a2 = att_a2 + head * 100;
        for (int n = 0; n < 100; n++) s += a2[n] * base[n * 300];
        uvecs[tid] = s;
    } else {
        int v = (tid - 400) / 200, k = (tid - 400) % 200;
        const float* base = out_a + v * 200 + k;
        for (int n = 0; n < 200; n++) s += out_a2[n] * base[n * 600];
        uvecs[400 + v * 200 + k] = s;
    }
}

// ---------------- pack layer-1 B matrix (interleaved Pt/Ps): Wcat1 [NPAD1][KP1] --------------
__global__ void k_pack1(const float* __restrict__ att_a, const float* __restrict__ W_ent,
                        const float* __restrict__ uvecs, unsigned short* __restrict__ W) {
    int idx = blockIdx.x * blockDim.x + threadIdx.x;
    if (idx >= NPAD1 * KP1) return;
    int r = idx >> 7, k = idx & (KP1 - 1);
    float val = 0.f;
    if (k < 100) {
        if (r < 200) {                       // Pt interleaved: col 2i+h = a_t head h row i
            int i = r >> 1, h = r & 1;
            val = att_a[h * 30000 + i * 300 + k];
        } else if (r < 400) {                // Ps interleaved
            int rr = r - 200, i = rr >> 1, h = rr & 1;
            val = att_a[h * 30000 + i * 300 + 100 + k];
        } else if (r < 600) {
            val = W_ent[k * 200 + (r - 400)];
        } else if (r < 604) {
            val = uvecs[(r - 600) * 100 + k];
        }
    }
    W[idx] = f2bf(val);
}

// ---------------- pack layer-2 B matrix (x is K-interleaved): Wcat2 [NPAD2][KP2] -------------
__global__ void k_pack2(const float* __restrict__ out_a, const float* __restrict__ uvecs,
                        unsigned short* __restrict__ W) {
    int idx = blockIdx.x * blockDim.x + threadIdx.x;
    if (idx >= NPAD2 * KP2) return;
    int r = idx >> 8, k = idx & (KP2 - 1);
    float val = 0.f;
    if (k < 200) {
        int klog = (k & 1) * 100 + (k >> 1);   // phys 2f=h0 feat f, 2f+1=h1 feat f
        if (r < 200)       val = out_a[r * 600 + klog];
        else if (r < 400)  val = out_a[(r - 200) * 600 + 200 + klog];
        else if (r == 400) val = uvecs[400 + klog];
        else if (r == 401) val = uvecs[600 + klog];
    }
    W[idx] = f2bf(val);
}

// ---------------- R1 interleaved projection: R1i[474][200], (R10[f],R11[f]) pairs ------------
__global__ void k_relproj1(const float* __restrict__ rel_emb, const float* __restrict__ att_a,
                           float* __restrict__ R1i) {
    int w = (blockIdx.x * blockDim.x + threadIdx.x) >> 6;
    int lane = threadIdx.x & 63;
    if (w >= N_RELS) return;
    const float* re = rel_emb + (size_t)w * 100;
    float2* dst = (float2*)(R1i + (size_t)w * 200);
    for (int f = lane; f < 100; f += 64) {
        const float* a0 = att_a + f * 300 + 200;
        const float* a1 = att_a + 30000 + f * 300 + 200;
        float s0 = 0.f, s1 = 0.f;
        for (int k = 0; k < 100; k++) {
            float rk = re[k];
            s0 += rk * a0[k];
            s1 += rk * a1[k];
        }
        dst[f] = make_float2(s0, s1);
    }
}

// dR1h[r] = R1h[r] . a2_h
__global__ void k_dR1(const float* __restrict__ R1i, const float* __restrict__ att_a2,
                      float* __restrict__ dR10, float* __restrict__ dR11) {
    int w = (blockIdx.x * blockDim.x + threadIdx.x) >> 6;
    int lane = threadIdx.x & 63;
    if (w >= N_RELS) return;
    const float2* row = (const float2*)(R1i + (size_t)w * 200);
    float s0 = 0.f, s1 = 0.f;
    for (int f = lane; f < 100; f += 64) {
        float2 v = row[f];
        s0 += v.x * att_a2[f];
        s1 += v.y * att_a2[100 + f];
    }
#pragma unroll
    for (int o = 32; o > 0; o >>= 1) {
        s0 += __shfl_down(s0, o);
        s1 += __shfl_down(s1, o);
    }
    if (lane == 0) { dR10[w] = s0; dR11[w] = s1; }
}

// ---------------- generic tiled fp32 matmul (474-row cases only) ----------------
template <bool BT>
__global__ __launch_bounds__(256) void k_mm(const float* __restrict__ A, int lda,
                                            const float* __restrict__ B, int ldb,
                                            float* __restrict__ C, int ldc,
                                            int M, int N, int K) {
    __shared__ float As[16][65];
    __shared__ float Bs[16][65];
    int tid = threadIdx.x;
    int tx = tid & 15, ty = tid >> 4;
    int m0 = blockIdx.y * 64, n0 = blockIdx.x * 64;
    float acc[4][4] = {};
    for (int k0 = 0; k0 < K; k0 += 16) {
        {
            int r = tid >> 2;
            int c4 = (tid & 3) * 4;
            int m = m0 + r;
#pragma unroll
            for (int u = 0; u < 4; u++) {
                int k = k0 + c4 + u;
                As[c4 + u][r] = (m < M && k < K) ? A[(size_t)m * lda + k] : 0.f;
            }
        }
        if (BT) {
            int r = tid >> 2;
            int c4 = (tid & 3) * 4;
            int n = n0 + r;
#pragma unroll
            for (int u = 0; u < 4; u++) {
                int k = k0 + c4 + u;
                Bs[c4 + u][r] = (n < N && k < K) ? B[(size_t)n * ldb + k] : 0.f;
            }
        } else {
            int kk = tid >> 4;
            int nn4 = (tid & 15) * 4;
            int k = k0 + kk;
#pragma unroll
            for (int u = 0; u < 4; u++) {
                int n = n0 + nn4 + u;
                Bs[kk][nn4 + u] = (k < K && n < N) ? B[(size_t)k * ldb + n] : 0.f;
            }
        }
        __syncthreads();
#pragma unroll
        for (int k = 0; k < 16; k++) {
            float a[4], b[4];
#pragma unroll
            for (int i = 0; i < 4; i++) a[i] = As[k][ty + 16 * i];
#pragma unroll
            for (int j = 0; j < 4; j++) b[j] = Bs[k][tx + 16 * j];
#pragma unroll
            for (int i = 0; i < 4; i++)
#pragma unroll
                for (int j = 0; j < 4; j++) acc[i][j] += a[i] * b[j];
        }
        __syncthreads();
    }
#pragma unroll
    for (int i = 0; i < 4; i++) {
        int m = m0 + ty + 16 * i;
        if (m >= M) continue;
#pragma unroll
        for (int j = 0; j < 4; j++) {
            int n = n0 + tx + 16 * j;
            if (n < N) C[(size_t)m * ldc + n] = acc[i][j];
        }
    }
}

// ---------------- per-row dot with vector (474-row cases) ----------------
__global__ void k_dotv(const float* __restrict__ mat, const float* __restrict__ vec,
                       float* __restrict__ out, int M, int F) {
    int w = (blockIdx.x * blockDim.x + threadIdx.x) >> 6;
    int lane = threadIdx.x & 63;
    if (w >= M) return;
    const float* r = mat + (size_t)w * F;
    float s = 0.f;
    for (int j = lane; j < F; j += 64) s += r[j] * vec[j];
#pragma unroll
    for (int o = 32; o > 0; o >>= 1) s += __shfl_down(s, o);
    if (lane == 0) out[w] = s;
}

// ---------------- CSR build ----------------
__global__ void k_hist(const int* __restrict__ tgt_el, const int* __restrict__ nhop,
                       int* __restrict__ deg) {
    int e = blockIdx.x * blockDim.x + threadIdx.x;
    if (e >= NE) return;
    int t = (e < E0) ? tgt_el[e] : nhop[(size_t)(e - E0) * 4 + 3];
    atomicAdd(&deg[t], 1);
}

__global__ void k_scan1(const int* __restrict__ deg, int* __restrict__ local,
                        int* __restrict__ bsums, int n) {
    int i = blockIdx.x * 256 + threadIdx.x;
    int v = (i < n) ? deg[i] : 0;
    int lane = threadIdx.x & 63;
    int wv = threadIdx.x >> 6;
    int x = v;
#pragma unroll
    for (int o = 1; o < 64; o <<= 1) {
        int t = __shfl_up(x, o);
        if (lane >= o) x += t;
    }
    __shared__ int wtot[4];
    if (lane == 63) wtot[wv] = x;
    __syncthreads();
    int add = 0;
    for (int k = 0; k < wv; k++) add += wtot[k];
    if (i < n) local[i] = add + x - v;
    if (threadIdx.x == 255) bsums[blockIdx.x] = add + x;
}

__global__ void k_scan2(int* __restrict__ bsums, int nb) {
    int tid = threadIdx.x;
    int v = (tid < nb) ? bsums[tid] : 0;
    int lane = tid & 63, wv = tid >> 6;
    int x = v;
#pragma unroll
    for (int o = 1; o < 64; o <<= 1) {
        int t = __shfl_up(x, o);
        if (lane >= o) x += t;
    }
    __shared__ int wtot[4];
    if (lane == 63) wtot[wv] = x;
    __syncthreads();
    int add = 0;
    for (int k = 0; k < wv; k++) add += wtot[k];
    __syncthreads();
    if (tid < nb) bsums[tid] = add + x - v;
    if (tid == 255) bsums[nb] = add + x;
}

__global__ void k_scan3(const int* __restrict__ local, const int* __restrict__ bsums,
                        int* __restrict__ rowptr, int* __restrict__ cursor, int n, int nb) {
    int i = blockIdx.x * 256 + threadIdx.x;
    if (i < n) {
        int v = local[i] + bsums[blockIdx.x];
        rowptr[i] = v;
        cursor[i] = v;
    } else if (i == n) {
        rowptr[n] = bsums[nb];
    }
}

// scatter edge payloads into CSR order
__global__ void k_scatter(const int* __restrict__ tgt_el, const int* __restrict__ src_el,
                          const int* __restrict__ etype, const int* __restrict__ nhop,
                          int* __restrict__ cursor,
                          int* __restrict__ tgts, int* __restrict__ srcs,
                          int2* __restrict__ relpk) {
    int e = blockIdx.x * blockDim.x + threadIdx.x;
    if (e >= NE) return;
    int t, s, r1, r2;
    if (e < E0) {
        t = tgt_el[e]; s = src_el[e]; r1 = etype[e]; r2 = -1;
    } else {
        const int* nh = nhop + (size_t)(e - E0) * 4;
        t = nh[3]; s = nh[0]; r1 = nh[1]; r2 = nh[2];
    }
    int p = atomicAdd(&cursor[t], 1);
    tgts[p] = t; srcs[p] = s;
    relpk[p] = make_int2(r1, r2);
}

// ---------------- per-edge attention scalars (CSR-position order) ----------------
__global__ void k_edge1(const int* __restrict__ tgts, const int* __restrict__ srcs,
                        const int2* __restrict__ relpk,
                        const unsigned short* __restrict__ Pcat,
                        const float* __restrict__ dR10, const float* __restrict__ dR11,
                        float2* __restrict__ wpair) {
    int p = blockIdx.x * blockDim.x + threadIdx.x;
    if (p >= NE) return;
    int t = tgts[p], s = srcs[p];
    int2 rp = relpk[p];
    float dr0 = dR10[rp.x], dr1 = dR11[rp.x];
    if (rp.y >= 0) { dr0 += dR10[rp.y]; dr1 += dR11[rp.y]; }
    uint2 td = *(const uint2*)(Pcat + (size_t)t * LD1 + 600);   // (u_t0,u_s0),(u_t1,u_s1)
    uint2 sd = *(const uint2*)(Pcat + (size_t)s * LD1 + 600);
    float p0 = bflo(td.x) + bfhi(sd.x) + dr0;
    float p1 = bflo(td.y) + bfhi(sd.y) + dr1;
    p0 = (p0 >= 0.f) ? p0 : LRALPHA * p0;
    p1 = (p1 >= 0.f) ? p1 : LRALPHA * p1;
    wpair[p] = make_float2(expf(-p0), expf(-p1));
}

__global__ void k_edge2(const int* __restrict__ tgts, const int* __restrict__ srcs,
                        const int2* __restrict__ relpk,
                        const unsigned short* __restrict__ Qcat,
                        const float* __restrict__ dR2, float* __restrict__ w2) {
    int p = blockIdx.x * blockDim.x + threadIdx.x;
    if (p >= NE) return;
    int t = tgts[p], s = srcs[p];
    int2 rp = relpk[p];
    float dr = dR2[rp.x];
    if (rp.y >= 0) dr += dR2[rp.y];
    uint32_t tq = *(const uint32_t*)(Qcat + (size_t)t * LD2 + 400);  // (dqt, dqs)
    uint32_t sq = *(const uint32_t*)(Qcat + (size_t)s * LD2 + 400);
    float pp = bflo(tq) + bfhi(sq) + dr;
    pp = (pp >= 0.f) ? pp : LRALPHA * pp;
    w2[p] = expf(-pp);
}

// ---------------- node aggregation layer 1 (wave/node) -> x bf16 K-interleaved --------------
__global__ void k_node1(const int* __restrict__ rowptr, const int* __restrict__ srcs,
                        const int2* __restrict__ relpk, const float2* __restrict__ wpair,
                        const unsigned short* __restrict__ Pcat,
                        const float* __restrict__ R1i,
                        unsigned short* __restrict__ x) {
    int node = (blockIdx.x * blockDim.x + threadIdx.x) >> 6;
    int lane = threadIdx.x & 63;
    if (node >= N_NODES) return;
    int f0 = lane, f1 = lane + 64;
    bool v1 = (f1 < 100);
    float b00 = 0, b01 = 0, b10 = 0, b11 = 0, rs0 = 0, rs1 = 0;
    int beg = rowptr[node], end = rowptr[node + 1];
    for (int p = beg; p < end; p++) {
        int s = srcs[p];
        int2 rp = relpk[p];
        float2 w = wpair[p];
        const float2* r1a = (const float2*)(R1i + (size_t)rp.x * 200);
        float2 ra0 = r1a[f0];
        float2 ra1 = v1 ? r1a[f1] : make_float2(0.f, 0.f);
        if (rp.y >= 0) {
            const float2* r1b = (const float2*)(R1i + (size_t)rp.y * 200);
            float2 t0 = r1b[f0];
            ra0.x += t0.x; ra0.y += t0.y;
            if (v1) { float2 t1 = r1b[f1]; ra1.x += t1.x; ra1.y += t1.y; }
        }
        const unsigned short* prow = Pcat + (size_t)s * LD1 + 200;
        uint32_t ps0 = *(const uint32_t*)(prow + 2 * f0);
        rs0 += w.x; rs1 += w.y;
        b00 += w.x * (bflo(ps0) + ra0.x);
        b01 += w.y * (bfhi(ps0) + ra0.y);
        if (v1) {
            uint32_t ps1 = *(const uint32_t*)(prow + 2 * f1);
            b10 += w.x * (bflo(ps1) + ra1.x);
            b11 += w.y * (bfhi(ps1) + ra1.y);
        }
    }
    float d0 = (rs0 == 0.f) ? 1e-12f : rs0;
    float d1 = (rs1 == 0.f) ? 1e-12f : rs1;
    const unsigned short* pn = Pcat + (size_t)node * LD1;
    unsigned short* xr = x + (size_t)node * KP2;
    {
        uint32_t pt = *(const uint32_t*)(pn + 2 * f0);
        float v = (b00 + rs0 * bflo(pt)) / d0;
        float u = (b01 + rs1 * bfhi(pt)) / d1;
        v = (v > 0.f) ? v : expm1f(v);
        u = (u > 0.f) ? u : expm1f(u);
        *(uint32_t*)(xr + 2 * f0) = (uint32_t)f2bf(v) | ((uint32_t)f2bf(u) << 16);
    }
    if (v1) {
        uint32_t pt = *(const uint32_t*)(pn + 2 * f1);
        float v = (b10 + rs0 * bflo(pt)) / d0;
        float u = (b11 + rs1 * bfhi(pt)) / d1;
        v = (v > 0.f) ? v : expm1f(v);
        u = (u > 0.f) ? u : expm1f(u);
        *(uint32_t*)(xr + 2 * f1) = (uint32_t)f2bf(v) | ((uint32_t)f2bf(u) << 16);
    }
    if (lane < (KP2 - 200) / 2) *(uint32_t*)(xr + 200 + 2 * lane) = 0;
}

// ---------------- node aggregation layer 2 + final fuse (wave/node) ----------------
__global__ void k_node2(const int* __restrict__ rowptr, const int* __restrict__ srcs,
                        const int2* __restrict__ relpk, const float* __restrict__ w2,
                        const unsigned short* __restrict__ Qcat,
                        const unsigned short* __restrict__ Pcat,
                        const float* __restrict__ R2, const float* __restrict__ mask,
                        float* __restrict__ out) {
    int node = (blockIdx.x * blockDim.x + threadIdx.x) >> 6;
    int lane = threadIdx.x & 63;
    if (node >= N_NODES) return;
    int q0 = lane, q1 = lane + 64;      // feature pairs (2q, 2q+1); 100 pairs
    bool v = (q1 < 100);
    float c00 = 0, c01 = 0, c10 = 0, c11 = 0, rs = 0;
    int beg = rowptr[node], end = rowptr[node + 1];
    for (int p = beg; p < end; p++) {
        int s = srcs[p];
        int2 rp = relpk[p];
        float W = w2[p];
        const float* r2r = R2 + (size_t)rp.x * 200;
        float2 ra = *(const float2*)(r2r + 2 * q0);
        float2 rb = v ? *(const float2*)(r2r + 2 * q1) : make_float2(0.f, 0.f);
        if (rp.y >= 0) {
            const float* r2b = R2 + (size_t)rp.y * 200;
            float2 t0 = *(const float2*)(r2b + 2 * q0);
            ra.x += t0.x; ra.y += t0.y;
            if (v) { float2 t1 = *(const float2*)(r2b + 2 * q1); rb.x += t1.x; rb.y += t1.y; }
        }
        const unsigned short* qsrow = Qcat + (size_t)s * LD2 + 200;
        uint32_t qa = *(const uint32_t*)(qsrow + 2 * q0);
        rs += W;
        c00 += W * (bflo(qa) + ra.x);
        c01 += W * (bfhi(qa) + ra.y);
        if (v) {
            uint32_t qb = *(const uint32_t*)(qsrow + 2 * q1);
            c10 += W * (bflo(qb) + rb.x);
            c11 += W * (bfhi(qb) + rb.y);
        }
    }
    float d = (rs == 0.f) ? 1e-12f : rs;
    const unsigned short* qt = Qcat + (size_t)node * LD2;
    const unsigned short* ew = Pcat + (size_t)node * LD1 + 400;
    float mk = mask[node];
    uint32_t t0 = *(const uint32_t*)(qt + 2 * q0);
    uint32_t e0 = *(const uint32_t*)(ew + 2 * q0);
    float val00 = bflo(e0) + mk * ((c00 + rs * bflo(t0)) / d);
    float val01 = bfhi(e0) + mk * ((c01 + rs * bfhi(t0)) / d);
    float val10 = 0.f, val11 = 0.f;
    if (v) {
        uint32_t t1 = *(const uint32_t*)(qt + 2 * q1);
        uint32_t e1 = *(const uint32_t*)(ew + 2 * q1);
        val10 = bflo(e1) + mk * ((c10 + rs * bflo(t1)) / d);
        val11 = bfhi(e1) + mk * ((c11 + rs * bfhi(t1)) / d);
    }
    float ss = val00 * val00 + val01 * val01 + val10 * val10 + val11 * val11;
#pragma unroll
    for (int o = 32; o > 0; o >>= 1) ss += __shfl_down(ss, o);
    ss = __shfl(ss, 0);
    float inv = 1.f / fmaxf(sqrtf(ss), 1e-12f);
    float* dst = out + (size_t)node * 200;
    *(float2*)(dst + 2 * q0) = make_float2(val00 * inv, val01 * inv);
    if (v) *(float2*)(dst + 2 * q1) = make_float2(val10 * inv, val11 * inv);
}

// ---------------- mask scatter ----------------
__global__ void k_mask(const int* __restrict__ batch, float* __restrict__ mask) {
    int i = blockIdx.x * blockDim.x + threadIdx.x;
    if (i < NB) mask[batch[(size_t)i * 3 + 2]] = 1.0f;
}

// ---------------- ortho losses: parallel partial reduction ----------------
__global__ void k_ortho_part(const float* __restrict__ att_a, const float* __restrict__ out_a,
                             float* __restrict__ accum) {
    float loc[9] = {0,0,0,0,0,0,0,0,0};
    int stride = gridDim.x * blockDim.x;
    for (int i = blockIdx.x * blockDim.x + threadIdx.x; i < 90000; i += stride) {
        int seg, li;
        const float* base;
        int L;
        if (i < 15000)      { seg = 0; li = i;          base = att_a;         L = 15000; }
        else if (i < 30000) { seg = 1; li = i - 15000;  base = att_a + 30000; L = 15000; }
        else                { seg = 2; li = i - 30000;  base = out_a;         L = 60000; }
        float a = base[li], b = base[L + li];
        loc[seg * 3 + 0] += a * a;
        loc[seg * 3 + 1] += b * b;
        loc[seg * 3 + 2] += a * b;
    }
    int lane = threadIdx.x & 63;
#pragma unroll
    for (int q = 0; q < 9; q++) {
        float s = loc[q];
#pragma unroll
        for (int o = 32; o > 0; o >>= 1) s += __shfl_down(s, o);
        if (lane == 0 && s != 0.f) atomicAdd(&accum[q], s);
    }
}

__global__ void k_ortho_fin(const float* __restrict__ accum, float* __restrict__ out_scalar) {
    if (threadIdx.x != 0 || blockIdx.x != 0) return;
    float total = 0.f;
#pragma unroll
    for (int m = 0; m < 3; m++) {
        float s0 = accum[m * 3 + 0], s1 = accum[m * 3 + 1], sc = accum[m * 3 + 2];
        float c = sc / (fmaxf(sqrtf(s0), 1e-12f) * fmaxf(sqrtf(s1), 1e-12f));
        total += 0.01f * 2.f * c * c;
    }
    out_scalar[0] = total;
}

// ---------------- launch ----------------
extern "C" void kernel_launch(void* const* d_in, const int* in_sizes, int n_in,
                              void* d_out, int out_size, void* d_ws, size_t ws_size,
                              hipStream_t stream) {
    const int* edge_list = (const int*)d_in[0];
    const int* edge_type = (const int*)d_in[1];
    const int* batch     = (const int*)d_in[2];
    const int* nhop      = (const int*)d_in[3];
    const float* ent_emb = (const float*)d_in[4];
    const float* rel_emb = (const float*)d_in[5];
    const float* W_ent   = (const float*)d_in[6];
    const float* W_rel   = (const float*)d_in[7];
    const float* att_a   = (const float*)d_in[8];
    const float* att_a2  = (const float*)d_in[9];
    const float* out_a   = (const float*)d_in[10];
    const float* out_a2  = (const float*)d_in[11];
    float* out = (float*)d_out;
    const int* tgt_el = edge_list;
    const int* src_el = edge_list + E0;

    char* ws = (char*)d_ws;
    size_t o = 0;
    auto alloc = [&](size_t nbytes) -> char* {
        char* p = ws + o;
        o += (nbytes + 255) & ~(size_t)255;
        return p;
    };
    unsigned short* ent_bf  = (unsigned short*)alloc((size_t)N_NODES * KP1 * 2);
    unsigned short* x_bf    = (unsigned short*)alloc((size_t)N_NODES * KP2 * 2);
    unsigned short* Pcat    = (unsigned short*)alloc((size_t)N_NODES * LD1 * 2);
    unsigned short* Qcat    = (unsigned short*)alloc((size_t)N_NODES * LD2 * 2);
    unsigned short* Wcat1   = (unsigned short*)alloc((size_t)NPAD1 * KP1 * 2);
    unsigned short* Wcat2   = (unsigned short*)alloc((size_t)NPAD2 * KP2 * 2);
    float* uvecs = (float*)alloc(800 * 4);
    float* R1i   = (float*)alloc(474u * 200 * 4);
    float* R2    = (float*)alloc(474u * 200 * 4);
    float* dR10  = (float*)alloc(474u * 4);
    float* dR11  = (float*)alloc(474u * 4);
    float* dR2   = (float*)alloc(474u * 4);
    float2* wpair = (float2*)alloc((size_t)NE * 8);
    float* w2    = (float*)alloc((size_t)NE * 4);
    int* rowptr  = (int*)alloc((N_NODES + 1) * 4);
    int* cursor  = (int*)alloc(N_NODES * 4);
    int* tgts    = (int*)alloc((size_t)NE * 4);
    int* srcs    = (int*)alloc((size_t)NE * 4);
    int2* relpk  = (int2*)alloc((size_t)NE * 8);
    float* mask  = (float*)alloc(N_NODES * 4);
    int* scanloc = (int*)alloc(N_NODES * 4);
    int* bsums   = (int*)alloc(260 * 4);
    float* oacc  = (float*)alloc(9 * 4);

    const int TPB = 256;
    int wave_blocks_40000 = (N_NODES * 64 + TPB - 1) / TPB;   // 10000
    int wave_blocks_474   = (N_RELS * 64 + TPB - 1) / TPB;    // 119
    int edge_blocks       = (NE + TPB - 1) / TPB;
    int scan_blocks       = (N_NODES + 255) / 256;            // 157

    hipMemsetAsync(cursor, 0, N_NODES * 4, stream);
    hipMemsetAsync(mask, 0, N_NODES * 4, stream);
    hipMemsetAsync(oacc, 0, 9 * 4, stream);

    // 1) normalize entities -> bf16 padded
    k_l2norm_bf16<<<wave_blocks_40000, TPB, 0, stream>>>(ent_emb, ent_bf);

    // 2) CSR by target, payloads in CSR order
    k_hist<<<edge_blocks, TPB, 0, stream>>>(tgt_el, nhop, cursor);
    k_scan1<<<scan_blocks, 256, 0, stream>>>(cursor, scanloc, bsums, N_NODES);
    k_scan2<<<1, 256, 0, stream>>>(bsums, scan_blocks);
    k_scan3<<<(N_NODES + 1 + 255) / 256, 256, 0, stream>>>(scanloc, bsums, rowptr, cursor, N_NODES, scan_blocks);
    k_scatter<<<edge_blocks, TPB, 0, stream>>>(tgt_el, src_el, edge_type, nhop, cursor,
                                               tgts, srcs, relpk);

    // 3) pack fused B matrices (zero-padded rows)
    k_uvec<<<4, 256, 0, stream>>>(att_a, att_a2, out_a, out_a2, uvecs);
    k_pack1<<<(NPAD1 * KP1 + 255) / 256, 256, 0, stream>>>(att_a, W_ent, uvecs, Wcat1);
    k_pack2<<<(NPAD2 * KP2 + 255) / 256, 256, 0, stream>>>(out_a, uvecs, Wcat2);

    // 4) fused layer-1 GEMM (MFMA bf16, N-split x2, 4-way ILP)
    k_gemm_mfma<KP1><<<dim3(625, 2), 256, 0, stream>>>(ent_bf, Wcat1, Pcat, LD1, 608, 5);

    // 5) relation-side projections (interleaved) + dots
    k_relproj1<<<wave_blocks_474, TPB, 0, stream>>>(rel_emb, att_a, R1i);
    k_dR1<<<wave_blocks_474, TPB, 0, stream>>>(R1i, att_a2, dR10, dR11);

    // 6) layer-1 edge weights + aggregation -> x_bf (K-interleaved)
    k_edge1<<<edge_blocks, TPB, 0, stream>>>(tgts, srcs, relpk, Pcat, dR10, dR11, wpair);
    k_node1<<<wave_blocks_40000, TPB, 0, stream>>>(rowptr, srcs, relpk, wpair, Pcat, R1i, x_bf);

    // 7) fused layer-2 GEMM (MFMA bf16, N-split x2, 4-way ILP)
    k_gemm_mfma<KP2><<<dim3(625, 2), 256, 0, stream>>>(x_bf, Wcat2, Qcat, LD2, 416, 4);

    // 8) out_relation_1 = rel_emb @ W_rel -> d_out; R2 = out_rel1 @ a_r2^T; dR2
    dim3 gor((200 + 63) / 64, (N_RELS + 63) / 64);
    k_mm<false><<<gor, TPB, 0, stream>>>(rel_emb, 100, W_rel, 200, out + 8000000, 200, N_RELS, 200, 100);
    k_mm<true><<<gor, TPB, 0, stream>>>(out + 8000000, 200, out_a + 400, 600, R2, 200, N_RELS, 200, 200);
    k_dotv<<<wave_blocks_474, TPB, 0, stream>>>(R2, out_a2, dR2, N_RELS, 200);

    // 9) layer-2 edge weights, mask, aggregation + final fuse
    k_edge2<<<edge_blocks, TPB, 0, stream>>>(tgts, srcs, relpk, Qcat, dR2, w2);
    k_mask<<<(NB + TPB - 1) / TPB, TPB, 0, stream>>>(batch, mask);
    k_node2<<<wave_blocks_40000, TPB, 0, stream>>>(rowptr, srcs, relpk, w2, Qcat, Pcat, R2, mask, out);

    // 10) ortho scalar (parallel)
    k_ortho_part<<<128, 256, 0, stream>>>(att_a, out_a, oacc);
    k_ortho_fin<<<1, 64, 0, stream>>>(oacc, out + 8094800);
}

// Round 8
// 514.780 us; speedup vs baseline: 1.0114x; 1.0056x over previous
//
#include <hip/hip_runtime.h>
#include <cstdint>
#include <cstddef>
#include <math.h>

#define N_NODES 40000
#define N_RELS  474
#define E0      100000
#define EN      30000
#define NE      130000
#define NB      8192
#define LRALPHA 0.2f

#define KP1 128   // padded K for layer-1 GEMM (K=100)
#define KP2 256   // padded K for layer-2 GEMM (K=200)
// Pcat cols: [0:200) Pt interleaved (2f=h0,2f+1=h1) | [200:400) Ps interleaved |
//            [400:600) entW natural | [600:604) dots (u_t0,u_s0,u_t1,u_s1) | pad
#define LD1 608
// Qcat cols: [0:200) Qt | [200:400) Qs | 400 dqt | 401 dqs | pad
#define LD2 416
#define NPAD1 640   // Wcat1 rows (zero-padded past 604)
#define NPAD2 448   // Wcat2 rows (zero-padded past 402)

typedef __attribute__((ext_vector_type(8))) short short8;
typedef __attribute__((ext_vector_type(4))) float floatx4;

static __device__ __forceinline__ unsigned short f2bf(float f) {
    union { float f; uint32_t u; } v; v.f = f;
    uint32_t r = v.u + 0x7fff + ((v.u >> 16) & 1);
    return (unsigned short)(r >> 16);
}
static __device__ __forceinline__ float bf2f(unsigned short h) {
    union { uint32_t u; float f; } v; v.u = ((uint32_t)h) << 16;
    return v.f;
}
static __device__ __forceinline__ float bflo(uint32_t u) { return bf2f((unsigned short)(u & 0xffff)); }
static __device__ __forceinline__ float bfhi(uint32_t u) { return bf2f((unsigned short)(u >> 16)); }

// ---------------- l2norm rows of ent -> bf16 padded [40000][KP1] ----------------
__global__ void k_l2norm_bf16(const float* __restrict__ in, unsigned short* __restrict__ out) {
    int w = (blockIdx.x * blockDim.x + threadIdx.x) >> 6;
    int lane = threadIdx.x & 63;
    if (w >= N_NODES) return;
    const float* r = in + (size_t)w * 100;
    float v0 = r[lane];
    int j1 = lane + 64;
    float v1 = (j1 < 100) ? r[j1] : 0.f;
    float ss = v0 * v0 + v1 * v1;
#pragma unroll
    for (int o = 32; o > 0; o >>= 1) ss += __shfl_down(ss, o);
    ss = __shfl(ss, 0);
    float inv = 1.f / fmaxf(sqrtf(ss), 1e-12f);
    unsigned short* dst = out + (size_t)w * KP1;
    dst[lane] = f2bf(v0 * inv);
    dst[j1] = (j1 < 100) ? f2bf(v1 * inv) : (unsigned short)0;
}

// ---------------- bf16 MFMA GEMM: register-preloaded B chunks, 4-way ILP -------------------
// A: [M][KP] bf16, B: [Npad][KP] bf16 (rows >= N are zero), C: [M][ldc] bf16.
// grid: (M/64, nsplits); each y handles gPerSplit groups of 64 cols.
// K processed in chunks of 128: all 16 B-fragments of a chunk preloaded to regs, then 16 MFMAs.
template <int KP>
__global__ __launch_bounds__(256) void k_gemm_mfma(const unsigned short* __restrict__ A,
                                                   const unsigned short* __restrict__ B,
                                                   unsigned short* __restrict__ C,
                                                   int ldc, int N, int gPerSplit) {
    constexpr int KSTEPS = KP / 32;          // 4 (L1) or 8 (L2)
    constexpr int KCH = KSTEPS / 4;          // chunks of 4 ksteps: 1 or 2
    __shared__ unsigned short cbuf[4][16][64];   // 8 KB, wave-private slabs
    int wave = threadIdx.x >> 6;
    int lane = threadIdx.x & 63;
    int quad = lane >> 4;
    int l16 = lane & 15;
    int m0 = blockIdx.x * 64 + wave * 16;
    // this wave's 16-row A strip (full K) in registers — loaded once
    short8 afrag[KSTEPS];
    const unsigned short* arow = A + (size_t)(m0 + l16) * KP + quad * 8;
#pragma unroll
    for (int ks = 0; ks < KSTEPS; ks++)
        afrag[ks] = *(const short8*)(arow + ks * 32);

    int Gtot = (N + 63) >> 6;
    int g0 = blockIdx.y * gPerSplit;
    int g1 = g0 + gPerSplit;
    if (g1 > Gtot) g1 = Gtot;
    for (int g = g0; g < g1; g++) {
        int nb = g << 6;
        const unsigned short* brow = B + (size_t)(nb + l16) * KP + quad * 8;
        floatx4 acc[4];
#pragma unroll
        for (int t = 0; t < 4; t++) acc[t] = (floatx4){0.f, 0.f, 0.f, 0.f};
#pragma unroll
        for (int ch = 0; ch < KCH; ch++) {
            // preload entire chunk's B fragments (4 tiles x 4 ksteps = 16 x 16B) -> 1 round trip
            short8 bf[4][4];
#pragma unroll
            for (int t = 0; t < 4; t++)
#pragma unroll
                for (int k = 0; k < 4; k++)
                    bf[t][k] = *(const short8*)(brow + (size_t)(t * 16) * KP + (ch * 4 + k) * 32);
            // 16 MFMAs: k-outer, tile-inner => 4 independent chains
#pragma unroll
            for (int k = 0; k < 4; k++)
#pragma unroll
                for (int t = 0; t < 4; t++)
                    acc[t] = __builtin_amdgcn_mfma_f32_16x16x32_bf16(afrag[ch * 4 + k], bf[t][k], acc[t], 0, 0, 0);
        }
        // C/D layout: col = l16, row = quad*4 + reg -> stage into LDS
        int r0 = quad * 4;
#pragma unroll
        for (int t = 0; t < 4; t++)
#pragma unroll
            for (int i = 0; i < 4; i++)
                cbuf[wave][r0 + i][t * 16 + l16] = f2bf(acc[t][i]);
        // coalesced flush, 16B/lane (same-wave LDS ops are in-order; no barrier)
        int colsA = N - nb; if (colsA > 64) colsA = 64;
        int cols8 = colsA >> 3;              // 8 (full) or 4 (32-col tail)
        int sh = (colsA >= 64) ? 3 : 2;
        int nchunks = cols8 << 4;            // 16 rows
        for (int c = lane; c < nchunks; c += 64) {
            int row = c >> sh;
            int col8 = (c & (cols8 - 1)) << 3;
            *(uint4*)(C + (size_t)(m0 + row) * ldc + nb + col8) =
                *(const uint4*)&cbuf[wave][row][col8];
        }
    }
}

// ---------------- u-vectors: u = a_part^T @ a2 ----------------
// uvecs: [0:100)=u_t0 [100:200)=u_s0 [200:300)=u_t1 [300:400)=u_s1 [400:600)=u_t2 [600:800)=u_s2
__global__ void k_uvec(const float* __restrict__ att_a, const float* __restrict__ att_a2,
                       const float* __restrict__ out_a, const float* __restrict__ out_a2,
                       float* __restrict__ uvecs) {
    int tid = blockIdx.x * blockDim.x + threadIdx.x;
    if (tid >= 800) return;
    float s = 0.f;
    if (tid < 400) {
        int v = tid / 100, k = tid % 100;
        int head = v >> 1, part = v & 1;
        const float* base = att_a + head * 30000 + part * 100 + k;
        const float* a2 = att_a2 + head * 100;
        for (int n = 0; n < 100; n++) s += a2[n] * base[n * 300];
        uvecs[tid] = s;
    } else {
        int v = (tid - 400) / 200, k = (tid - 400) % 200;
        const float* base = out_a + v * 200 + k;
        for (int n = 0; n < 200; n++) s += out_a2[n] * base[n * 600];
        uvecs[400 + v * 200 + k] = s;
    }
}

// ---------------- pack layer-1 B matrix (interleaved Pt/Ps): Wcat1 [NPAD1][KP1] --------------
__global__ void k_pack1(const float* __restrict__ att_a, const float* __restrict__ W_ent,
                        const float* __restrict__ uvecs, unsigned short* __restrict__ W) {
    int idx = blockIdx.x * blockDim.x + threadIdx.x;
    if (idx >= NPAD1 * KP1) return;
    int r = idx >> 7, k = idx & (KP1 - 1);
    float val = 0.f;
    if (k < 100) {
        if (r < 200) {                       // Pt interleaved: col 2i+h = a_t head h row i
            int i = r >> 1, h = r & 1;
            val = att_a[h * 30000 + i * 300 + k];
        } else if (r < 400) {                // Ps interleaved
            int rr = r - 200, i = rr >> 1, h = rr & 1;
            val = att_a[h * 30000 + i * 300 + 100 + k];
        } else if (r < 600) {
            val = W_ent[k * 200 + (r - 400)];
        } else if (r < 604) {
            val = uvecs[(r - 600) * 100 + k];
        }
    }
    W[idx] = f2bf(val);
}

// ---------------- pack layer-2 B matrix (x is K-interleaved): Wcat2 [NPAD2][KP2] -------------
__global__ void k_pack2(const float* __restrict__ out_a, const float* __restrict__ uvecs,
                        unsigned short* __restrict__ W) {
    int idx = blockIdx.x * blockDim.x + threadIdx.x;
    if (idx >= NPAD2 * KP2) return;
    int r = idx >> 8, k = idx & (KP2 - 1);
    float val = 0.f;
    if (k < 200) {
        int klog = (k & 1) * 100 + (k >> 1);   // phys 2f=h0 feat f, 2f+1=h1 feat f
        if (r < 200)       val = out_a[r * 600 + klog];
        else if (r < 400)  val = out_a[(r - 200) * 600 + 200 + klog];
        else if (r == 400) val = uvecs[400 + klog];
        else if (r == 401) val = uvecs[600 + klog];
    }
    W[idx] = f2bf(val);
}

// ---------------- R1 interleaved projection: R1i[474][200], (R10[f],R11[f]) pairs ------------
__global__ void k_relproj1(const float* __restrict__ rel_emb, const float* __restrict__ att_a,
                           float* __restrict__ R1i) {
    int w = (blockIdx.x * blockDim.x + threadIdx.x) >> 6;
    int lane = threadIdx.x & 63;
    if (w >= N_RELS) return;
    const float* re = rel_emb + (size_t)w * 100;
    float2* dst = (float2*)(R1i + (size_t)w * 200);
    for (int f = lane; f < 100; f += 64) {
        const float* a0 = att_a + f * 300 + 200;
        const float* a1 = att_a + 30000 + f * 300 + 200;
        float s0 = 0.f, s1 = 0.f;
        for (int k = 0; k < 100; k++) {
            float rk = re[k];
            s0 += rk * a0[k];
            s1 += rk * a1[k];
        }
        dst[f] = make_float2(s0, s1);
    }
}

// dR1h[r] = R1h[r] . a2_h
__global__ void k_dR1(const float* __restrict__ R1i, const float* __restrict__ att_a2,
                      float* __restrict__ dR10, float* __restrict__ dR11) {
    int w = (blockIdx.x * blockDim.x + threadIdx.x) >> 6;
    int lane = threadIdx.x & 63;
    if (w >= N_RELS) return;
    const float2* row = (const float2*)(R1i + (size_t)w * 200);
    float s0 = 0.f, s1 = 0.f;
    for (int f = lane; f < 100; f += 64) {
        float2 v = row[f];
        s0 += v.x * att_a2[f];
        s1 += v.y * att_a2[100 + f];
    }
#pragma unroll
    for (int o = 32; o > 0; o >>= 1) {
        s0 += __shfl_down(s0, o);
        s1 += __shfl_down(s1, o);
    }
    if (lane == 0) { dR10[w] = s0; dR11[w] = s1; }
}

// ---------------- generic tiled fp32 matmul (474-row cases only) ----------------
template <bool BT>
__global__ __launch_bounds__(256) void k_mm(const float* __restrict__ A, int lda,
                                            const float* __restrict__ B, int ldb,
                                            float* __restrict__ C, int ldc,
                                            int M, int N, int K) {
    __shared__ float As[16][65];
    __shared__ float Bs[16][65];
    int tid = threadIdx.x;
    int tx = tid & 15, ty = tid >> 4;
    int m0 = blockIdx.y * 64, n0 = blockIdx.x * 64;
    float acc[4][4] = {};
    for (int k0 = 0; k0 < K; k0 += 16) {
        {
            int r = tid >> 2;
            int c4 = (tid & 3) * 4;
            int m = m0 + r;
#pragma unroll
            for (int u = 0; u < 4; u++) {
                int k = k0 + c4 + u;
                As[c4 + u][r] = (m < M && k < K) ? A[(size_t)m * lda + k] : 0.f;
            }
        }
        if (BT) {
            int r = tid >> 2;
            int c4 = (tid & 3) * 4;
            int n = n0 + r;
#pragma unroll
            for (int u = 0; u < 4; u++) {
                int k = k0 + c4 + u;
                Bs[c4 + u][r] = (n < N && k < K) ? B[(size_t)n * ldb + k] : 0.f;
            }
        } else {
            int kk = tid >> 4;
            int nn4 = (tid & 15) * 4;
            int k = k0 + kk;
#pragma unroll
            for (int u = 0; u < 4; u++) {
                int n = n0 + nn4 + u;
                Bs[kk][nn4 + u] = (k < K && n < N) ? B[(size_t)k * ldb + n] : 0.f;
            }
        }
        __syncthreads();
#pragma unroll
        for (int k = 0; k < 16; k++) {
            float a[4], b[4];
#pragma unroll
            for (int i = 0; i < 4; i++) a[i] = As[k][ty + 16 * i];
#pragma unroll
            for (int j = 0; j < 4; j++) b[j] = Bs[k][tx + 16 * j];
#pragma unroll
            for (int i = 0; i < 4; i++)
#pragma unroll
                for (int j = 0; j < 4; j++) acc[i][j] += a[i] * b[j];
        }
        __syncthreads();
    }
#pragma unroll
    for (int i = 0; i < 4; i++) {
        int m = m0 + ty + 16 * i;
        if (m >= M) continue;
#pragma unroll
        for (int j = 0; j < 4; j++) {
            int n = n0 + tx + 16 * j;
            if (n < N) C[(size_t)m * ldc + n] = acc[i][j];
        }
    }
}

// ---------------- per-row dot with vector (474-row cases) ----------------
__global__ void k_dotv(const float* __restrict__ mat, const float* __restrict__ vec,
                       float* __restrict__ out, int M, int F) {
    int w = (blockIdx.x * blockDim.x + threadIdx.x) >> 6;
    int lane = threadIdx.x & 63;
    if (w >= M) return;
    const float* r = mat + (size_t)w * F;
    float s = 0.f;
    for (int j = lane; j < F; j += 64) s += r[j] * vec[j];
#pragma unroll
    for (int o = 32; o > 0; o >>= 1) s += __shfl_down(s, o);
    if (lane == 0) out[w] = s;
}

// ---------------- CSR build ----------------
__global__ void k_hist(const int* __restrict__ tgt_el, const int* __restrict__ nhop,
                       int* __restrict__ deg) {
    int e = blockIdx.x * blockDim.x + threadIdx.x;
    if (e >= NE) return;
    int t = (e < E0) ? tgt_el[e] : nhop[(size_t)(e - E0) * 4 + 3];
    atomicAdd(&deg[t], 1);
}

__global__ void k_scan1(const int* __restrict__ deg, int* __restrict__ local,
                        int* __restrict__ bsums, int n) {
    int i = blockIdx.x * 256 + threadIdx.x;
    int v = (i < n) ? deg[i] : 0;
    int lane = threadIdx.x & 63;
    int wv = threadIdx.x >> 6;
    int x = v;
#pragma unroll
    for (int o = 1; o < 64; o <<= 1) {
        int t = __shfl_up(x, o);
        if (lane >= o) x += t;
    }
    __shared__ int wtot[4];
    if (lane == 63) wtot[wv] = x;
    __syncthreads();
    int add = 0;
    for (int k = 0; k < wv; k++) add += wtot[k];
    if (i < n) local[i] = add + x - v;
    if (threadIdx.x == 255) bsums[blockIdx.x] = add + x;
}

__global__ void k_scan2(int* __restrict__ bsums, int nb) {
    int tid = threadIdx.x;
    int v = (tid < nb) ? bsums[tid] : 0;
    int lane = tid & 63, wv = tid >> 6;
    int x = v;
#pragma unroll
    for (int o = 1; o < 64; o <<= 1) {
        int t = __shfl_up(x, o);
        if (lane >= o) x += t;
    }
    __shared__ int wtot[4];
    if (lane == 63) wtot[wv] = x;
    __syncthreads();
    int add = 0;
    for (int k = 0; k < wv; k++) add += wtot[k];
    __syncthreads();
    if (tid < nb) bsums[tid] = add + x - v;
    if (tid == 255) bsums[nb] = add + x;
}

__global__ void k_scan3(const int* __restrict__ local, const int* __restrict__ bsums,
                        int* __restrict__ rowptr, int* __restrict__ cursor, int n, int nb) {
    int i = blockIdx.x * 256 + threadIdx.x;
    if (i < n) {
        int v = local[i] + bsums[blockIdx.x];
        rowptr[i] = v;
        cursor[i] = v;
    } else if (i == n) {
        rowptr[n] = bsums[nb];
    }
}

// scatter edge payloads into CSR order
__global__ void k_scatter(const int* __restrict__ tgt_el, const int* __restrict__ src_el,
                          const int* __restrict__ etype, const int* __restrict__ nhop,
                          int* __restrict__ cursor,
                          int* __restrict__ tgts, int* __restrict__ srcs,
                          int2* __restrict__ relpk) {
    int e = blockIdx.x * blockDim.x + threadIdx.x;
    if (e >= NE) return;
    int t, s, r1, r2;
    if (e < E0) {
        t = tgt_el[e]; s = src_el[e]; r1 = etype[e]; r2 = -1;
    } else {
        const int* nh = nhop + (size_t)(e - E0) * 4;
        t = nh[3]; s = nh[0]; r1 = nh[1]; r2 = nh[2];
    }
    int p = atomicAdd(&cursor[t], 1);
    tgts[p] = t; srcs[p] = s;
    relpk[p] = make_int2(r1, r2);
}

// ---------------- per-edge attention scalars (CSR-position order) ----------------
__global__ void k_edge1(const int* __restrict__ tgts, const int* __restrict__ srcs,
                        const int2* __restrict__ relpk,
                        const unsigned short* __restrict__ Pcat,
                        const float* __restrict__ dR10, const float* __restrict__ dR11,
                        float2* __restrict__ wpair) {
    int p = blockIdx.x * blockDim.x + threadIdx.x;
    if (p >= NE) return;
    int t = tgts[p], s = srcs[p];
    int2 rp = relpk[p];
    float dr0 = dR10[rp.x], dr1 = dR11[rp.x];
    if (rp.y >= 0) { dr0 += dR10[rp.y]; dr1 += dR11[rp.y]; }
    uint2 td = *(const uint2*)(Pcat + (size_t)t * LD1 + 600);   // (u_t0,u_s0),(u_t1,u_s1)
    uint2 sd = *(const uint2*)(Pcat + (size_t)s * LD1 + 600);
    float p0 = bflo(td.x) + bfhi(sd.x) + dr0;
    float p1 = bflo(td.y) + bfhi(sd.y) + dr1;
    p0 = (p0 >= 0.f) ? p0 : LRALPHA * p0;
    p1 = (p1 >= 0.f) ? p1 : LRALPHA * p1;
    wpair[p] = make_float2(expf(-p0), expf(-p1));
}

__global__ void k_edge2(const int* __restrict__ tgts, const int* __restrict__ srcs,
                        const int2* __restrict__ relpk,
                        const unsigned short* __restrict__ Qcat,
                        const float* __restrict__ dR2, float* __restrict__ w2) {
    int p = blockIdx.x * blockDim.x + threadIdx.x;
    if (p >= NE) return;
    int t = tgts[p], s = srcs[p];
    int2 rp = relpk[p];
    float dr = dR2[rp.x];
    if (rp.y >= 0) dr += dR2[rp.y];
    uint32_t tq = *(const uint32_t*)(Qcat + (size_t)t * LD2 + 400);  // (dqt, dqs)
    uint32_t sq = *(const uint32_t*)(Qcat + (size_t)s * LD2 + 400);
    float pp = bflo(tq) + bfhi(sq) + dr;
    pp = (pp >= 0.f) ? pp : LRALPHA * pp;
    w2[p] = expf(-pp);
}

// ---------------- node aggregation layer 1 (wave/node) -> x bf16 K-interleaved --------------
__global__ void k_node1(const int* __restrict__ rowptr, const int* __restrict__ srcs,
                        const int2* __restrict__ relpk, const float2* __restrict__ wpair,
                        const unsigned short* __restrict__ Pcat,
                        const float* __restrict__ R1i,
                        unsigned short* __restrict__ x) {
    int node = (blockIdx.x * blockDim.x + threadIdx.x) >> 6;
    int lane = threadIdx.x & 63;
    if (node >= N_NODES) return;
    int f0 = lane, f1 = lane + 64;
    bool v1 = (f1 < 100);
    float b00 = 0, b01 = 0, b10 = 0, b11 = 0, rs0 = 0, rs1 = 0;
    int beg = rowptr[node], end = rowptr[node + 1];
    for (int p = beg; p < end; p++) {
        int s = srcs[p];
        int2 rp = relpk[p];
        float2 w = wpair[p];
        const float2* r1a = (const float2*)(R1i + (size_t)rp.x * 200);
        float2 ra0 = r1a[f0];
        float2 ra1 = v1 ? r1a[f1] : make_float2(0.f, 0.f);
        if (rp.y >= 0) {
            const float2* r1b = (const float2*)(R1i + (size_t)rp.y * 200);
            float2 t0 = r1b[f0];
            ra0.x += t0.x; ra0.y += t0.y;
            if (v1) { float2 t1 = r1b[f1]; ra1.x += t1.x; ra1.y += t1.y; }
        }
        const unsigned short* prow = Pcat + (size_t)s * LD1 + 200;
        uint32_t ps0 = *(const uint32_t*)(prow + 2 * f0);
        rs0 += w.x; rs1 += w.y;
        b00 += w.x * (bflo(ps0) + ra0.x);
        b01 += w.y * (bfhi(ps0) + ra0.y);
        if (v1) {
            uint32_t ps1 = *(const uint32_t*)(prow + 2 * f1);
            b10 += w.x * (bflo(ps1) + ra1.x);
            b11 += w.y * (bfhi(ps1) + ra1.y);
        }
    }
    float d0 = (rs0 == 0.f) ? 1e-12f : rs0;
    float d1 = (rs1 == 0.f) ? 1e-12f : rs1;
    const unsigned short* pn = Pcat + (size_t)node * LD1;
    unsigned short* xr = x + (size_t)node * KP2;
    {
        uint32_t pt = *(const uint32_t*)(pn + 2 * f0);
        float v = (b00 + rs0 * bflo(pt)) / d0;
        float u = (b01 + rs1 * bfhi(pt)) / d1;
        v = (v > 0.f) ? v : expm1f(v);
        u = (u > 0.f) ? u : expm1f(u);
        *(uint32_t*)(xr + 2 * f0) = (uint32_t)f2bf(v) | ((uint32_t)f2bf(u) << 16);
    }
    if (v1) {
        uint32_t pt = *(const uint32_t*)(pn + 2 * f1);
        float v = (b10 + rs0 * bflo(pt)) / d0;
        float u = (b11 + rs1 * bfhi(pt)) / d1;
        v = (v > 0.f) ? v : expm1f(v);
        u = (u > 0.f) ? u : expm1f(u);
        *(uint32_t*)(xr + 2 * f1) = (uint32_t)f2bf(v) | ((uint32_t)f2bf(u) << 16);
    }
    if (lane < (KP2 - 200) / 2) *(uint32_t*)(xr + 200 + 2 * lane) = 0;
}

// ---------------- node aggregation layer 2 + final fuse (wave/node) ----------------
__global__ void k_node2(const int* __restrict__ rowptr, const int* __restrict__ srcs,
                        const int2* __restrict__ relpk, const float* __restrict__ w2,
                        const unsigned short* __restrict__ Qcat,
                        const unsigned short* __restrict__ Pcat,
                        const float* __restrict__ R2, const float* __restrict__ mask,
                        float* __restrict__ out) {
    int node = (blockIdx.x * blockDim.x + threadIdx.x) >> 6;
    int lane = threadIdx.x & 63;
    if (node >= N_NODES) return;
    int q0 = lane, q1 = lane + 64;      // feature pairs (2q, 2q+1); 100 pairs
    bool v = (q1 < 100);
    float c00 = 0, c01 = 0, c10 = 0, c11 = 0, rs = 0;
    int beg = rowptr[node], end = rowptr[node + 1];
    for (int p = beg; p < end; p++) {
        int s = srcs[p];
        int2 rp = relpk[p];
        float W = w2[p];
        const float* r2r = R2 + (size_t)rp.x * 200;
        float2 ra = *(const float2*)(r2r + 2 * q0);
        float2 rb = v ? *(const float2*)(r2r + 2 * q1) : make_float2(0.f, 0.f);
        if (rp.y >= 0) {
            const float* r2b = R2 + (size_t)rp.y * 200;
            float2 t0 = *(const float2*)(r2b + 2 * q0);
            ra.x += t0.x; ra.y += t0.y;
            if (v) { float2 t1 = *(const float2*)(r2b + 2 * q1); rb.x += t1.x; rb.y += t1.y; }
        }
        const unsigned short* qsrow = Qcat + (size_t)s * LD2 + 200;
        uint32_t qa = *(const uint32_t*)(qsrow + 2 * q0);
        rs += W;
        c00 += W * (bflo(qa) + ra.x);
        c01 += W * (bfhi(qa) + ra.y);
        if (v) {
            uint32_t qb = *(const uint32_t*)(qsrow + 2 * q1);
            c10 += W * (bflo(qb) + rb.x);
            c11 += W * (bfhi(qb) + rb.y);
        }
    }
    float d = (rs == 0.f) ? 1e-12f : rs;
    const unsigned short* qt = Qcat + (size_t)node * LD2;
    const unsigned short* ew = Pcat + (size_t)node * LD1 + 400;
    float mk = mask[node];
    uint32_t t0 = *(const uint32_t*)(qt + 2 * q0);
    uint32_t e0 = *(const uint32_t*)(ew + 2 * q0);
    float val00 = bflo(e0) + mk * ((c00 + rs * bflo(t0)) / d);
    float val01 = bfhi(e0) + mk * ((c01 + rs * bfhi(t0)) / d);
    float val10 = 0.f, val11 = 0.f;
    if (v) {
        uint32_t t1 = *(const uint32_t*)(qt + 2 * q1);
        uint32_t e1 = *(const uint32_t*)(ew + 2 * q1);
        val10 = bflo(e1) + mk * ((c10 + rs * bflo(t1)) / d);
        val11 = bfhi(e1) + mk * ((c11 + rs * bfhi(t1)) / d);
    }
    float ss = val00 * val00 + val01 * val01 + val10 * val10 + val11 * val11;
#pragma unroll
    for (int o = 32; o > 0; o >>= 1) ss += __shfl_down(ss, o);
    ss = __shfl(ss, 0);
    float inv = 1.f / fmaxf(sqrtf(ss), 1e-12f);
    float* dst = out + (size_t)node * 200;
    *(float2*)(dst + 2 * q0) = make_float2(val00 * inv, val01 * inv);
    if (v) *(float2*)(dst + 2 * q1) = make_float2(val10 * inv, val11 * inv);
}

// ---------------- mask scatter ----------------
__global__ void k_mask(const int* __restrict__ batch, float* __restrict__ mask) {
    int i = blockIdx.x * blockDim.x + threadIdx.x;
    if (i < NB) mask[batch[(size_t)i * 3 + 2]] = 1.0f;
}

// ---------------- ortho losses: parallel partial reduction ----------------
__global__ void k_ortho_part(const float* __restrict__ att_a, const float* __restrict__ out_a,
                             float* __restrict__ accum) {
    float loc[9] = {0,0,0,0,0,0,0,0,0};
    int stride = gridDim.x * blockDim.x;
    for (int i = blockIdx.x * blockDim.x + threadIdx.x; i < 90000; i += stride) {
        int seg, li;
        const float* base;
        int L;
        if (i < 15000)      { seg = 0; li = i;          base = att_a;         L = 15000; }
        else if (i < 30000) { seg = 1; li = i - 15000;  base = att_a + 30000; L = 15000; }
        else                { seg = 2; li = i - 30000;  base = out_a;         L = 60000; }
        float a = base[li], b = base[L + li];
        loc[seg * 3 + 0] += a * a;
        loc[seg * 3 + 1] += b * b;
        loc[seg * 3 + 2] += a * b;
    }
    int lane = threadIdx.x & 63;
#pragma unroll
    for (int q = 0; q < 9; q++) {
        float s = loc[q];
#pragma unroll
        for (int o = 32; o > 0; o >>= 1) s += __shfl_down(s, o);
        if (lane == 0 && s != 0.f) atomicAdd(&accum[q], s);
    }
}

__global__ void k_ortho_fin(const float* __restrict__ accum, float* __restrict__ out_scalar) {
    if (threadIdx.x != 0 || blockIdx.x != 0) return;
    float total = 0.f;
#pragma unroll
    for (int m = 0; m < 3; m++) {
        float s0 = accum[m * 3 + 0], s1 = accum[m * 3 + 1], sc = accum[m * 3 + 2];
        float c = sc / (fmaxf(sqrtf(s0), 1e-12f) * fmaxf(sqrtf(s1), 1e-12f));
        total += 0.01f * 2.f * c * c;
    }
    out_scalar[0] = total;
}

// ---------------- launch ----------------
extern "C" void kernel_launch(void* const* d_in, const int* in_sizes, int n_in,
                              void* d_out, int out_size, void* d_ws, size_t ws_size,
                              hipStream_t stream) {
    const int* edge_list = (const int*)d_in[0];
    const int* edge_type = (const int*)d_in[1];
    const int* batch     = (const int*)d_in[2];
    const int* nhop      = (const int*)d_in[3];
    const float* ent_emb = (const float*)d_in[4];
    const float* rel_emb = (const float*)d_in[5];
    const float* W_ent   = (const float*)d_in[6];
    const float* W_rel   = (const float*)d_in[7];
    const float* att_a   = (const float*)d_in[8];
    const float* att_a2  = (const float*)d_in[9];
    const float* out_a   = (const float*)d_in[10];
    const float* out_a2  = (const float*)d_in[11];
    float* out = (float*)d_out;
    const int* tgt_el = edge_list;
    const int* src_el = edge_list + E0;

    char* ws = (char*)d_ws;
    size_t o = 0;
    auto alloc = [&](size_t nbytes) -> char* {
        char* p = ws + o;
        o += (nbytes + 255) & ~(size_t)255;
        return p;
    };
    unsigned short* ent_bf  = (unsigned short*)alloc((size_t)N_NODES * KP1 * 2);
    unsigned short* x_bf    = (unsigned short*)alloc((size_t)N_NODES * KP2 * 2);
    unsigned short* Pcat    = (unsigned short*)alloc((size_t)N_NODES * LD1 * 2);
    unsigned short* Qcat    = (unsigned short*)alloc((size_t)N_NODES * LD2 * 2);
    unsigned short* Wcat1   = (unsigned short*)alloc((size_t)NPAD1 * KP1 * 2);
    unsigned short* Wcat2   = (unsigned short*)alloc((size_t)NPAD2 * KP2 * 2);
    float* uvecs = (float*)alloc(800 * 4);
    float* R1i   = (float*)alloc(474u * 200 * 4);
    float* R2    = (float*)alloc(474u * 200 * 4);
    float* dR10  = (float*)alloc(474u * 4);
    float* dR11  = (float*)alloc(474u * 4);
    float* dR2   = (float*)alloc(474u * 4);
    float2* wpair = (float2*)alloc((size_t)NE * 8);
    float* w2    = (float*)alloc((size_t)NE * 4);
    int* rowptr  = (int*)alloc((N_NODES + 1) * 4);
    int* cursor  = (int*)alloc(N_NODES * 4);
    int* tgts    = (int*)alloc((size_t)NE * 4);
    int* srcs    = (int*)alloc((size_t)NE * 4);
    int2* relpk  = (int2*)alloc((size_t)NE * 8);
    float* mask  = (float*)alloc(N_NODES * 4);
    int* scanloc = (int*)alloc(N_NODES * 4);
    int* bsums   = (int*)alloc(260 * 4);
    float* oacc  = (float*)alloc(9 * 4);

    const int TPB = 256;
    int wave_blocks_40000 = (N_NODES * 64 + TPB - 1) / TPB;   // 10000
    int wave_blocks_474   = (N_RELS * 64 + TPB - 1) / TPB;    // 119
    int edge_blocks       = (NE + TPB - 1) / TPB;
    int scan_blocks       = (N_NODES + 255) / 256;            // 157

    hipMemsetAsync(cursor, 0, N_NODES * 4, stream);
    hipMemsetAsync(mask, 0, N_NODES * 4, stream);
    hipMemsetAsync(oacc, 0, 9 * 4, stream);

    // 1) normalize entities -> bf16 padded
    k_l2norm_bf16<<<wave_blocks_40000, TPB, 0, stream>>>(ent_emb, ent_bf);

    // 2) CSR by target, payloads in CSR order
    k_hist<<<edge_blocks, TPB, 0, stream>>>(tgt_el, nhop, cursor);
    k_scan1<<<scan_blocks, 256, 0, stream>>>(cursor, scanloc, bsums, N_NODES);
    k_scan2<<<1, 256, 0, stream>>>(bsums, scan_blocks);
    k_scan3<<<(N_NODES + 1 + 255) / 256, 256, 0, stream>>>(scanloc, bsums, rowptr, cursor, N_NODES, scan_blocks);
    k_scatter<<<edge_blocks, TPB, 0, stream>>>(tgt_el, src_el, edge_type, nhop, cursor,
                                               tgts, srcs, relpk);

    // 3) pack fused B matrices (zero-padded rows)
    k_uvec<<<4, 256, 0, stream>>>(att_a, att_a2, out_a, out_a2, uvecs);
    k_pack1<<<(NPAD1 * KP1 + 255) / 256, 256, 0, stream>>>(att_a, W_ent, uvecs, Wcat1);
    k_pack2<<<(NPAD2 * KP2 + 255) / 256, 256, 0, stream>>>(out_a, uvecs, Wcat2);

    // 4) fused layer-1 GEMM (MFMA bf16, N-split x2, chunk-preloaded B)
    k_gemm_mfma<KP1><<<dim3(625, 2), 256, 0, stream>>>(ent_bf, Wcat1, Pcat, LD1, 608, 5);

    // 5) relation-side projections (interleaved) + dots
    k_relproj1<<<wave_blocks_474, TPB, 0, stream>>>(rel_emb, att_a, R1i);
    k_dR1<<<wave_blocks_474, TPB, 0, stream>>>(R1i, att_a2, dR10, dR11);

    // 6) layer-1 edge weights + aggregation -> x_bf (K-interleaved)
    k_edge1<<<edge_blocks, TPB, 0, stream>>>(tgts, srcs, relpk, Pcat, dR10, dR11, wpair);
    k_node1<<<wave_blocks_40000, TPB, 0, stream>>>(rowptr, srcs, relpk, wpair, Pcat, R1i, x_bf);

    // 7) fused layer-2 GEMM (MFMA bf16, N-split x2, chunk-preloaded B)
    k_gemm_mfma<KP2><<<dim3(625, 2), 256, 0, stream>>>(x_bf, Wcat2, Qcat, LD2, 416, 4);

    // 8) out_relation_1 = rel_emb @ W_rel -> d_out; R2 = out_rel1 @ a_r2^T; dR2
    dim3 gor((200 + 63) / 64, (N_RELS + 63) / 64);
    k_mm<false><<<gor, TPB, 0, stream>>>(rel_emb, 100, W_rel, 200, out + 8000000, 200, N_RELS, 200, 100);
    k_mm<true><<<gor, TPB, 0, stream>>>(out + 8000000, 200, out_a + 400, 600, R2, 200, N_RELS, 200, 200);
    k_dotv<<<wave_blocks_474, TPB, 0, stream>>>(R2, out_a2, dR2, N_RELS, 200);

    // 9) layer-2 edge weights, mask, aggregation + final fuse
    k_edge2<<<edge_blocks, TPB, 0, stream>>>(tgts, srcs, relpk, Qcat, dR2, w2);
    k_mask<<<(NB + TPB - 1) / TPB, TPB, 0, stream>>>(batch, mask);
    k_node2<<<wave_blocks_40000, TPB, 0, stream>>>(rowptr, srcs, relpk, w2, Qcat, Pcat, R2, mask, out);

    // 10) ortho scalar (parallel)
    k_ortho_part<<<128, 256, 0, stream>>>(att_a, out_a, oacc);
    k_ortho_fin<<<1, 64, 0, stream>>>(oacc, out + 8094800);
}

// Round 9
// 436.181 us; speedup vs baseline: 1.1936x; 1.1802x over previous
//
#include <hip/hip_runtime.h>
#include <cstdint>
#include <cstddef>
#include <math.h>

#define N_NODES 40000
#define N_RELS  474
#define E0      100000
#define EN      30000
#define NE      130000
#define NB      8192
#define LRALPHA 0.2f

#define KP1 128   // padded K for layer-1 GEMM (K=100)
#define KP2 256   // padded K for layer-2 GEMM (K=200)
// Pcat cols: [0:200) Pt interleaved (2f=h0,2f+1=h1) | [200:400) Ps interleaved |
//            [400:600) entW natural | [600:604) dots (u_t0,u_s0,u_t1,u_s1) | pad
#define LD1 608
// Qcat cols: [0:200) Qt | [200:400) Qs | 400 dqt | 401 dqs | pad
#define LD2 416
#define NPAD1 640   // Wcat1 rows (zero-padded past 604)
#define NPAD2 448   // Wcat2 rows (zero-padded past 402)

typedef __attribute__((ext_vector_type(8))) short short8;
typedef __attribute__((ext_vector_type(4))) float floatx4;

static __device__ __forceinline__ unsigned short f2bf(float f) {
    union { float f; uint32_t u; } v; v.f = f;
    uint32_t r = v.u + 0x7fff + ((v.u >> 16) & 1);
    return (unsigned short)(r >> 16);
}
static __device__ __forceinline__ float bf2f(unsigned short h) {
    union { uint32_t u; float f; } v; v.u = ((uint32_t)h) << 16;
    return v.f;
}
static __device__ __forceinline__ float bflo(uint32_t u) { return bf2f((unsigned short)(u & 0xffff)); }
static __device__ __forceinline__ float bfhi(uint32_t u) { return bf2f((unsigned short)(u >> 16)); }

// ---------------- l2norm rows of ent -> bf16 padded [40000][KP1] ----------------
__global__ void k_l2norm_bf16(const float* __restrict__ in, unsigned short* __restrict__ out) {
    int w = (blockIdx.x * blockDim.x + threadIdx.x) >> 6;
    int lane = threadIdx.x & 63;
    if (w >= N_NODES) return;
    const float* r = in + (size_t)w * 100;
    float v0 = r[lane];
    int j1 = lane + 64;
    float v1 = (j1 < 100) ? r[j1] : 0.f;
    float ss = v0 * v0 + v1 * v1;
#pragma unroll
    for (int o = 32; o > 0; o >>= 1) ss += __shfl_down(ss, o);
    ss = __shfl(ss, 0);
    float inv = 1.f / fmaxf(sqrtf(ss), 1e-12f);
    unsigned short* dst = out + (size_t)w * KP1;
    dst[lane] = f2bf(v0 * inv);
    dst[j1] = (j1 < 100) ? f2bf(v1 * inv) : (unsigned short)0;
}

// ---------------- bf16 MFMA GEMM: fragment-ordered B (coalesced), 4-way ILP ----------------
// A: [M][KP] bf16 row-major. B: fragment order — frag(tile,ks) at ((tile*KSTEPS+ks)*64+lane)*8.
// C: [M][ldc] bf16. grid: (M/64, nsplits); each y handles gPerSplit groups of 64 cols.
template <int KP>
__global__ __launch_bounds__(256) void k_gemm_mfma(const unsigned short* __restrict__ A,
                                                   const unsigned short* __restrict__ B,
                                                   unsigned short* __restrict__ C,
                                                   int ldc, int N, int gPerSplit) {
    constexpr int KSTEPS = KP / 32;          // 4 (L1) or 8 (L2)
    constexpr int KCH = KSTEPS / 4;          // chunks of 4 ksteps
    __shared__ unsigned short cbuf[4][16][64];   // 8 KB, wave-private slabs
    int wave = threadIdx.x >> 6;
    int lane = threadIdx.x & 63;
    int quad = lane >> 4;
    int l16 = lane & 15;
    int m0 = blockIdx.x * 64 + wave * 16;
    // this wave's 16-row A strip (full K) in registers — loaded once
    short8 afrag[KSTEPS];
    const unsigned short* arow = A + (size_t)(m0 + l16) * KP + quad * 8;
#pragma unroll
    for (int ks = 0; ks < KSTEPS; ks++)
        afrag[ks] = *(const short8*)(arow + ks * 32);

    int Gtot = (N + 63) >> 6;
    int g0 = blockIdx.y * gPerSplit;
    int g1 = g0 + gPerSplit;
    if (g1 > Gtot) g1 = Gtot;
    for (int g = g0; g < g1; g++) {
        int nb = g << 6;
        // group's B: contiguous block of 4 tiles * KSTEPS fragments, each 512 shorts
        const unsigned short* bgrp = B + (((size_t)(g << 2) * KSTEPS) << 9) + (lane << 3);
        floatx4 acc[4];
#pragma unroll
        for (int t = 0; t < 4; t++) acc[t] = (floatx4){0.f, 0.f, 0.f, 0.f};
#pragma unroll
        for (int ch = 0; ch < KCH; ch++) {
            short8 bf[4][4];
#pragma unroll
            for (int t = 0; t < 4; t++)
#pragma unroll
                for (int k = 0; k < 4; k++)
                    bf[t][k] = *(const short8*)(bgrp + ((size_t)(t * KSTEPS + ch * 4 + k) << 9));
#pragma unroll
            for (int k = 0; k < 4; k++)
#pragma unroll
                for (int t = 0; t < 4; t++)
                    acc[t] = __builtin_amdgcn_mfma_f32_16x16x32_bf16(afrag[ch * 4 + k], bf[t][k], acc[t], 0, 0, 0);
        }
        // C/D layout: col = l16, row = quad*4 + reg -> stage into LDS
        int r0 = quad * 4;
#pragma unroll
        for (int t = 0; t < 4; t++)
#pragma unroll
            for (int i = 0; i < 4; i++)
                cbuf[wave][r0 + i][t * 16 + l16] = f2bf(acc[t][i]);
        // coalesced flush, 16B/lane (same-wave LDS ops are in-order; no barrier)
        int colsA = N - nb; if (colsA > 64) colsA = 64;
        int cols8 = colsA >> 3;              // 8 (full) or 4 (32-col tail)
        int sh = (colsA >= 64) ? 3 : 2;
        int nchunks = cols8 << 4;            // 16 rows
        for (int c = lane; c < nchunks; c += 64) {
            int row = c >> sh;
            int col8 = (c & (cols8 - 1)) << 3;
            *(uint4*)(C + (size_t)(m0 + row) * ldc + nb + col8) =
                *(const uint4*)&cbuf[wave][row][col8];
        }
    }
}

// ---------------- u-vectors: u = a_part^T @ a2 ----------------
// uvecs: [0:100)=u_t0 [100:200)=u_s0 [200:300)=u_t1 [300:400)=u_s1 [400:600)=u_t2 [600:800)=u_s2
__global__ void k_uvec(const float* __restrict__ att_a, const float* __restrict__ att_a2,
                       const float* __restrict__ out_a, const float* __restrict__ out_a2,
                       float* __restrict__ uvecs) {
    int tid = blockIdx.x * blockDim.x + threadIdx.x;
    if (tid >= 800) return;
    float s = 0.f;
    if (tid < 400) {
        int v = tid / 100, k = tid % 100;
        int head = v >> 1, part = v & 1;
        const float* base = att_a + head * 30000 + part * 100 + k;
        const float* a2 = att_a2 + head * 100;
        for (int n = 0; n < 100; n++) s += a2[n] * base[n * 300];
        uvecs[tid] = s;
    } else {
        int v = (tid - 400) / 200, k = (tid - 400) % 200;
        const float* base = out_a + v * 200 + k;
        for (int n = 0; n < 200; n++) s += out_a2[n] * base[n * 600];
        uvecs[400 + v * 200 + k] = s;
    }
}

// ---------------- pack layer-1 B matrix -> FRAGMENT ORDER [NPAD1/16 tiles][KSTEPS=4][64][8] --
__global__ void k_pack1(const float* __restrict__ att_a, const float* __restrict__ W_ent,
                        const float* __restrict__ uvecs, unsigned short* __restrict__ W) {
    int idx = blockIdx.x * blockDim.x + threadIdx.x;
    if (idx >= NPAD1 * KP1) return;
    int j = idx & 7;
    int lane = (idx >> 3) & 63;
    int u = idx >> 9;
    int ks = u & 3;           // KSTEPS1 = 4
    int t = u >> 2;
    int r = t * 16 + (lane & 15);          // logical B row
    int k = ks * 32 + (lane >> 4) * 8 + j; // logical col
    float val = 0.f;
    if (k < 100) {
        if (r < 200) {                       // Pt interleaved: row 2i+h = a_t head h row i
            int i = r >> 1, h = r & 1;
            val = att_a[h * 30000 + i * 300 + k];
        } else if (r < 400) {                // Ps interleaved
            int rr = r - 200, i = rr >> 1, h = rr & 1;
            val = att_a[h * 30000 + i * 300 + 100 + k];
        } else if (r < 600) {
            val = W_ent[k * 200 + (r - 400)];
        } else if (r < 604) {
            val = uvecs[(r - 600) * 100 + k];
        }
    }
    W[idx] = f2bf(val);
}

// ---------------- pack layer-2 B matrix -> FRAGMENT ORDER (x is K-interleaved) ---------------
__global__ void k_pack2(const float* __restrict__ out_a, const float* __restrict__ uvecs,
                        unsigned short* __restrict__ W) {
    int idx = blockIdx.x * blockDim.x + threadIdx.x;
    if (idx >= NPAD2 * KP2) return;
    int j = idx & 7;
    int lane = (idx >> 3) & 63;
    int u = idx >> 9;
    int ks = u & 7;           // KSTEPS2 = 8
    int t = u >> 3;
    int r = t * 16 + (lane & 15);
    int k = ks * 32 + (lane >> 4) * 8 + j;
    float val = 0.f;
    if (k < 200) {
        int klog = (k & 1) * 100 + (k >> 1);   // phys 2f=h0 feat f, 2f+1=h1 feat f
        if (r < 200)       val = out_a[r * 600 + klog];
        else if (r < 400)  val = out_a[(r - 200) * 600 + 200 + klog];
        else if (r == 400) val = uvecs[400 + klog];
        else if (r == 401) val = uvecs[600 + klog];
    }
    W[idx] = f2bf(val);
}

// ---------------- R1 interleaved projection: R1i[474][200], (R10[f],R11[f]) pairs ------------
__global__ void k_relproj1(const float* __restrict__ rel_emb, const float* __restrict__ att_a,
                           float* __restrict__ R1i) {
    int w = (blockIdx.x * blockDim.x + threadIdx.x) >> 6;
    int lane = threadIdx.x & 63;
    if (w >= N_RELS) return;
    const float* re = rel_emb + (size_t)w * 100;
    float2* dst = (float2*)(R1i + (size_t)w * 200);
    for (int f = lane; f < 100; f += 64) {
        const float* a0 = att_a + f * 300 + 200;
        const float* a1 = att_a + 30000 + f * 300 + 200;
        float s0 = 0.f, s1 = 0.f;
        for (int k = 0; k < 100; k++) {
            float rk = re[k];
            s0 += rk * a0[k];
            s1 += rk * a1[k];
        }
        dst[f] = make_float2(s0, s1);
    }
}

// dR1h[r] = R1h[r] . a2_h
__global__ void k_dR1(const float* __restrict__ R1i, const float* __restrict__ att_a2,
                      float* __restrict__ dR10, float* __restrict__ dR11) {
    int w = (blockIdx.x * blockDim.x + threadIdx.x) >> 6;
    int lane = threadIdx.x & 63;
    if (w >= N_RELS) return;
    const float2* row = (const float2*)(R1i + (size_t)w * 200);
    float s0 = 0.f, s1 = 0.f;
    for (int f = lane; f < 100; f += 64) {
        float2 v = row[f];
        s0 += v.x * att_a2[f];
        s1 += v.y * att_a2[100 + f];
    }
#pragma unroll
    for (int o = 32; o > 0; o >>= 1) {
        s0 += __shfl_down(s0, o);
        s1 += __shfl_down(s1, o);
    }
    if (lane == 0) { dR10[w] = s0; dR11[w] = s1; }
}

// ---------------- generic tiled fp32 matmul (474-row cases only) ----------------
template <bool BT>
__global__ __launch_bounds__(256) void k_mm(const float* __restrict__ A, int lda,
                                            const float* __restrict__ B, int ldb,
                                            float* __restrict__ C, int ldc,
                                            int M, int N, int K) {
    __shared__ float As[16][65];
    __shared__ float Bs[16][65];
    int tid = threadIdx.x;
    int tx = tid & 15, ty = tid >> 4;
    int m0 = blockIdx.y * 64, n0 = blockIdx.x * 64;
    float acc[4][4] = {};
    for (int k0 = 0; k0 < K; k0 += 16) {
        {
            int r = tid >> 2;
            int c4 = (tid & 3) * 4;
            int m = m0 + r;
#pragma unroll
            for (int u = 0; u < 4; u++) {
                int k = k0 + c4 + u;
                As[c4 + u][r] = (m < M && k < K) ? A[(size_t)m * lda + k] : 0.f;
            }
        }
        if (BT) {
            int r = tid >> 2;
            int c4 = (tid & 3) * 4;
            int n = n0 + r;
#pragma unroll
            for (int u = 0; u < 4; u++) {
                int k = k0 + c4 + u;
                Bs[c4 + u][r] = (n < N && k < K) ? B[(size_t)n * ldb + k] : 0.f;
            }
        } else {
            int kk = tid >> 4;
            int nn4 = (tid & 15) * 4;
            int k = k0 + kk;
#pragma unroll
            for (int u = 0; u < 4; u++) {
                int n = n0 + nn4 + u;
                Bs[kk][nn4 + u] = (k < K && n < N) ? B[(size_t)k * ldb + n] : 0.f;
            }
        }
        __syncthreads();
#pragma unroll
        for (int k = 0; k < 16; k++) {
            float a[4], b[4];
#pragma unroll
            for (int i = 0; i < 4; i++) a[i] = As[k][ty + 16 * i];
#pragma unroll
            for (int j = 0; j < 4; j++) b[j] = Bs[k][tx + 16 * j];
#pragma unroll
            for (int i = 0; i < 4; i++)
#pragma unroll
                for (int j = 0; j < 4; j++) acc[i][j] += a[i] * b[j];
        }
        __syncthreads();
    }
#pragma unroll
    for (int i = 0; i < 4; i++) {
        int m = m0 + ty + 16 * i;
        if (m >= M) continue;
#pragma unroll
        for (int j = 0; j < 4; j++) {
            int n = n0 + tx + 16 * j;
            if (n < N) C[(size_t)m * ldc + n] = acc[i][j];
        }
    }
}

// ---------------- per-row dot with vector (474-row cases) ----------------
__global__ void k_dotv(const float* __restrict__ mat, const float* __restrict__ vec,
                       float* __restrict__ out, int M, int F) {
    int w = (blockIdx.x * blockDim.x + threadIdx.x) >> 6;
    int lane = threadIdx.x & 63;
    if (w >= M) return;
    const float* r = mat + (size_t)w * F;
    float s = 0.f;
    for (int j = lane; j < F; j += 64) s += r[j] * vec[j];
#pragma unroll
    for (int o = 32; o > 0; o >>= 1) s += __shfl_down(s, o);
    if (lane == 0) out[w] = s;
}

// ---------------- CSR build ----------------
__global__ void k_hist(const int* __restrict__ tgt_el, const int* __restrict__ nhop,
                       int* __restrict__ deg) {
    int e = blockIdx.x * blockDim.x + threadIdx.x;
    if (e >= NE) return;
    int t = (e < E0) ? tgt_el[e] : nhop[(size_t)(e - E0) * 4 + 3];
    atomicAdd(&deg[t], 1);
}

__global__ void k_scan1(const int* __restrict__ deg, int* __restrict__ local,
                        int* __restrict__ bsums, int n) {
    int i = blockIdx.x * 256 + threadIdx.x;
    int v = (i < n) ? deg[i] : 0;
    int lane = threadIdx.x & 63;
    int wv = threadIdx.x >> 6;
    int x = v;
#pragma unroll
    for (int o = 1; o < 64; o <<= 1) {
        int t = __shfl_up(x, o);
        if (lane >= o) x += t;
    }
    __shared__ int wtot[4];
    if (lane == 63) wtot[wv] = x;
    __syncthreads();
    int add = 0;
    for (int k = 0; k < wv; k++) add += wtot[k];
    if (i < n) local[i] = add + x - v;
    if (threadIdx.x == 255) bsums[blockIdx.x] = add + x;
}

__global__ void k_scan2(int* __restrict__ bsums, int nb) {
    int tid = threadIdx.x;
    int v = (tid < nb) ? bsums[tid] : 0;
    int lane = tid & 63, wv = tid >> 6;
    int x = v;
#pragma unroll
    for (int o = 1; o < 64; o <<= 1) {
        int t = __shfl_up(x, o);
        if (lane >= o) x += t;
    }
    __shared__ int wtot[4];
    if (lane == 63) wtot[wv] = x;
    __syncthreads();
    int add = 0;
    for (int k = 0; k < wv; k++) add += wtot[k];
    __syncthreads();
    if (tid < nb) bsums[tid] = add + x - v;
    if (tid == 255) bsums[nb] = add + x;
}

__global__ void k_scan3(const int* __restrict__ local, const int* __restrict__ bsums,
                        int* __restrict__ rowptr, int* __restrict__ cursor, int n, int nb) {
    int i = blockIdx.x * 256 + threadIdx.x;
    if (i < n) {
        int v = local[i] + bsums[blockIdx.x];
        rowptr[i] = v;
        cursor[i] = v;
    } else if (i == n) {
        rowptr[n] = bsums[nb];
    }
}

// scatter edge payloads into CSR order
__global__ void k_scatter(const int* __restrict__ tgt_el, const int* __restrict__ src_el,
                          const int* __restrict__ etype, const int* __restrict__ nhop,
                          int* __restrict__ cursor,
                          int* __restrict__ tgts, int* __restrict__ srcs,
                          int2* __restrict__ relpk) {
    int e = blockIdx.x * blockDim.x + threadIdx.x;
    if (e >= NE) return;
    int t, s, r1, r2;
    if (e < E0) {
        t = tgt_el[e]; s = src_el[e]; r1 = etype[e]; r2 = -1;
    } else {
        const int* nh = nhop + (size_t)(e - E0) * 4;
        t = nh[3]; s = nh[0]; r1 = nh[1]; r2 = nh[2];
    }
    int p = atomicAdd(&cursor[t], 1);
    tgts[p] = t; srcs[p] = s;
    relpk[p] = make_int2(r1, r2);
}

// ---------------- per-edge attention scalars (CSR-position order) ----------------
__global__ void k_edge1(const int* __restrict__ tgts, const int* __restrict__ srcs,
                        const int2* __restrict__ relpk,
                        const unsigned short* __restrict__ Pcat,
                        const float* __restrict__ dR10, const float* __restrict__ dR11,
                        float2* __restrict__ wpair) {
    int p = blockIdx.x * blockDim.x + threadIdx.x;
    if (p >= NE) return;
    int t = tgts[p], s = srcs[p];
    int2 rp = relpk[p];
    float dr0 = dR10[rp.x], dr1 = dR11[rp.x];
    if (rp.y >= 0) { dr0 += dR10[rp.y]; dr1 += dR11[rp.y]; }
    uint2 td = *(const uint2*)(Pcat + (size_t)t * LD1 + 600);   // (u_t0,u_s0),(u_t1,u_s1)
    uint2 sd = *(const uint2*)(Pcat + (size_t)s * LD1 + 600);
    float p0 = bflo(td.x) + bfhi(sd.x) + dr0;
    float p1 = bflo(td.y) + bfhi(sd.y) + dr1;
    p0 = (p0 >= 0.f) ? p0 : LRALPHA * p0;
    p1 = (p1 >= 0.f) ? p1 : LRALPHA * p1;
    wpair[p] = make_float2(expf(-p0), expf(-p1));
}

__global__ void k_edge2(const int* __restrict__ tgts, const int* __restrict__ srcs,
                        const int2* __restrict__ relpk,
                        const unsigned short* __restrict__ Qcat,
                        const float* __restrict__ dR2, float* __restrict__ w2) {
    int p = blockIdx.x * blockDim.x + threadIdx.x;
    if (p >= NE) return;
    int t = tgts[p], s = srcs[p];
    int2 rp = relpk[p];
    float dr = dR2[rp.x];
    if (rp.y >= 0) dr += dR2[rp.y];
    uint32_t tq = *(const uint32_t*)(Qcat + (size_t)t * LD2 + 400);  // (dqt, dqs)
    uint32_t sq = *(const uint32_t*)(Qcat + (size_t)s * LD2 + 400);
    float pp = bflo(tq) + bfhi(sq) + dr;
    pp = (pp >= 0.f) ? pp : LRALPHA * pp;
    w2[p] = expf(-pp);
}

// ---------------- node aggregation layer 1 (wave/node) -> x bf16 K-interleaved --------------
__global__ void k_node1(const int* __restrict__ rowptr, const int* __restrict__ srcs,
                        const int2* __restrict__ relpk, const float2* __restrict__ wpair,
                        const unsigned short* __restrict__ Pcat,
                        const float* __restrict__ R1i,
                        unsigned short* __restrict__ x) {
    int node = (blockIdx.x * blockDim.x + threadIdx.x) >> 6;
    int lane = threadIdx.x & 63;
    if (node >= N_NODES) return;
    int f0 = lane, f1 = lane + 64;
    bool v1 = (f1 < 100);
    float b00 = 0, b01 = 0, b10 = 0, b11 = 0, rs0 = 0, rs1 = 0;
    int beg = rowptr[node], end = rowptr[node + 1];
    for (int p = beg; p < end; p++) {
        int s = srcs[p];
        int2 rp = relpk[p];
        float2 w = wpair[p];
        const float2* r1a = (const float2*)(R1i + (size_t)rp.x * 200);
        float2 ra0 = r1a[f0];
        float2 ra1 = v1 ? r1a[f1] : make_float2(0.f, 0.f);
        if (rp.y >= 0) {
            const float2* r1b = (const float2*)(R1i + (size_t)rp.y * 200);
            float2 t0 = r1b[f0];
            ra0.x += t0.x; ra0.y += t0.y;
            if (v1) { float2 t1 = r1b[f1]; ra1.x += t1.x; ra1.y += t1.y; }
        }
        const unsigned short* prow = Pcat + (size_t)s * LD1 + 200;
        uint32_t ps0 = *(const uint32_t*)(prow + 2 * f0);
        rs0 += w.x; rs1 += w.y;
        b00 += w.x * (bflo(ps0) + ra0.x);
        b01 += w.y * (bfhi(ps0) + ra0.y);
        if (v1) {
            uint32_t ps1 = *(const uint32_t*)(prow + 2 * f1);
            b10 += w.x * (bflo(ps1) + ra1.x);
            b11 += w.y * (bfhi(ps1) + ra1.y);
        }
    }
    float d0 = (rs0 == 0.f) ? 1e-12f : rs0;
    float d1 = (rs1 == 0.f) ? 1e-12f : rs1;
    const unsigned short* pn = Pcat + (size_t)node * LD1;
    unsigned short* xr = x + (size_t)node * KP2;
    {
        uint32_t pt = *(const uint32_t*)(pn + 2 * f0);
        float v = (b00 + rs0 * bflo(pt)) / d0;
        float u = (b01 + rs1 * bfhi(pt)) / d1;
        v = (v > 0.f) ? v : expm1f(v);
        u = (u > 0.f) ? u : expm1f(u);
        *(uint32_t*)(xr + 2 * f0) = (uint32_t)f2bf(v) | ((uint32_t)f2bf(u) << 16);
    }
    if (v1) {
        uint32_t pt = *(const uint32_t*)(pn + 2 * f1);
        float v = (b10 + rs0 * bflo(pt)) / d0;
        float u = (b11 + rs1 * bfhi(pt)) / d1;
        v = (v > 0.f) ? v : expm1f(v);
        u = (u > 0.f) ? u : expm1f(u);
        *(uint32_t*)(xr + 2 * f1) = (uint32_t)f2bf(v) | ((uint32_t)f2bf(u) << 16);
    }
    if (lane < (KP2 - 200) / 2) *(uint32_t*)(xr + 200 + 2 * lane) = 0;
}

// ---------------- node aggregation layer 2 + final fuse (wave/node) ----------------
__global__ void k_node2(const int* __restrict__ rowptr, const int* __restrict__ srcs,
                        const int2* __restrict__ relpk, const float* __restrict__ w2,
                        const unsigned short* __restrict__ Qcat,
                        const unsigned short* __restrict__ Pcat,
                        const float* __restrict__ R2, const float* __restrict__ mask,
                        float* __restrict__ out) {
    int node = (blockIdx.x * blockDim.x + threadIdx.x) >> 6;
    int lane = threadIdx.x & 63;
    if (node >= N_NODES) return;
    int q0 = lane, q1 = lane + 64;      // feature pairs (2q, 2q+1); 100 pairs
    bool v = (q1 < 100);
    float c00 = 0, c01 = 0, c10 = 0, c11 = 0, rs = 0;
    int beg = rowptr[node], end = rowptr[node + 1];
    for (int p = beg; p < end; p++) {
        int s = srcs[p];
        int2 rp = relpk[p];
        float W = w2[p];
        const float* r2r = R2 + (size_t)rp.x * 200;
        float2 ra = *(const float2*)(r2r + 2 * q0);
        float2 rb = v ? *(const float2*)(r2r + 2 * q1) : make_float2(0.f, 0.f);
        if (rp.y >= 0) {
            const float* r2b = R2 + (size_t)rp.y * 200;
            float2 t0 = *(const float2*)(r2b + 2 * q0);
            ra.x += t0.x; ra.y += t0.y;
            if (v) { float2 t1 = *(const float2*)(r2b + 2 * q1); rb.x += t1.x; rb.y += t1.y; }
        }
        const unsigned short* qsrow = Qcat + (size_t)s * LD2 + 200;
        uint32_t qa = *(const uint32_t*)(qsrow + 2 * q0);
        rs += W;
        c00 += W * (bflo(qa) + ra.x);
        c01 += W * (bfhi(qa) + ra.y);
        if (v) {
            uint32_t qb = *(const uint32_t*)(qsrow + 2 * q1);
            c10 += W * (bflo(qb) + rb.x);
            c11 += W * (bfhi(qb) + rb.y);
        }
    }
    float d = (rs == 0.f) ? 1e-12f : rs;
    const unsigned short* qt = Qcat + (size_t)node * LD2;
    const unsigned short* ew = Pcat + (size_t)node * LD1 + 400;
    float mk = mask[node];
    uint32_t t0 = *(const uint32_t*)(qt + 2 * q0);
    uint32_t e0 = *(const uint32_t*)(ew + 2 * q0);
    float val00 = bflo(e0) + mk * ((c00 + rs * bflo(t0)) / d);
    float val01 = bfhi(e0) + mk * ((c01 + rs * bfhi(t0)) / d);
    float val10 = 0.f, val11 = 0.f;
    if (v) {
        uint32_t t1 = *(const uint32_t*)(qt + 2 * q1);
        uint32_t e1 = *(const uint32_t*)(ew + 2 * q1);
        val10 = bflo(e1) + mk * ((c10 + rs * bflo(t1)) / d);
        val11 = bfhi(e1) + mk * ((c11 + rs * bfhi(t1)) / d);
    }
    float ss = val00 * val00 + val01 * val01 + val10 * val10 + val11 * val11;
#pragma unroll
    for (int o = 32; o > 0; o >>= 1) ss += __shfl_down(ss, o);
    ss = __shfl(ss, 0);
    float inv = 1.f / fmaxf(sqrtf(ss), 1e-12f);
    float* dst = out + (size_t)node * 200;
    *(float2*)(dst + 2 * q0) = make_float2(val00 * inv, val01 * inv);
    if (v) *(float2*)(dst + 2 * q1) = make_float2(val10 * inv, val11 * inv);
}

// ---------------- mask scatter ----------------
__global__ void k_mask(const int* __restrict__ batch, float* __restrict__ mask) {
    int i = blockIdx.x * blockDim.x + threadIdx.x;
    if (i < NB) mask[batch[(size_t)i * 3 + 2]] = 1.0f;
}

// ---------------- ortho losses: parallel partial reduction ----------------
__global__ void k_ortho_part(const float* __restrict__ att_a, const float* __restrict__ out_a,
                             float* __restrict__ accum) {
    float loc[9] = {0,0,0,0,0,0,0,0,0};
    int stride = gridDim.x * blockDim.x;
    for (int i = blockIdx.x * blockDim.x + threadIdx.x; i < 90000; i += stride) {
        int seg, li;
        const float* base;
        int L;
        if (i < 15000)      { seg = 0; li = i;          base = att_a;         L = 15000; }
        else if (i < 30000) { seg = 1; li = i - 15000;  base = att_a + 30000; L = 15000; }
        else                { seg = 2; li = i - 30000;  base = out_a;         L = 60000; }
        float a = base[li], b = base[L + li];
        loc[seg * 3 + 0] += a * a;
        loc[seg * 3 + 1] += b * b;
        loc[seg * 3 + 2] += a * b;
    }
    int lane = threadIdx.x & 63;
#pragma unroll
    for (int q = 0; q < 9; q++) {
        float s = loc[q];
#pragma unroll
        for (int o = 32; o > 0; o >>= 1) s += __shfl_down(s, o);
        if (lane == 0 && s != 0.f) atomicAdd(&accum[q], s);
    }
}

__global__ void k_ortho_fin(const float* __restrict__ accum, float* __restrict__ out_scalar) {
    if (threadIdx.x != 0 || blockIdx.x != 0) return;
    float total = 0.f;
#pragma unroll
    for (int m = 0; m < 3; m++) {
        float s0 = accum[m * 3 + 0], s1 = accum[m * 3 + 1], sc = accum[m * 3 + 2];
        float c = sc / (fmaxf(sqrtf(s0), 1e-12f) * fmaxf(sqrtf(s1), 1e-12f));
        total += 0.01f * 2.f * c * c;
    }
    out_scalar[0] = total;
}

// ---------------- launch ----------------
extern "C" void kernel_launch(void* const* d_in, const int* in_sizes, int n_in,
                              void* d_out, int out_size, void* d_ws, size_t ws_size,
                              hipStream_t stream) {
    const int* edge_list = (const int*)d_in[0];
    const int* edge_type = (const int*)d_in[1];
    const int* batch     = (const int*)d_in[2];
    const int* nhop      = (const int*)d_in[3];
    const float* ent_emb = (const float*)d_in[4];
    const float* rel_emb = (const float*)d_in[5];
    const float* W_ent   = (const float*)d_in[6];
    const float* W_rel   = (const float*)d_in[7];
    const float* att_a   = (const float*)d_in[8];
    const float* att_a2  = (const float*)d_in[9];
    const float* out_a   = (const float*)d_in[10];
    const float* out_a2  = (const float*)d_in[11];
    float* out = (float*)d_out;
    const int* tgt_el = edge_list;
    const int* src_el = edge_list + E0;

    char* ws = (char*)d_ws;
    size_t o = 0;
    auto alloc = [&](size_t nbytes) -> char* {
        char* p = ws + o;
        o += (nbytes + 255) & ~(size_t)255;
        return p;
    };
    unsigned short* ent_bf  = (unsigned short*)alloc((size_t)N_NODES * KP1 * 2);
    unsigned short* x_bf    = (unsigned short*)alloc((size_t)N_NODES * KP2 * 2);
    unsigned short* Pcat    = (unsigned short*)alloc((size_t)N_NODES * LD1 * 2);
    unsigned short* Qcat    = (unsigned short*)alloc((size_t)N_NODES * LD2 * 2);
    unsigned short* Wcat1   = (unsigned short*)alloc((size_t)NPAD1 * KP1 * 2);
    unsigned short* Wcat2   = (unsigned short*)alloc((size_t)NPAD2 * KP2 * 2);
    float* uvecs = (float*)alloc(800 * 4);
    float* R1i   = (float*)alloc(474u * 200 * 4);
    float* R2    = (float*)alloc(474u * 200 * 4);
    float* dR10  = (float*)alloc(474u * 4);
    float* dR11  = (float*)alloc(474u * 4);
    float* dR2   = (float*)alloc(474u * 4);
    float2* wpair = (float2*)alloc((size_t)NE * 8);
    float* w2    = (float*)alloc((size_t)NE * 4);
    int* rowptr  = (int*)alloc((N_NODES + 1) * 4);
    int* cursor  = (int*)alloc(N_NODES * 4);
    int* tgts    = (int*)alloc((size_t)NE * 4);
    int* srcs    = (int*)alloc((size_t)NE * 4);
    int2* relpk  = (int2*)alloc((size_t)NE * 8);
    float* mask  = (float*)alloc(N_NODES * 4);
    int* scanloc = (int*)alloc(N_NODES * 4);
    int* bsums   = (int*)alloc(260 * 4);
    float* oacc  = (float*)alloc(9 * 4);

    const int TPB = 256;
    int wave_blocks_40000 = (N_NODES * 64 + TPB - 1) / TPB;   // 10000
    int wave_blocks_474   = (N_RELS * 64 + TPB - 1) / TPB;    // 119
    int edge_blocks       = (NE + TPB - 1) / TPB;
    int scan_blocks       = (N_NODES + 255) / 256;            // 157

    hipMemsetAsync(cursor, 0, N_NODES * 4, stream);
    hipMemsetAsync(mask, 0, N_NODES * 4, stream);
    hipMemsetAsync(oacc, 0, 9 * 4, stream);

    // 1) normalize entities -> bf16 padded
    k_l2norm_bf16<<<wave_blocks_40000, TPB, 0, stream>>>(ent_emb, ent_bf);

    // 2) CSR by target, payloads in CSR order
    k_hist<<<edge_blocks, TPB, 0, stream>>>(tgt_el, nhop, cursor);
    k_scan1<<<scan_blocks, 256, 0, stream>>>(cursor, scanloc, bsums, N_NODES);
    k_scan2<<<1, 256, 0, stream>>>(bsums, scan_blocks);
    k_scan3<<<(N_NODES + 1 + 255) / 256, 256, 0, stream>>>(scanloc, bsums, rowptr, cursor, N_NODES, scan_blocks);
    k_scatter<<<edge_blocks, TPB, 0, stream>>>(tgt_el, src_el, edge_type, nhop, cursor,
                                               tgts, srcs, relpk);

    // 3) pack fused B matrices (fragment order, zero-padded rows)
    k_uvec<<<4, 256, 0, stream>>>(att_a, att_a2, out_a, out_a2, uvecs);
    k_pack1<<<(NPAD1 * KP1 + 255) / 256, 256, 0, stream>>>(att_a, W_ent, uvecs, Wcat1);
    k_pack2<<<(NPAD2 * KP2 + 255) / 256, 256, 0, stream>>>(out_a, uvecs, Wcat2);

    // 4) fused layer-1 GEMM (MFMA bf16, fragment-ordered B)
    k_gemm_mfma<KP1><<<dim3(625, 2), 256, 0, stream>>>(ent_bf, Wcat1, Pcat, LD1, 608, 5);

    // 5) relation-side projections (interleaved) + dots
    k_relproj1<<<wave_blocks_474, TPB, 0, stream>>>(rel_emb, att_a, R1i);
    k_dR1<<<wave_blocks_474, TPB, 0, stream>>>(R1i, att_a2, dR10, dR11);

    // 6) layer-1 edge weights + aggregation -> x_bf (K-interleaved)
    k_edge1<<<edge_blocks, TPB, 0, stream>>>(tgts, srcs, relpk, Pcat, dR10, dR11, wpair);
    k_node1<<<wave_blocks_40000, TPB, 0, stream>>>(rowptr, srcs, relpk, wpair, Pcat, R1i, x_bf);

    // 7) fused layer-2 GEMM (MFMA bf16, fragment-ordered B)
    k_gemm_mfma<KP2><<<dim3(625, 2), 256, 0, stream>>>(x_bf, Wcat2, Qcat, LD2, 416, 4);

    // 8) out_relation_1 = rel_emb @ W_rel -> d_out; R2 = out_rel1 @ a_r2^T; dR2
    dim3 gor((200 + 63) / 64, (N_RELS + 63) / 64);
    k_mm<false><<<gor, TPB, 0, stream>>>(rel_emb, 100, W_rel, 200, out + 8000000, 200, N_RELS, 200, 100);
    k_mm<true><<<gor, TPB, 0, stream>>>(out + 8000000, 200, out_a + 400, 600, R2, 200, N_RELS, 200, 200);
    k_dotv<<<wave_blocks_474, TPB, 0, stream>>>(R2, out_a2, dR2, N_RELS, 200);

    // 9) layer-2 edge weights, mask, aggregation + final fuse
    k_edge2<<<edge_blocks, TPB, 0, stream>>>(tgts, srcs, relpk, Qcat, dR2, w2);
    k_mask<<<(NB + TPB - 1) / TPB, TPB, 0, stream>>>(batch, mask);
    k_node2<<<wave_blocks_40000, TPB, 0, stream>>>(rowptr, srcs, relpk, w2, Qcat, Pcat, R2, mask, out);

    // 10) ortho scalar (parallel)
    k_ortho_part<<<128, 256, 0, stream>>>(att_a, out_a, oacc);
    k_ortho_fin<<<1, 64, 0, stream>>>(oacc, out + 8094800);
}

// Round 10
// 420.151 us; speedup vs baseline: 1.2391x; 1.0382x over previous
//
#include <hip/hip_runtime.h>
#include <cstdint>
#include <cstddef>
#include <math.h>

#define N_NODES 40000
#define N_RELS  474
#define E0      100000
#define EN      30000
#define NE      130000
#define NB      8192
#define LRALPHA 0.2f

#define KP1 128   // padded K for layer-1 GEMM (K=100)
#define KP2 256   // padded K for layer-2 GEMM (K=200)
// Pcat cols: [0:200) Pt interleaved (2f=h0,2f+1=h1) | [200:400) Ps interleaved |
//            [400:600) entW natural | [600:604) dots (u_t0,u_s0,u_t1,u_s1) | pad
#define LD1 608
// Qcat cols: [0:200) Qt | [200:400) Qs | 400 dqt | 401 dqs | pad
#define LD2 416
#define NPAD1 640   // Wcat1 rows (zero-padded past 604)
#define NPAD2 448   // Wcat2 rows (zero-padded past 402)

typedef __attribute__((ext_vector_type(8))) short short8;
typedef __attribute__((ext_vector_type(4))) float floatx4;

static __device__ __forceinline__ unsigned short f2bf(float f) {
    union { float f; uint32_t u; } v; v.f = f;
    uint32_t r = v.u + 0x7fff + ((v.u >> 16) & 1);
    return (unsigned short)(r >> 16);
}
static __device__ __forceinline__ float bf2f(unsigned short h) {
    union { uint32_t u; float f; } v; v.u = ((uint32_t)h) << 16;
    return v.f;
}
static __device__ __forceinline__ float bflo(uint32_t u) { return bf2f((unsigned short)(u & 0xffff)); }
static __device__ __forceinline__ float bfhi(uint32_t u) { return bf2f((unsigned short)(u >> 16)); }

// ---------------- l2norm rows of ent -> bf16 padded [40000][KP1] ----------------
__global__ void k_l2norm_bf16(const float* __restrict__ in, unsigned short* __restrict__ out) {
    int w = (blockIdx.x * blockDim.x + threadIdx.x) >> 6;
    int lane = threadIdx.x & 63;
    if (w >= N_NODES) return;
    const float* r = in + (size_t)w * 100;
    float v0 = r[lane];
    int j1 = lane + 64;
    float v1 = (j1 < 100) ? r[j1] : 0.f;
    float ss = v0 * v0 + v1 * v1;
#pragma unroll
    for (int o = 32; o > 0; o >>= 1) ss += __shfl_down(ss, o);
    ss = __shfl(ss, 0);
    float inv = 1.f / fmaxf(sqrtf(ss), 1e-12f);
    unsigned short* dst = out + (size_t)w * KP1;
    dst[lane] = f2bf(v0 * inv);
    dst[j1] = (j1 < 100) ? f2bf(v1 * inv) : (unsigned short)0;
}

// ---------------- bf16 MFMA GEMM: fragment-ordered B (coalesced), 4-way ILP ----------------
template <int KP>
__global__ __launch_bounds__(256) void k_gemm_mfma(const unsigned short* __restrict__ A,
                                                   const unsigned short* __restrict__ B,
                                                   unsigned short* __restrict__ C,
                                                   int ldc, int N, int gPerSplit) {
    constexpr int KSTEPS = KP / 32;
    constexpr int KCH = KSTEPS / 4;
    __shared__ unsigned short cbuf[4][16][64];
    int wave = threadIdx.x >> 6;
    int lane = threadIdx.x & 63;
    int quad = lane >> 4;
    int l16 = lane & 15;
    int m0 = blockIdx.x * 64 + wave * 16;
    short8 afrag[KSTEPS];
    const unsigned short* arow = A + (size_t)(m0 + l16) * KP + quad * 8;
#pragma unroll
    for (int ks = 0; ks < KSTEPS; ks++)
        afrag[ks] = *(const short8*)(arow + ks * 32);

    int Gtot = (N + 63) >> 6;
    int g0 = blockIdx.y * gPerSplit;
    int g1 = g0 + gPerSplit;
    if (g1 > Gtot) g1 = Gtot;
    for (int g = g0; g < g1; g++) {
        int nb = g << 6;
        const unsigned short* bgrp = B + (((size_t)(g << 2) * KSTEPS) << 9) + (lane << 3);
        floatx4 acc[4];
#pragma unroll
        for (int t = 0; t < 4; t++) acc[t] = (floatx4){0.f, 0.f, 0.f, 0.f};
#pragma unroll
        for (int ch = 0; ch < KCH; ch++) {
            short8 bf[4][4];
#pragma unroll
            for (int t = 0; t < 4; t++)
#pragma unroll
                for (int k = 0; k < 4; k++)
                    bf[t][k] = *(const short8*)(bgrp + ((size_t)(t * KSTEPS + ch * 4 + k) << 9));
#pragma unroll
            for (int k = 0; k < 4; k++)
#pragma unroll
                for (int t = 0; t < 4; t++)
                    acc[t] = __builtin_amdgcn_mfma_f32_16x16x32_bf16(afrag[ch * 4 + k], bf[t][k], acc[t], 0, 0, 0);
        }
        int r0 = quad * 4;
#pragma unroll
        for (int t = 0; t < 4; t++)
#pragma unroll
            for (int i = 0; i < 4; i++)
                cbuf[wave][r0 + i][t * 16 + l16] = f2bf(acc[t][i]);
        int colsA = N - nb; if (colsA > 64) colsA = 64;
        int cols8 = colsA >> 3;
        int sh = (colsA >= 64) ? 3 : 2;
        int nchunks = cols8 << 4;
        for (int c = lane; c < nchunks; c += 64) {
            int row = c >> sh;
            int col8 = (c & (cols8 - 1)) << 3;
            *(uint4*)(C + (size_t)(m0 + row) * ldc + nb + col8) =
                *(const uint4*)&cbuf[wave][row][col8];
        }
    }
}

// ---------------- u-vectors: u = a_part^T @ a2 ----------------
__global__ void k_uvec(const float* __restrict__ att_a, const float* __restrict__ att_a2,
                       const float* __restrict__ out_a, const float* __restrict__ out_a2,
                       float* __restrict__ uvecs) {
    int tid = blockIdx.x * blockDim.x + threadIdx.x;
    if (tid >= 800) return;
    float s = 0.f;
    if (tid < 400) {
        int v = tid / 100, k = tid % 100;
        int head = v >> 1, part = v & 1;
        const float* base = att_a + head * 30000 + part * 100 + k;
        const float* a2 = att_a2 + head * 100;
        for (int n = 0; n < 100; n++) s += a2[n] * base[n * 300];
        uvecs[tid] = s;
    } else {
        int v = (tid - 400) / 200, k = (tid - 400) % 200;
        const float* base = out_a + v * 200 + k;
        for (int n = 0; n < 200; n++) s += out_a2[n] * base[n * 600];
        uvecs[400 + v * 200 + k] = s;
    }
}

// ---------------- pack layer-1 B matrix -> FRAGMENT ORDER ----------------
__global__ void k_pack1(const float* __restrict__ att_a, const float* __restrict__ W_ent,
                        const float* __restrict__ uvecs, unsigned short* __restrict__ W) {
    int idx = blockIdx.x * blockDim.x + threadIdx.x;
    if (idx >= NPAD1 * KP1) return;
    int j = idx & 7;
    int lane = (idx >> 3) & 63;
    int u = idx >> 9;
    int ks = u & 3;
    int t = u >> 2;
    int r = t * 16 + (lane & 15);
    int k = ks * 32 + (lane >> 4) * 8 + j;
    float val = 0.f;
    if (k < 100) {
        if (r < 200) {
            int i = r >> 1, h = r & 1;
            val = att_a[h * 30000 + i * 300 + k];
        } else if (r < 400) {
            int rr = r - 200, i = rr >> 1, h = rr & 1;
            val = att_a[h * 30000 + i * 300 + 100 + k];
        } else if (r < 600) {
            val = W_ent[k * 200 + (r - 400)];
        } else if (r < 604) {
            val = uvecs[(r - 600) * 100 + k];
        }
    }
    W[idx] = f2bf(val);
}

// ---------------- pack layer-2 B matrix -> FRAGMENT ORDER ----------------
__global__ void k_pack2(const float* __restrict__ out_a, const float* __restrict__ uvecs,
                        unsigned short* __restrict__ W) {
    int idx = blockIdx.x * blockDim.x + threadIdx.x;
    if (idx >= NPAD2 * KP2) return;
    int j = idx & 7;
    int lane = (idx >> 3) & 63;
    int u = idx >> 9;
    int ks = u & 7;
    int t = u >> 3;
    int r = t * 16 + (lane & 15);
    int k = ks * 32 + (lane >> 4) * 8 + j;
    float val = 0.f;
    if (k < 200) {
        int klog = (k & 1) * 100 + (k >> 1);
        if (r < 200)       val = out_a[r * 600 + klog];
        else if (r < 400)  val = out_a[(r - 200) * 600 + 200 + klog];
        else if (r == 400) val = uvecs[400 + klog];
        else if (r == 401) val = uvecs[600 + klog];
    }
    W[idx] = f2bf(val);
}

// ---------------- R1 interleaved projection: R1i[474][200] ----------------
__global__ void k_relproj1(const float* __restrict__ rel_emb, const float* __restrict__ att_a,
                           float* __restrict__ R1i) {
    int w = (blockIdx.x * blockDim.x + threadIdx.x) >> 6;
    int lane = threadIdx.x & 63;
    if (w >= N_RELS) return;
    const float* re = rel_emb + (size_t)w * 100;
    float2* dst = (float2*)(R1i + (size_t)w * 200);
    for (int f = lane; f < 100; f += 64) {
        const float* a0 = att_a + f * 300 + 200;
        const float* a1 = att_a + 30000 + f * 300 + 200;
        float s0 = 0.f, s1 = 0.f;
        for (int k = 0; k < 100; k++) {
            float rk = re[k];
            s0 += rk * a0[k];
            s1 += rk * a1[k];
        }
        dst[f] = make_float2(s0, s1);
    }
}

__global__ void k_dR1(const float* __restrict__ R1i, const float* __restrict__ att_a2,
                      float* __restrict__ dR10, float* __restrict__ dR11) {
    int w = (blockIdx.x * blockDim.x + threadIdx.x) >> 6;
    int lane = threadIdx.x & 63;
    if (w >= N_RELS) return;
    const float2* row = (const float2*)(R1i + (size_t)w * 200);
    float s0 = 0.f, s1 = 0.f;
    for (int f = lane; f < 100; f += 64) {
        float2 v = row[f];
        s0 += v.x * att_a2[f];
        s1 += v.y * att_a2[100 + f];
    }
#pragma unroll
    for (int o = 32; o > 0; o >>= 1) {
        s0 += __shfl_down(s0, o);
        s1 += __shfl_down(s1, o);
    }
    if (lane == 0) { dR10[w] = s0; dR11[w] = s1; }
}

// ---------------- generic tiled fp32 matmul (474-row cases only) ----------------
template <bool BT>
__global__ __launch_bounds__(256) void k_mm(const float* __restrict__ A, int lda,
                                            const float* __restrict__ B, int ldb,
                                            float* __restrict__ C, int ldc,
                                            int M, int N, int K) {
    __shared__ float As[16][65];
    __shared__ float Bs[16][65];
    int tid = threadIdx.x;
    int tx = tid & 15, ty = tid >> 4;
    int m0 = blockIdx.y * 64, n0 = blockIdx.x * 64;
    float acc[4][4] = {};
    for (int k0 = 0; k0 < K; k0 += 16) {
        {
            int r = tid >> 2;
            int c4 = (tid & 3) * 4;
            int m = m0 + r;
#pragma unroll
            for (int u = 0; u < 4; u++) {
                int k = k0 + c4 + u;
                As[c4 + u][r] = (m < M && k < K) ? A[(size_t)m * lda + k] : 0.f;
            }
        }
        if (BT) {
            int r = tid >> 2;
            int c4 = (tid & 3) * 4;
            int n = n0 + r;
#pragma unroll
            for (int u = 0; u < 4; u++) {
                int k = k0 + c4 + u;
                Bs[c4 + u][r] = (n < N && k < K) ? B[(size_t)n * ldb + k] : 0.f;
            }
        } else {
            int kk = tid >> 4;
            int nn4 = (tid & 15) * 4;
            int k = k0 + kk;
#pragma unroll
            for (int u = 0; u < 4; u++) {
                int n = n0 + nn4 + u;
                Bs[kk][nn4 + u] = (k < K && n < N) ? B[(size_t)k * ldb + n] : 0.f;
            }
        }
        __syncthreads();
#pragma unroll
        for (int k = 0; k < 16; k++) {
            float a[4], b[4];
#pragma unroll
            for (int i = 0; i < 4; i++) a[i] = As[k][ty + 16 * i];
#pragma unroll
            for (int j = 0; j < 4; j++) b[j] = Bs[k][tx + 16 * j];
#pragma unroll
            for (int i = 0; i < 4; i++)
#pragma unroll
                for (int j = 0; j < 4; j++) acc[i][j] += a[i] * b[j];
        }
        __syncthreads();
    }
#pragma unroll
    for (int i = 0; i < 4; i++) {
        int m = m0 + ty + 16 * i;
        if (m >= M) continue;
#pragma unroll
        for (int j = 0; j < 4; j++) {
            int n = n0 + tx + 16 * j;
            if (n < N) C[(size_t)m * ldc + n] = acc[i][j];
        }
    }
}

// ---------------- per-row dot with vector (474-row cases) ----------------
__global__ void k_dotv(const float* __restrict__ mat, const float* __restrict__ vec,
                       float* __restrict__ out, int M, int F) {
    int w = (blockIdx.x * blockDim.x + threadIdx.x) >> 6;
    int lane = threadIdx.x & 63;
    if (w >= M) return;
    const float* r = mat + (size_t)w * F;
    float s = 0.f;
    for (int j = lane; j < F; j += 64) s += r[j] * vec[j];
#pragma unroll
    for (int o = 32; o > 0; o >>= 1) s += __shfl_down(s, o);
    if (lane == 0) out[w] = s;
}

// ---------------- CSR build ----------------
__global__ void k_hist(const int* __restrict__ tgt_el, const int* __restrict__ nhop,
                       int* __restrict__ deg) {
    int e = blockIdx.x * blockDim.x + threadIdx.x;
    if (e >= NE) return;
    int t = (e < E0) ? tgt_el[e] : nhop[(size_t)(e - E0) * 4 + 3];
    atomicAdd(&deg[t], 1);
}

__global__ void k_scan1(const int* __restrict__ deg, int* __restrict__ local,
                        int* __restrict__ bsums, int n) {
    int i = blockIdx.x * 256 + threadIdx.x;
    int v = (i < n) ? deg[i] : 0;
    int lane = threadIdx.x & 63;
    int wv = threadIdx.x >> 6;
    int x = v;
#pragma unroll
    for (int o = 1; o < 64; o <<= 1) {
        int t = __shfl_up(x, o);
        if (lane >= o) x += t;
    }
    __shared__ int wtot[4];
    if (lane == 63) wtot[wv] = x;
    __syncthreads();
    int add = 0;
    for (int k = 0; k < wv; k++) add += wtot[k];
    if (i < n) local[i] = add + x - v;
    if (threadIdx.x == 255) bsums[blockIdx.x] = add + x;
}

__global__ void k_scan2(int* __restrict__ bsums, int nb) {
    int tid = threadIdx.x;
    int v = (tid < nb) ? bsums[tid] : 0;
    int lane = tid & 63, wv = tid >> 6;
    int x = v;
#pragma unroll
    for (int o = 1; o < 64; o <<= 1) {
        int t = __shfl_up(x, o);
        if (lane >= o) x += t;
    }
    __shared__ int wtot[4];
    if (lane == 63) wtot[wv] = x;
    __syncthreads();
    int add = 0;
    for (int k = 0; k < wv; k++) add += wtot[k];
    __syncthreads();
    if (tid < nb) bsums[tid] = add + x - v;
    if (tid == 255) bsums[nb] = add + x;
}

__global__ void k_scan3(const int* __restrict__ local, const int* __restrict__ bsums,
                        int* __restrict__ rowptr, int* __restrict__ cursor, int n, int nb) {
    int i = blockIdx.x * 256 + threadIdx.x;
    if (i < n) {
        int v = local[i] + bsums[blockIdx.x];
        rowptr[i] = v;
        cursor[i] = v;
    } else if (i == n) {
        rowptr[n] = bsums[nb];
    }
}

// scatter edge payloads into CSR order
__global__ void k_scatter(const int* __restrict__ tgt_el, const int* __restrict__ src_el,
                          const int* __restrict__ etype, const int* __restrict__ nhop,
                          int* __restrict__ cursor,
                          int* __restrict__ tgts, int* __restrict__ srcs,
                          int2* __restrict__ relpk) {
    int e = blockIdx.x * blockDim.x + threadIdx.x;
    if (e >= NE) return;
    int t, s, r1, r2;
    if (e < E0) {
        t = tgt_el[e]; s = src_el[e]; r1 = etype[e]; r2 = -1;
    } else {
        const int* nh = nhop + (size_t)(e - E0) * 4;
        t = nh[3]; s = nh[0]; r1 = nh[1]; r2 = nh[2];
    }
    int p = atomicAdd(&cursor[t], 1);
    tgts[p] = t; srcs[p] = s;
    relpk[p] = make_int2(r1, r2);
}

// ---------------- per-edge attention scalars (CSR-position order) ----------------
__global__ void k_edge1(const int* __restrict__ tgts, const int* __restrict__ srcs,
                        const int2* __restrict__ relpk,
                        const unsigned short* __restrict__ Pcat,
                        const float* __restrict__ dR10, const float* __restrict__ dR11,
                        float2* __restrict__ wpair) {
    int p = blockIdx.x * blockDim.x + threadIdx.x;
    if (p >= NE) return;
    int t = tgts[p], s = srcs[p];
    int2 rp = relpk[p];
    float dr0 = dR10[rp.x], dr1 = dR11[rp.x];
    if (rp.y >= 0) { dr0 += dR10[rp.y]; dr1 += dR11[rp.y]; }
    uint2 td = *(const uint2*)(Pcat + (size_t)t * LD1 + 600);
    uint2 sd = *(const uint2*)(Pcat + (size_t)s * LD1 + 600);
    float p0 = bflo(td.x) + bfhi(sd.x) + dr0;
    float p1 = bflo(td.y) + bfhi(sd.y) + dr1;
    p0 = (p0 >= 0.f) ? p0 : LRALPHA * p0;
    p1 = (p1 >= 0.f) ? p1 : LRALPHA * p1;
    wpair[p] = make_float2(expf(-p0), expf(-p1));
}

__global__ void k_edge2(const int* __restrict__ tgts, const int* __restrict__ srcs,
                        const int2* __restrict__ relpk,
                        const unsigned short* __restrict__ Qcat,
                        const float* __restrict__ dR2, float* __restrict__ w2) {
    int p = blockIdx.x * blockDim.x + threadIdx.x;
    if (p >= NE) return;
    int t = tgts[p], s = srcs[p];
    int2 rp = relpk[p];
    float dr = dR2[rp.x];
    if (rp.y >= 0) dr += dR2[rp.y];
    uint32_t tq = *(const uint32_t*)(Qcat + (size_t)t * LD2 + 400);
    uint32_t sq = *(const uint32_t*)(Qcat + (size_t)s * LD2 + 400);
    float pp = bflo(tq) + bfhi(sq) + dr;
    pp = (pp >= 0.f) ? pp : LRALPHA * pp;
    w2[p] = expf(-pp);
}

// ---------------- node aggregation layer 1 (wave/node, 2-wide edge unroll) ------------------
__global__ __launch_bounds__(256, 8) void k_node1(
                        const int* __restrict__ rowptr, const int* __restrict__ srcs,
                        const int2* __restrict__ relpk, const float2* __restrict__ wpair,
                        const unsigned short* __restrict__ Pcat,
                        const float* __restrict__ R1i,
                        unsigned short* __restrict__ x) {
    int node = (blockIdx.x * blockDim.x + threadIdx.x) >> 6;
    int lane = threadIdx.x & 63;
    if (node >= N_NODES) return;
    int f0 = lane, f1 = lane + 64;
    bool v1 = (f1 < 100);
    float b00 = 0, b01 = 0, b10 = 0, b11 = 0, rs0 = 0, rs1 = 0;
    int beg = rowptr[node], end = rowptr[node + 1];
    int p = beg;
    for (; p + 2 <= end; p += 2) {
        // metadata for both edges (independent loads)
        int sA = srcs[p], sB = srcs[p + 1];
        int2 rpA = relpk[p], rpB = relpk[p + 1];
        float2 wA = wpair[p], wB = wpair[p + 1];
        // R1 rows (L2-resident)
        const float2* rA = (const float2*)(R1i + (size_t)rpA.x * 200);
        const float2* rB = (const float2*)(R1i + (size_t)rpB.x * 200);
        float2 raA0 = rA[f0], raB0 = rB[f0];
        float2 raA1 = v1 ? rA[f1] : make_float2(0.f, 0.f);
        float2 raB1 = v1 ? rB[f1] : make_float2(0.f, 0.f);
        if (rpA.y >= 0) {
            const float2* r2 = (const float2*)(R1i + (size_t)rpA.y * 200);
            float2 t0 = r2[f0]; raA0.x += t0.x; raA0.y += t0.y;
            if (v1) { float2 t1 = r2[f1]; raA1.x += t1.x; raA1.y += t1.y; }
        }
        if (rpB.y >= 0) {
            const float2* r2 = (const float2*)(R1i + (size_t)rpB.y * 200);
            float2 t0 = r2[f0]; raB0.x += t0.x; raB0.y += t0.y;
            if (v1) { float2 t1 = r2[f1]; raB1.x += t1.x; raB1.y += t1.y; }
        }
        // both Ps gathers issued together
        const unsigned short* pA = Pcat + (size_t)sA * LD1 + 200;
        const unsigned short* pB = Pcat + (size_t)sB * LD1 + 200;
        uint32_t psA0 = *(const uint32_t*)(pA + 2 * f0);
        uint32_t psB0 = *(const uint32_t*)(pB + 2 * f0);
        uint32_t psA1 = v1 ? *(const uint32_t*)(pA + 2 * f1) : 0u;
        uint32_t psB1 = v1 ? *(const uint32_t*)(pB + 2 * f1) : 0u;
        rs0 += wA.x + wB.x; rs1 += wA.y + wB.y;
        b00 += wA.x * (bflo(psA0) + raA0.x) + wB.x * (bflo(psB0) + raB0.x);
        b01 += wA.y * (bfhi(psA0) + raA0.y) + wB.y * (bfhi(psB0) + raB0.y);
        if (v1) {
            b10 += wA.x * (bflo(psA1) + raA1.x) + wB.x * (bflo(psB1) + raB1.x);
            b11 += wA.y * (bfhi(psA1) + raA1.y) + wB.y * (bfhi(psB1) + raB1.y);
        }
    }
    if (p < end) {
        int s = srcs[p];
        int2 rp = relpk[p];
        float2 w = wpair[p];
        const float2* r1a = (const float2*)(R1i + (size_t)rp.x * 200);
        float2 ra0 = r1a[f0];
        float2 ra1 = v1 ? r1a[f1] : make_float2(0.f, 0.f);
        if (rp.y >= 0) {
            const float2* r1b = (const float2*)(R1i + (size_t)rp.y * 200);
            float2 t0 = r1b[f0]; ra0.x += t0.x; ra0.y += t0.y;
            if (v1) { float2 t1 = r1b[f1]; ra1.x += t1.x; ra1.y += t1.y; }
        }
        const unsigned short* prow = Pcat + (size_t)s * LD1 + 200;
        uint32_t ps0 = *(const uint32_t*)(prow + 2 * f0);
        rs0 += w.x; rs1 += w.y;
        b00 += w.x * (bflo(ps0) + ra0.x);
        b01 += w.y * (bfhi(ps0) + ra0.y);
        if (v1) {
            uint32_t ps1 = *(const uint32_t*)(prow + 2 * f1);
            b10 += w.x * (bflo(ps1) + ra1.x);
            b11 += w.y * (bfhi(ps1) + ra1.y);
        }
    }
    float d0 = (rs0 == 0.f) ? 1e-12f : rs0;
    float d1 = (rs1 == 0.f) ? 1e-12f : rs1;
    const unsigned short* pn = Pcat + (size_t)node * LD1;
    unsigned short* xr = x + (size_t)node * KP2;
    {
        uint32_t pt = *(const uint32_t*)(pn + 2 * f0);
        float v = (b00 + rs0 * bflo(pt)) / d0;
        float u = (b01 + rs1 * bfhi(pt)) / d1;
        v = (v > 0.f) ? v : expm1f(v);
        u = (u > 0.f) ? u : expm1f(u);
        *(uint32_t*)(xr + 2 * f0) = (uint32_t)f2bf(v) | ((uint32_t)f2bf(u) << 16);
    }
    if (v1) {
        uint32_t pt = *(const uint32_t*)(pn + 2 * f1);
        float v = (b10 + rs0 * bflo(pt)) / d0;
        float u = (b11 + rs1 * bfhi(pt)) / d1;
        v = (v > 0.f) ? v : expm1f(v);
        u = (u > 0.f) ? u : expm1f(u);
        *(uint32_t*)(xr + 2 * f1) = (uint32_t)f2bf(v) | ((uint32_t)f2bf(u) << 16);
    }
    if (lane < (KP2 - 200) / 2) *(uint32_t*)(xr + 200 + 2 * lane) = 0;
}

// ---------------- node aggregation layer 2 + final fuse (wave/node, 2-wide unroll) ----------
__global__ __launch_bounds__(256, 8) void k_node2(
                        const int* __restrict__ rowptr, const int* __restrict__ srcs,
                        const int2* __restrict__ relpk, const float* __restrict__ w2,
                        const unsigned short* __restrict__ Qcat,
                        const unsigned short* __restrict__ Pcat,
                        const float* __restrict__ R2, const float* __restrict__ mask,
                        float* __restrict__ out) {
    int node = (blockIdx.x * blockDim.x + threadIdx.x) >> 6;
    int lane = threadIdx.x & 63;
    if (node >= N_NODES) return;
    int q0 = lane, q1 = lane + 64;
    bool v = (q1 < 100);
    float c00 = 0, c01 = 0, c10 = 0, c11 = 0, rs = 0;
    int beg = rowptr[node], end = rowptr[node + 1];
    int p = beg;
    for (; p + 2 <= end; p += 2) {
        int sA = srcs[p], sB = srcs[p + 1];
        int2 rpA = relpk[p], rpB = relpk[p + 1];
        float WA = w2[p], WB = w2[p + 1];
        const float* rA = R2 + (size_t)rpA.x * 200;
        const float* rB = R2 + (size_t)rpB.x * 200;
        float2 raA = *(const float2*)(rA + 2 * q0);
        float2 raB = *(const float2*)(rB + 2 * q0);
        float2 rbA = v ? *(const float2*)(rA + 2 * q1) : make_float2(0.f, 0.f);
        float2 rbB = v ? *(const float2*)(rB + 2 * q1) : make_float2(0.f, 0.f);
        if (rpA.y >= 0) {
            const float* r2b = R2 + (size_t)rpA.y * 200;
            float2 t0 = *(const float2*)(r2b + 2 * q0); raA.x += t0.x; raA.y += t0.y;
            if (v) { float2 t1 = *(const float2*)(r2b + 2 * q1); rbA.x += t1.x; rbA.y += t1.y; }
        }
        if (rpB.y >= 0) {
            const float* r2b = R2 + (size_t)rpB.y * 200;
            float2 t0 = *(const float2*)(r2b + 2 * q0); raB.x += t0.x; raB.y += t0.y;
            if (v) { float2 t1 = *(const float2*)(r2b + 2 * q1); rbB.x += t1.x; rbB.y += t1.y; }
        }
        const unsigned short* qA = Qcat + (size_t)sA * LD2 + 200;
        const unsigned short* qB = Qcat + (size_t)sB * LD2 + 200;
        uint32_t qaA = *(const uint32_t*)(qA + 2 * q0);
        uint32_t qaB = *(const uint32_t*)(qB + 2 * q0);
        uint32_t qbA = v ? *(const uint32_t*)(qA + 2 * q1) : 0u;
        uint32_t qbB = v ? *(const uint32_t*)(qB + 2 * q1) : 0u;
        rs += WA + WB;
        c00 += WA * (bflo(qaA) + raA.x) + WB * (bflo(qaB) + raB.x);
        c01 += WA * (bfhi(qaA) + raA.y) + WB * (bfhi(qaB) + raB.y);
        if (v) {
            c10 += WA * (bflo(qbA) + rbA.x) + WB * (bflo(qbB) + rbB.x);
            c11 += WA * (bfhi(qbA) + rbA.y) + WB * (bfhi(qbB) + rbB.y);
        }
    }
    if (p < end) {
        int s = srcs[p];
        int2 rp = relpk[p];
        float W = w2[p];
        const float* r2r = R2 + (size_t)rp.x * 200;
        float2 ra = *(const float2*)(r2r + 2 * q0);
        float2 rb = v ? *(const float2*)(r2r + 2 * q1) : make_float2(0.f, 0.f);
        if (rp.y >= 0) {
            const float* r2b = R2 + (size_t)rp.y * 200;
            float2 t0 = *(const float2*)(r2b + 2 * q0); ra.x += t0.x; ra.y += t0.y;
            if (v) { float2 t1 = *(const float2*)(r2b + 2 * q1); rb.x += t1.x; rb.y += t1.y; }
        }
        const unsigned short* qsrow = Qcat + (size_t)s * LD2 + 200;
        uint32_t qa = *(const uint32_t*)(qsrow + 2 * q0);
        rs += W;
        c00 += W * (bflo(qa) + ra.x);
        c01 += W * (bfhi(qa) + ra.y);
        if (v) {
            uint32_t qb = *(const uint32_t*)(qsrow + 2 * q1);
            c10 += W * (bflo(qb) + rb.x);
            c11 += W * (bfhi(qb) + rb.y);
        }
    }
    float d = (rs == 0.f) ? 1e-12f : rs;
    const unsigned short* qt = Qcat + (size_t)node * LD2;
    const unsigned short* ew = Pcat + (size_t)node * LD1 + 400;
    float mk = mask[node];
    uint32_t t0 = *(const uint32_t*)(qt + 2 * q0);
    uint32_t e0 = *(const uint32_t*)(ew + 2 * q0);
    float val00 = bflo(e0) + mk * ((c00 + rs * bflo(t0)) / d);
    float val01 = bfhi(e0) + mk * ((c01 + rs * bfhi(t0)) / d);
    float val10 = 0.f, val11 = 0.f;
    if (v) {
        uint32_t t1 = *(const uint32_t*)(qt + 2 * q1);
        uint32_t e1 = *(const uint32_t*)(ew + 2 * q1);
        val10 = bflo(e1) + mk * ((c10 + rs * bflo(t1)) / d);
        val11 = bfhi(e1) + mk * ((c11 + rs * bfhi(t1)) / d);
    }
    float ss = val00 * val00 + val01 * val01 + val10 * val10 + val11 * val11;
#pragma unroll
    for (int o = 32; o > 0; o >>= 1) ss += __shfl_down(ss, o);
    ss = __shfl(ss, 0);
    float inv = 1.f / fmaxf(sqrtf(ss), 1e-12f);
    float* dst = out + (size_t)node * 200;
    *(float2*)(dst + 2 * q0) = make_float2(val00 * inv, val01 * inv);
    if (v) *(float2*)(dst + 2 * q1) = make_float2(val10 * inv, val11 * inv);
}

// ---------------- mask scatter ----------------
__global__ void k_mask(const int* __restrict__ batch, float* __restrict__ mask) {
    int i = blockIdx.x * blockDim.x + threadIdx.x;
    if (i < NB) mask[batch[(size_t)i * 3 + 2]] = 1.0f;
}

// ---------------- ortho losses: parallel partial reduction ----------------
__global__ void k_ortho_part(const float* __restrict__ att_a, const float* __restrict__ out_a,
                             float* __restrict__ accum) {
    float loc[9] = {0,0,0,0,0,0,0,0,0};
    int stride = gridDim.x * blockDim.x;
    for (int i = blockIdx.x * blockDim.x + threadIdx.x; i < 90000; i += stride) {
        int seg, li;
        const float* base;
        int L;
        if (i < 15000)      { seg = 0; li = i;          base = att_a;         L = 15000; }
        else if (i < 30000) { seg = 1; li = i - 15000;  base = att_a + 30000; L = 15000; }
        else                { seg = 2; li = i - 30000;  base = out_a;         L = 60000; }
        float a = base[li], b = base[L + li];
        loc[seg * 3 + 0] += a * a;
        loc[seg * 3 + 1] += b * b;
        loc[seg * 3 + 2] += a * b;
    }
    int lane = threadIdx.x & 63;
#pragma unroll
    for (int q = 0; q < 9; q++) {
        float s = loc[q];
#pragma unroll
        for (int o = 32; o > 0; o >>= 1) s += __shfl_down(s, o);
        if (lane == 0 && s != 0.f) atomicAdd(&accum[q], s);
    }
}

__global__ void k_ortho_fin(const float* __restrict__ accum, float* __restrict__ out_scalar) {
    if (threadIdx.x != 0 || blockIdx.x != 0) return;
    float total = 0.f;
#pragma unroll
    for (int m = 0; m < 3; m++) {
        float s0 = accum[m * 3 + 0], s1 = accum[m * 3 + 1], sc = accum[m * 3 + 2];
        float c = sc / (fmaxf(sqrtf(s0), 1e-12f) * fmaxf(sqrtf(s1), 1e-12f));
        total += 0.01f * 2.f * c * c;
    }
    out_scalar[0] = total;
}

// ---------------- launch ----------------
extern "C" void kernel_launch(void* const* d_in, const int* in_sizes, int n_in,
                              void* d_out, int out_size, void* d_ws, size_t ws_size,
                              hipStream_t stream) {
    const int* edge_list = (const int*)d_in[0];
    const int* edge_type = (const int*)d_in[1];
    const int* batch     = (const int*)d_in[2];
    const int* nhop      = (const int*)d_in[3];
    const float* ent_emb = (const float*)d_in[4];
    const float* rel_emb = (const float*)d_in[5];
    const float* W_ent   = (const float*)d_in[6];
    const float* W_rel   = (const float*)d_in[7];
    const float* att_a   = (const float*)d_in[8];
    const float* att_a2  = (const float*)d_in[9];
    const float* out_a   = (const float*)d_in[10];
    const float* out_a2  = (const float*)d_in[11];
    float* out = (float*)d_out;
    const int* tgt_el = edge_list;
    const int* src_el = edge_list + E0;

    char* ws = (char*)d_ws;
    size_t o = 0;
    auto alloc = [&](size_t nbytes) -> char* {
        char* p = ws + o;
        o += (nbytes + 255) & ~(size_t)255;
        return p;
    };
    unsigned short* ent_bf  = (unsigned short*)alloc((size_t)N_NODES * KP1 * 2);
    unsigned short* x_bf    = (unsigned short*)alloc((size_t)N_NODES * KP2 * 2);
    unsigned short* Pcat    = (unsigned short*)alloc((size_t)N_NODES * LD1 * 2);
    unsigned short* Qcat    = (unsigned short*)alloc((size_t)N_NODES * LD2 * 2);
    unsigned short* Wcat1   = (unsigned short*)alloc((size_t)NPAD1 * KP1 * 2);
    unsigned short* Wcat2   = (unsigned short*)alloc((size_t)NPAD2 * KP2 * 2);
    float* uvecs = (float*)alloc(800 * 4);
    float* R1i   = (float*)alloc(474u * 200 * 4);
    float* R2    = (float*)alloc(474u * 200 * 4);
    float* dR10  = (float*)alloc(474u * 4);
    float* dR11  = (float*)alloc(474u * 4);
    float* dR2   = (float*)alloc(474u * 4);
    float2* wpair = (float2*)alloc((size_t)NE * 8);
    float* w2    = (float*)alloc((size_t)NE * 4);
    int* rowptr  = (int*)alloc((N_NODES + 1) * 4);
    int* cursor  = (int*)alloc(N_NODES * 4);
    int* tgts    = (int*)alloc((size_t)NE * 4);
    int* srcs    = (int*)alloc((size_t)NE * 4);
    int2* relpk  = (int2*)alloc((size_t)NE * 8);
    float* mask  = (float*)alloc(N_NODES * 4);
    int* scanloc = (int*)alloc(N_NODES * 4);
    int* bsums   = (int*)alloc(260 * 4);
    float* oacc  = (float*)alloc(9 * 4);

    const int TPB = 256;
    int wave_blocks_40000 = (N_NODES * 64 + TPB - 1) / TPB;   // 10000
    int wave_blocks_474   = (N_RELS * 64 + TPB - 1) / TPB;    // 119
    int edge_blocks       = (NE + TPB - 1) / TPB;
    int scan_blocks       = (N_NODES + 255) / 256;            // 157

    hipMemsetAsync(cursor, 0, N_NODES * 4, stream);
    hipMemsetAsync(mask, 0, N_NODES * 4, stream);
    hipMemsetAsync(oacc, 0, 9 * 4, stream);

    // 1) normalize entities -> bf16 padded
    k_l2norm_bf16<<<wave_blocks_40000, TPB, 0, stream>>>(ent_emb, ent_bf);

    // 2) CSR by target, payloads in CSR order
    k_hist<<<edge_blocks, TPB, 0, stream>>>(tgt_el, nhop, cursor);
    k_scan1<<<scan_blocks, 256, 0, stream>>>(cursor, scanloc, bsums, N_NODES);
    k_scan2<<<1, 256, 0, stream>>>(bsums, scan_blocks);
    k_scan3<<<(N_NODES + 1 + 255) / 256, 256, 0, stream>>>(scanloc, bsums, rowptr, cursor, N_NODES, scan_blocks);
    k_scatter<<<edge_blocks, TPB, 0, stream>>>(tgt_el, src_el, edge_type, nhop, cursor,
                                               tgts, srcs, relpk);

    // 3) pack fused B matrices (fragment order, zero-padded rows)
    k_uvec<<<4, 256, 0, stream>>>(att_a, att_a2, out_a, out_a2, uvecs);
    k_pack1<<<(NPAD1 * KP1 + 255) / 256, 256, 0, stream>>>(att_a, W_ent, uvecs, Wcat1);
    k_pack2<<<(NPAD2 * KP2 + 255) / 256, 256, 0, stream>>>(out_a, uvecs, Wcat2);

    // 4) fused layer-1 GEMM (MFMA bf16, fragment-ordered B)
    k_gemm_mfma<KP1><<<dim3(625, 2), 256, 0, stream>>>(ent_bf, Wcat1, Pcat, LD1, 608, 5);

    // 5) relation-side projections (interleaved) + dots
    k_relproj1<<<wave_blocks_474, TPB, 0, stream>>>(rel_emb, att_a, R1i);
    k_dR1<<<wave_blocks_474, TPB, 0, stream>>>(R1i, att_a2, dR10, dR11);

    // 6) layer-1 edge weights + aggregation -> x_bf (K-interleaved)
    k_edge1<<<edge_blocks, TPB, 0, stream>>>(tgts, srcs, relpk, Pcat, dR10, dR11, wpair);
    k_node1<<<wave_blocks_40000, TPB, 0, stream>>>(rowptr, srcs, relpk, wpair, Pcat, R1i, x_bf);

    // 7) fused layer-2 GEMM (MFMA bf16, fragment-ordered B)
    k_gemm_mfma<KP2><<<dim3(625, 2), 256, 0, stream>>>(x_bf, Wcat2, Qcat, LD2, 416, 4);

    // 8) out_relation_1 = rel_emb @ W_rel -> d_out; R2 = out_rel1 @ a_r2^T; dR2
    dim3 gor((200 + 63) / 64, (N_RELS + 63) / 64);
    k_mm<false><<<gor, TPB, 0, stream>>>(rel_emb, 100, W_rel, 200, out + 8000000, 200, N_RELS, 200, 100);
    k_mm<true><<<gor, TPB, 0, stream>>>(out + 8000000, 200, out_a + 400, 600, R2, 200, N_RELS, 200, 200);
    k_dotv<<<wave_blocks_474, TPB, 0, stream>>>(R2, out_a2, dR2, N_RELS, 200);

    // 9) layer-2 edge weights, mask, aggregation + final fuse
    k_edge2<<<edge_blocks, TPB, 0, stream>>>(tgts, srcs, relpk, Qcat, dR2, w2);
    k_mask<<<(NB + TPB - 1) / TPB, TPB, 0, stream>>>(batch, mask);
    k_node2<<<wave_blocks_40000, TPB, 0, stream>>>(rowptr, srcs, relpk, w2, Qcat, Pcat, R2, mask, out);

    // 10) ortho scalar (parallel)
    k_ortho_part<<<128, 256, 0, stream>>>(att_a, out_a, oacc);
    k_ortho_fin<<<1, 64, 0, stream>>>(oacc, out + 8094800);
}

// Round 11
// 407.341 us; speedup vs baseline: 1.2781x; 1.0314x over previous
//
#include <hip/hip_runtime.h>
#include <cstdint>
#include <cstddef>
#include <math.h>

#define N_NODES 40000
#define N_RELS  474
#define E0      100000
#define EN      30000
#define NE      130000
#define NB      8192
#define LRALPHA 0.2f

#define KP1 128
#define KP2 256
// Pcat cols: [0:200) Pt interleaved | [200:400) Ps interleaved | [400:600) entW | [600:604) dots | pad
#define LD1 608
// Qcat cols: [0:200) Qt | [200:400) Qs | 400 dqt | 401 dqs | pad
#define LD2 416
#define NPAD1 640
#define NPAD2 448

typedef __attribute__((ext_vector_type(8))) short short8;
typedef __attribute__((ext_vector_type(4))) float floatx4;

static __device__ __forceinline__ unsigned short f2bf(float f) {
    union { float f; uint32_t u; } v; v.f = f;
    uint32_t r = v.u + 0x7fff + ((v.u >> 16) & 1);
    return (unsigned short)(r >> 16);
}
static __device__ __forceinline__ float bf2f(unsigned short h) {
    union { uint32_t u; float f; } v; v.u = ((uint32_t)h) << 16;
    return v.f;
}
static __device__ __forceinline__ float bflo(uint32_t u) { return bf2f((unsigned short)(u & 0xffff)); }
static __device__ __forceinline__ float bfhi(uint32_t u) { return bf2f((unsigned short)(u >> 16)); }

// ---------------- l2norm rows of ent -> bf16 padded [40000][KP1] ----------------
__global__ void k_l2norm_bf16(const float* __restrict__ in, unsigned short* __restrict__ out) {
    int w = (blockIdx.x * blockDim.x + threadIdx.x) >> 6;
    int lane = threadIdx.x & 63;
    if (w >= N_NODES) return;
    const float* r = in + (size_t)w * 100;
    float v0 = r[lane];
    int j1 = lane + 64;
    float v1 = (j1 < 100) ? r[j1] : 0.f;
    float ss = v0 * v0 + v1 * v1;
#pragma unroll
    for (int o = 32; o > 0; o >>= 1) ss += __shfl_down(ss, o);
    ss = __shfl(ss, 0);
    float inv = 1.f / fmaxf(sqrtf(ss), 1e-12f);
    unsigned short* dst = out + (size_t)w * KP1;
    dst[lane] = f2bf(v0 * inv);
    dst[j1] = (j1 < 100) ? f2bf(v1 * inv) : (unsigned short)0;
}

// ---------------- bf16 MFMA GEMM: fragment-ordered B (coalesced), 4-way ILP ----------------
template <int KP>
__global__ __launch_bounds__(256) void k_gemm_mfma(const unsigned short* __restrict__ A,
                                                   const unsigned short* __restrict__ B,
                                                   unsigned short* __restrict__ C,
                                                   int ldc, int N, int gPerSplit) {
    constexpr int KSTEPS = KP / 32;
    constexpr int KCH = KSTEPS / 4;
    __shared__ unsigned short cbuf[4][16][64];
    int wave = threadIdx.x >> 6;
    int lane = threadIdx.x & 63;
    int quad = lane >> 4;
    int l16 = lane & 15;
    int m0 = blockIdx.x * 64 + wave * 16;
    short8 afrag[KSTEPS];
    const unsigned short* arow = A + (size_t)(m0 + l16) * KP + quad * 8;
#pragma unroll
    for (int ks = 0; ks < KSTEPS; ks++)
        afrag[ks] = *(const short8*)(arow + ks * 32);

    int Gtot = (N + 63) >> 6;
    int g0 = blockIdx.y * gPerSplit;
    int g1 = g0 + gPerSplit;
    if (g1 > Gtot) g1 = Gtot;
    for (int g = g0; g < g1; g++) {
        int nb = g << 6;
        const unsigned short* bgrp = B + (((size_t)(g << 2) * KSTEPS) << 9) + (lane << 3);
        floatx4 acc[4];
#pragma unroll
        for (int t = 0; t < 4; t++) acc[t] = (floatx4){0.f, 0.f, 0.f, 0.f};
#pragma unroll
        for (int ch = 0; ch < KCH; ch++) {
            short8 bf[4][4];
#pragma unroll
            for (int t = 0; t < 4; t++)
#pragma unroll
                for (int k = 0; k < 4; k++)
                    bf[t][k] = *(const short8*)(bgrp + ((size_t)(t * KSTEPS + ch * 4 + k) << 9));
#pragma unroll
            for (int k = 0; k < 4; k++)
#pragma unroll
                for (int t = 0; t < 4; t++)
                    acc[t] = __builtin_amdgcn_mfma_f32_16x16x32_bf16(afrag[ch * 4 + k], bf[t][k], acc[t], 0, 0, 0);
        }
        int r0 = quad * 4;
#pragma unroll
        for (int t = 0; t < 4; t++)
#pragma unroll
            for (int i = 0; i < 4; i++)
                cbuf[wave][r0 + i][t * 16 + l16] = f2bf(acc[t][i]);
        int colsA = N - nb; if (colsA > 64) colsA = 64;
        int cols8 = colsA >> 3;
        int sh = (colsA >= 64) ? 3 : 2;
        int nchunks = cols8 << 4;
        for (int c = lane; c < nchunks; c += 64) {
            int row = c >> sh;
            int col8 = (c & (cols8 - 1)) << 3;
            *(uint4*)(C + (size_t)(m0 + row) * ldc + nb + col8) =
                *(const uint4*)&cbuf[wave][row][col8];
        }
    }
}

// ---------------- u-vectors ----------------
__global__ void k_uvec(const float* __restrict__ att_a, const float* __restrict__ att_a2,
                       const float* __restrict__ out_a, const float* __restrict__ out_a2,
                       float* __restrict__ uvecs) {
    int tid = blockIdx.x * blockDim.x + threadIdx.x;
    if (tid >= 800) return;
    float s = 0.f;
    if (tid < 400) {
        int v = tid / 100, k = tid % 100;
        int head = v >> 1, part = v & 1;
        const float* base = att_a + head * 30000 + part * 100 + k;
        const float* a2 = att_a2 + head * 100;
        for (int n = 0; n < 100; n++) s += a2[n] * base[n * 300];
        uvecs[tid] = s;
    } else {
        int v = (tid - 400) / 200, k = (tid - 400) % 200;
        const float* base = out_a + v * 200 + k;
        for (int n = 0; n < 200; n++) s += out_a2[n] * base[n * 600];
        uvecs[400 + v * 200 + k] = s;
    }
}

// ---------------- pack layer-1 B matrix -> FRAGMENT ORDER ----------------
__global__ void k_pack1(const float* __restrict__ att_a, const float* __restrict__ W_ent,
                        const float* __restrict__ uvecs, unsigned short* __restrict__ W) {
    int idx = blockIdx.x * blockDim.x + threadIdx.x;
    if (idx >= NPAD1 * KP1) return;
    int j = idx & 7;
    int lane = (idx >> 3) & 63;
    int u = idx >> 9;
    int ks = u & 3;
    int t = u >> 2;
    int r = t * 16 + (lane & 15);
    int k = ks * 32 + (lane >> 4) * 8 + j;
    float val = 0.f;
    if (k < 100) {
        if (r < 200) {
            int i = r >> 1, h = r & 1;
            val = att_a[h * 30000 + i * 300 + k];
        } else if (r < 400) {
            int rr = r - 200, i = rr >> 1, h = rr & 1;
            val = att_a[h * 30000 + i * 300 + 100 + k];
        } else if (r < 600) {
            val = W_ent[k * 200 + (r - 400)];
        } else if (r < 604) {
            val = uvecs[(r - 600) * 100 + k];
        }
    }
    W[idx] = f2bf(val);
}

// ---------------- pack layer-2 B matrix -> FRAGMENT ORDER ----------------
__global__ void k_pack2(const float* __restrict__ out_a, const float* __restrict__ uvecs,
                        unsigned short* __restrict__ W) {
    int idx = blockIdx.x * blockDim.x + threadIdx.x;
    if (idx >= NPAD2 * KP2) return;
    int j = idx & 7;
    int lane = (idx >> 3) & 63;
    int u = idx >> 9;
    int ks = u & 7;
    int t = u >> 3;
    int r = t * 16 + (lane & 15);
    int k = ks * 32 + (lane >> 4) * 8 + j;
    float val = 0.f;
    if (k < 200) {
        int klog = (k & 1) * 100 + (k >> 1);
        if (r < 200)       val = out_a[r * 600 + klog];
        else if (r < 400)  val = out_a[(r - 200) * 600 + 200 + klog];
        else if (r == 400) val = uvecs[400 + klog];
        else if (r == 401) val = uvecs[600 + klog];
    }
    W[idx] = f2bf(val);
}

// ---------------- R1 interleaved projection ----------------
__global__ void k_relproj1(const float* __restrict__ rel_emb, const float* __restrict__ att_a,
                           float* __restrict__ R1i) {
    int w = (blockIdx.x * blockDim.x + threadIdx.x) >> 6;
    int lane = threadIdx.x & 63;
    if (w >= N_RELS) return;
    const float* re = rel_emb + (size_t)w * 100;
    float2* dst = (float2*)(R1i + (size_t)w * 200);
    for (int f = lane; f < 100; f += 64) {
        const float* a0 = att_a + f * 300 + 200;
        const float* a1 = att_a + 30000 + f * 300 + 200;
        float s0 = 0.f, s1 = 0.f;
        for (int k = 0; k < 100; k++) {
            float rk = re[k];
            s0 += rk * a0[k];
            s1 += rk * a1[k];
        }
        dst[f] = make_float2(s0, s1);
    }
}

__global__ void k_dR1(const float* __restrict__ R1i, const float* __restrict__ att_a2,
                      float* __restrict__ dR10, float* __restrict__ dR11) {
    int w = (blockIdx.x * blockDim.x + threadIdx.x) >> 6;
    int lane = threadIdx.x & 63;
    if (w >= N_RELS) return;
    const float2* row = (const float2*)(R1i + (size_t)w * 200);
    float s0 = 0.f, s1 = 0.f;
    for (int f = lane; f < 100; f += 64) {
        float2 v = row[f];
        s0 += v.x * att_a2[f];
        s1 += v.y * att_a2[100 + f];
    }
#pragma unroll
    for (int o = 32; o > 0; o >>= 1) {
        s0 += __shfl_down(s0, o);
        s1 += __shfl_down(s1, o);
    }
    if (lane == 0) { dR10[w] = s0; dR11[w] = s1; }
}

// ---------------- generic tiled fp32 matmul (474-row cases only) ----------------
template <bool BT>
__global__ __launch_bounds__(256) void k_mm(const float* __restrict__ A, int lda,
                                            const float* __restrict__ B, int ldb,
                                            float* __restrict__ C, int ldc,
                                            int M, int N, int K) {
    __shared__ float As[16][65];
    __shared__ float Bs[16][65];
    int tid = threadIdx.x;
    int tx = tid & 15, ty = tid >> 4;
    int m0 = blockIdx.y * 64, n0 = blockIdx.x * 64;
    float acc[4][4] = {};
    for (int k0 = 0; k0 < K; k0 += 16) {
        {
            int r = tid >> 2;
            int c4 = (tid & 3) * 4;
            int m = m0 + r;
#pragma unroll
            for (int u = 0; u < 4; u++) {
                int k = k0 + c4 + u;
                As[c4 + u][r] = (m < M && k < K) ? A[(size_t)m * lda + k] : 0.f;
            }
        }
        if (BT) {
            int r = tid >> 2;
            int c4 = (tid & 3) * 4;
            int n = n0 + r;
#pragma unroll
            for (int u = 0; u < 4; u++) {
                int k = k0 + c4 + u;
                Bs[c4 + u][r] = (n < N && k < K) ? B[(size_t)n * ldb + k] : 0.f;
            }
        } else {
            int kk = tid >> 4;
            int nn4 = (tid & 15) * 4;
            int k = k0 + kk;
#pragma unroll
            for (int u = 0; u < 4; u++) {
                int n = n0 + nn4 + u;
                Bs[kk][nn4 + u] = (k < K && n < N) ? B[(size_t)k * ldb + n] : 0.f;
            }
        }
        __syncthreads();
#pragma unroll
        for (int k = 0; k < 16; k++) {
            float a[4], b[4];
#pragma unroll
            for (int i = 0; i < 4; i++) a[i] = As[k][ty + 16 * i];
#pragma unroll
            for (int j = 0; j < 4; j++) b[j] = Bs[k][tx + 16 * j];
#pragma unroll
            for (int i = 0; i < 4; i++)
#pragma unroll
                for (int j = 0; j < 4; j++) acc[i][j] += a[i] * b[j];
        }
        __syncthreads();
    }
#pragma unroll
    for (int i = 0; i < 4; i++) {
        int m = m0 + ty + 16 * i;
        if (m >= M) continue;
#pragma unroll
        for (int j = 0; j < 4; j++) {
            int n = n0 + tx + 16 * j;
            if (n < N) C[(size_t)m * ldc + n] = acc[i][j];
        }
    }
}

// ---------------- per-row dot with vector ----------------
__global__ void k_dotv(const float* __restrict__ mat, const float* __restrict__ vec,
                       float* __restrict__ out, int M, int F) {
    int w = (blockIdx.x * blockDim.x + threadIdx.x) >> 6;
    int lane = threadIdx.x & 63;
    if (w >= M) return;
    const float* r = mat + (size_t)w * F;
    float s = 0.f;
    for (int j = lane; j < F; j += 64) s += r[j] * vec[j];
#pragma unroll
    for (int o = 32; o > 0; o >>= 1) s += __shfl_down(s, o);
    if (lane == 0) out[w] = s;
}

// ---------------- CSR build ----------------
__global__ void k_hist(const int* __restrict__ tgt_el, const int* __restrict__ nhop,
                       int* __restrict__ deg) {
    int e = blockIdx.x * blockDim.x + threadIdx.x;
    if (e >= NE) return;
    int t = (e < E0) ? tgt_el[e] : nhop[(size_t)(e - E0) * 4 + 3];
    atomicAdd(&deg[t], 1);
}

__global__ void k_scan1(const int* __restrict__ deg, int* __restrict__ local,
                        int* __restrict__ bsums, int n) {
    int i = blockIdx.x * 256 + threadIdx.x;
    int v = (i < n) ? deg[i] : 0;
    int lane = threadIdx.x & 63;
    int wv = threadIdx.x >> 6;
    int x = v;
#pragma unroll
    for (int o = 1; o < 64; o <<= 1) {
        int t = __shfl_up(x, o);
        if (lane >= o) x += t;
    }
    __shared__ int wtot[4];
    if (lane == 63) wtot[wv] = x;
    __syncthreads();
    int add = 0;
    for (int k = 0; k < wv; k++) add += wtot[k];
    if (i < n) local[i] = add + x - v;
    if (threadIdx.x == 255) bsums[blockIdx.x] = add + x;
}

__global__ void k_scan2(int* __restrict__ bsums, int nb) {
    int tid = threadIdx.x;
    int v = (tid < nb) ? bsums[tid] : 0;
    int lane = tid & 63, wv = tid >> 6;
    int x = v;
#pragma unroll
    for (int o = 1; o < 64; o <<= 1) {
        int t = __shfl_up(x, o);
        if (lane >= o) x += t;
    }
    __shared__ int wtot[4];
    if (lane == 63) wtot[wv] = x;
    __syncthreads();
    int add = 0;
    for (int k = 0; k < wv; k++) add += wtot[k];
    __syncthreads();
    if (tid < nb) bsums[tid] = add + x - v;
    if (tid == 255) bsums[nb] = add + x;
}

__global__ void k_scan3(const int* __restrict__ local, const int* __restrict__ bsums,
                        int* __restrict__ rowptr, int* __restrict__ cursor, int n, int nb) {
    int i = blockIdx.x * 256 + threadIdx.x;
    if (i < n) {
        int v = local[i] + bsums[blockIdx.x];
        rowptr[i] = v;
        cursor[i] = v;
    } else if (i == n) {
        rowptr[n] = bsums[nb];
    }
}

__global__ void k_scatter(const int* __restrict__ tgt_el, const int* __restrict__ src_el,
                          const int* __restrict__ etype, const int* __restrict__ nhop,
                          int* __restrict__ cursor,
                          int* __restrict__ tgts, int* __restrict__ srcs,
                          int2* __restrict__ relpk) {
    int e = blockIdx.x * blockDim.x + threadIdx.x;
    if (e >= NE) return;
    int t, s, r1, r2;
    if (e < E0) {
        t = tgt_el[e]; s = src_el[e]; r1 = etype[e]; r2 = -1;
    } else {
        const int* nh = nhop + (size_t)(e - E0) * 4;
        t = nh[3]; s = nh[0]; r1 = nh[1]; r2 = nh[2];
    }
    int p = atomicAdd(&cursor[t], 1);
    tgts[p] = t; srcs[p] = s;
    relpk[p] = make_int2(r1, r2);
}

// ---------------- per-edge attention scalars ----------------
__global__ void k_edge1(const int* __restrict__ tgts, const int* __restrict__ srcs,
                        const int2* __restrict__ relpk,
                        const unsigned short* __restrict__ Pcat,
                        const float* __restrict__ dR10, const float* __restrict__ dR11,
                        float2* __restrict__ wpair) {
    int p = blockIdx.x * blockDim.x + threadIdx.x;
    if (p >= NE) return;
    int t = tgts[p], s = srcs[p];
    int2 rp = relpk[p];
    float dr0 = dR10[rp.x], dr1 = dR11[rp.x];
    if (rp.y >= 0) { dr0 += dR10[rp.y]; dr1 += dR11[rp.y]; }
    uint2 td = *(const uint2*)(Pcat + (size_t)t * LD1 + 600);
    uint2 sd = *(const uint2*)(Pcat + (size_t)s * LD1 + 600);
    float p0 = bflo(td.x) + bfhi(sd.x) + dr0;
    float p1 = bflo(td.y) + bfhi(sd.y) + dr1;
    p0 = (p0 >= 0.f) ? p0 : LRALPHA * p0;
    p1 = (p1 >= 0.f) ? p1 : LRALPHA * p1;
    wpair[p] = make_float2(expf(-p0), expf(-p1));
}

__global__ void k_edge2(const int* __restrict__ tgts, const int* __restrict__ srcs,
                        const int2* __restrict__ relpk,
                        const unsigned short* __restrict__ Qcat,
                        const float* __restrict__ dR2, float* __restrict__ w2) {
    int p = blockIdx.x * blockDim.x + threadIdx.x;
    if (p >= NE) return;
    int t = tgts[p], s = srcs[p];
    int2 rp = relpk[p];
    float dr = dR2[rp.x];
    if (rp.y >= 0) dr += dR2[rp.y];
    uint32_t tq = *(const uint32_t*)(Qcat + (size_t)t * LD2 + 400);
    uint32_t sq = *(const uint32_t*)(Qcat + (size_t)s * LD2 + 400);
    float pp = bflo(tq) + bfhi(sq) + dr;
    pp = (pp >= 0.f) ? pp : LRALPHA * pp;
    w2[p] = expf(-pp);
}

// ---------------- node aggregation layer 1: shuffle-broadcast metadata + 4-wide gathers -----
__global__ __launch_bounds__(256, 4) void k_node1(
                        const int* __restrict__ rowptr, const int* __restrict__ srcs,
                        const int2* __restrict__ relpk, const float2* __restrict__ wpair,
                        const unsigned short* __restrict__ Pcat,
                        const float* __restrict__ R1i,
                        unsigned short* __restrict__ x) {
    int node = (blockIdx.x * blockDim.x + threadIdx.x) >> 6;
    int lane = threadIdx.x & 63;
    if (node >= N_NODES) return;
    int f0 = lane, f1 = lane + 64;
    bool v1 = (f1 < 100);
    float b00 = 0, b01 = 0, b10 = 0, b11 = 0, rs0 = 0, rs1 = 0;
    int beg = rowptr[node], end = rowptr[node + 1];
    int deg = end - beg;
    int fast = (deg < 64) ? deg : 64;
    // one coalesced lane-indexed metadata load for up to 64 edges
    int sL = 0, rxL = 0, ryL = -1;
    float wxL = 0.f, wyL = 0.f;
    if (lane < fast) {
        sL = srcs[beg + lane];
        int2 rp = relpk[beg + lane];
        rxL = rp.x; ryL = rp.y;
        float2 w = wpair[beg + lane];
        wxL = w.x; wyL = w.y;
    }
    for (int j = 0; j < fast; j += 4) {
#pragma unroll
        for (int u = 0; u < 4; u++) {
            int jj = j + u;
            int sE = __shfl(sL, jj & 63);
            int rxE = __shfl(rxL, jj & 63);
            int ryE = __shfl(ryL, jj & 63);
            float wxE = __shfl(wxL, jj & 63);
            float wyE = __shfl(wyL, jj & 63);
            if (jj >= fast) { sE = 0; rxE = 0; ryE = -1; wxE = 0.f; wyE = 0.f; }
            const float2* rA = (const float2*)(R1i + (size_t)rxE * 200);
            const unsigned short* pS = Pcat + (size_t)sE * LD1 + 200;
            uint32_t ps0 = *(const uint32_t*)(pS + 2 * f0);
            uint32_t ps1 = v1 ? *(const uint32_t*)(pS + 2 * f1) : 0u;
            float2 ra0 = rA[f0];
            float2 ra1 = v1 ? rA[f1] : make_float2(0.f, 0.f);
            if (ryE >= 0) {
                const float2* rB = (const float2*)(R1i + (size_t)ryE * 200);
                float2 t0 = rB[f0]; ra0.x += t0.x; ra0.y += t0.y;
                if (v1) { float2 t1 = rB[f1]; ra1.x += t1.x; ra1.y += t1.y; }
            }
            rs0 += wxE; rs1 += wyE;
            b00 += wxE * (bflo(ps0) + ra0.x);
            b01 += wyE * (bfhi(ps0) + ra0.y);
            if (v1) {
                b10 += wxE * (bflo(ps1) + ra1.x);
                b11 += wyE * (bfhi(ps1) + ra1.y);
            }
        }
    }
    // rare deg>64 tail
    for (int p = beg + fast; p < end; p++) {
        int s = srcs[p];
        int2 rp = relpk[p];
        float2 w = wpair[p];
        const float2* r1a = (const float2*)(R1i + (size_t)rp.x * 200);
        float2 ra0 = r1a[f0];
        float2 ra1 = v1 ? r1a[f1] : make_float2(0.f, 0.f);
        if (rp.y >= 0) {
            const float2* r1b = (const float2*)(R1i + (size_t)rp.y * 200);
            float2 t0 = r1b[f0]; ra0.x += t0.x; ra0.y += t0.y;
            if (v1) { float2 t1 = r1b[f1]; ra1.x += t1.x; ra1.y += t1.y; }
        }
        const unsigned short* prow = Pcat + (size_t)s * LD1 + 200;
        uint32_t ps0 = *(const uint32_t*)(prow + 2 * f0);
        rs0 += w.x; rs1 += w.y;
        b00 += w.x * (bflo(ps0) + ra0.x);
        b01 += w.y * (bfhi(ps0) + ra0.y);
        if (v1) {
            uint32_t ps1 = *(const uint32_t*)(prow + 2 * f1);
            b10 += w.x * (bflo(ps1) + ra1.x);
            b11 += w.y * (bfhi(ps1) + ra1.y);
        }
    }
    float d0 = (rs0 == 0.f) ? 1e-12f : rs0;
    float d1 = (rs1 == 0.f) ? 1e-12f : rs1;
    const unsigned short* pn = Pcat + (size_t)node * LD1;
    unsigned short* xr = x + (size_t)node * KP2;
    {
        uint32_t pt = *(const uint32_t*)(pn + 2 * f0);
        float v = (b00 + rs0 * bflo(pt)) / d0;
        float u = (b01 + rs1 * bfhi(pt)) / d1;
        v = (v > 0.f) ? v : expm1f(v);
        u = (u > 0.f) ? u : expm1f(u);
        *(uint32_t*)(xr + 2 * f0) = (uint32_t)f2bf(v) | ((uint32_t)f2bf(u) << 16);
    }
    if (v1) {
        uint32_t pt = *(const uint32_t*)(pn + 2 * f1);
        float v = (b10 + rs0 * bflo(pt)) / d0;
        float u = (b11 + rs1 * bfhi(pt)) / d1;
        v = (v > 0.f) ? v : expm1f(v);
        u = (u > 0.f) ? u : expm1f(u);
        *(uint32_t*)(xr + 2 * f1) = (uint32_t)f2bf(v) | ((uint32_t)f2bf(u) << 16);
    }
    if (lane < (KP2 - 200) / 2) *(uint32_t*)(xr + 200 + 2 * lane) = 0;
}

// ---------------- node aggregation layer 2: shuffle-broadcast metadata + 4-wide gathers -----
__global__ __launch_bounds__(256, 4) void k_node2(
                        const int* __restrict__ rowptr, const int* __restrict__ srcs,
                        const int2* __restrict__ relpk, const float* __restrict__ w2,
                        const unsigned short* __restrict__ Qcat,
                        const unsigned short* __restrict__ Pcat,
                        const float* __restrict__ R2, const float* __restrict__ mask,
                        float* __restrict__ out) {
    int node = (blockIdx.x * blockDim.x + threadIdx.x) >> 6;
    int lane = threadIdx.x & 63;
    if (node >= N_NODES) return;
    int q0 = lane, q1 = lane + 64;
    bool v = (q1 < 100);
    float c00 = 0, c01 = 0, c10 = 0, c11 = 0, rs = 0;
    int beg = rowptr[node], end = rowptr[node + 1];
    int deg = end - beg;
    int fast = (deg < 64) ? deg : 64;
    int sL = 0, rxL = 0, ryL = -1;
    float WL = 0.f;
    if (lane < fast) {
        sL = srcs[beg + lane];
        int2 rp = relpk[beg + lane];
        rxL = rp.x; ryL = rp.y;
        WL = w2[beg + lane];
    }
    for (int j = 0; j < fast; j += 4) {
#pragma unroll
        for (int u = 0; u < 4; u++) {
            int jj = j + u;
            int sE = __shfl(sL, jj & 63);
            int rxE = __shfl(rxL, jj & 63);
            int ryE = __shfl(ryL, jj & 63);
            float WE = __shfl(WL, jj & 63);
            if (jj >= fast) { sE = 0; rxE = 0; ryE = -1; WE = 0.f; }
            const float* rA = R2 + (size_t)rxE * 200;
            const unsigned short* qS = Qcat + (size_t)sE * LD2 + 200;
            uint32_t qa = *(const uint32_t*)(qS + 2 * q0);
            uint32_t qb = v ? *(const uint32_t*)(qS + 2 * q1) : 0u;
            float2 ra = *(const float2*)(rA + 2 * q0);
            float2 rb = v ? *(const float2*)(rA + 2 * q1) : make_float2(0.f, 0.f);
            if (ryE >= 0) {
                const float* rB = R2 + (size_t)ryE * 200;
                float2 t0 = *(const float2*)(rB + 2 * q0); ra.x += t0.x; ra.y += t0.y;
                if (v) { float2 t1 = *(const float2*)(rB + 2 * q1); rb.x += t1.x; rb.y += t1.y; }
            }
            rs += WE;
            c00 += WE * (bflo(qa) + ra.x);
            c01 += WE * (bfhi(qa) + ra.y);
            if (v) {
                c10 += WE * (bflo(qb) + rb.x);
                c11 += WE * (bfhi(qb) + rb.y);
            }
        }
    }
    // rare deg>64 tail
    for (int p = beg + fast; p < end; p++) {
        int s = srcs[p];
        int2 rp = relpk[p];
        float W = w2[p];
        const float* r2r = R2 + (size_t)rp.x * 200;
        float2 ra = *(const float2*)(r2r + 2 * q0);
        float2 rb = v ? *(const float2*)(r2r + 2 * q1) : make_float2(0.f, 0.f);
        if (rp.y >= 0) {
            const float* r2b = R2 + (size_t)rp.y * 200;
            float2 t0 = *(const float2*)(r2b + 2 * q0); ra.x += t0.x; ra.y += t0.y;
            if (v) { float2 t1 = *(const float2*)(r2b + 2 * q1); rb.x += t1.x; rb.y += t1.y; }
        }
        const unsigned short* qsrow = Qcat + (size_t)s * LD2 + 200;
        uint32_t qa = *(const uint32_t*)(qsrow + 2 * q0);
        rs += W;
        c00 += W * (bflo(qa) + ra.x);
        c01 += W * (bfhi(qa) + ra.y);
        if (v) {
            uint32_t qb = *(const uint32_t*)(qsrow + 2 * q1);
            c10 += W * (bflo(qb) + rb.x);
            c11 += W * (bfhi(qb) + rb.y);
        }
    }
    float d = (rs == 0.f) ? 1e-12f : rs;
    const unsigned short* qt = Qcat + (size_t)node * LD2;
    const unsigned short* ew = Pcat + (size_t)node * LD1 + 400;
    float mk = mask[node];
    uint32_t t0 = *(const uint32_t*)(qt + 2 * q0);
    uint32_t e0 = *(const uint32_t*)(ew + 2 * q0);
    float val00 = bflo(e0) + mk * ((c00 + rs * bflo(t0)) / d);
    float val01 = bfhi(e0) + mk * ((c01 + rs * bfhi(t0)) / d);
    float val10 = 0.f, val11 = 0.f;
    if (v) {
        uint32_t t1 = *(const uint32_t*)(qt + 2 * q1);
        uint32_t e1 = *(const uint32_t*)(ew + 2 * q1);
        val10 = bflo(e1) + mk * ((c10 + rs * bflo(t1)) / d);
        val11 = bfhi(e1) + mk * ((c11 + rs * bfhi(t1)) / d);
    }
    float ss = val00 * val00 + val01 * val01 + val10 * val10 + val11 * val11;
#pragma unroll
    for (int o = 32; o > 0; o >>= 1) ss += __shfl_down(ss, o);
    ss = __shfl(ss, 0);
    float inv = 1.f / fmaxf(sqrtf(ss), 1e-12f);
    float* dst = out + (size_t)node * 200;
    *(float2*)(dst + 2 * q0) = make_float2(val00 * inv, val01 * inv);
    if (v) *(float2*)(dst + 2 * q1) = make_float2(val10 * inv, val11 * inv);
}

// ---------------- mask scatter ----------------
__global__ void k_mask(const int* __restrict__ batch, float* __restrict__ mask) {
    int i = blockIdx.x * blockDim.x + threadIdx.x;
    if (i < NB) mask[batch[(size_t)i * 3 + 2]] = 1.0f;
}

// ---------------- ortho losses ----------------
__global__ void k_ortho_part(const float* __restrict__ att_a, const float* __restrict__ out_a,
                             float* __restrict__ accum) {
    float loc[9] = {0,0,0,0,0,0,0,0,0};
    int stride = gridDim.x * blockDim.x;
    for (int i = blockIdx.x * blockDim.x + threadIdx.x; i < 90000; i += stride) {
        int seg, li;
        const float* base;
        int L;
        if (i < 15000)      { seg = 0; li = i;          base = att_a;         L = 15000; }
        else if (i < 30000) { seg = 1; li = i - 15000;  base = att_a + 30000; L = 15000; }
        else                { seg = 2; li = i - 30000;  base = out_a;         L = 60000; }
        float a = base[li], b = base[L + li];
        loc[seg * 3 + 0] += a * a;
        loc[seg * 3 + 1] += b * b;
        loc[seg * 3 + 2] += a * b;
    }
    int lane = threadIdx.x & 63;
#pragma unroll
    for (int q = 0; q < 9; q++) {
        float s = loc[q];
#pragma unroll
        for (int o = 32; o > 0; o >>= 1) s += __shfl_down(s, o);
        if (lane == 0 && s != 0.f) atomicAdd(&accum[q], s);
    }
}

__global__ void k_ortho_fin(const float* __restrict__ accum, float* __restrict__ out_scalar) {
    if (threadIdx.x != 0 || blockIdx.x != 0) return;
    float total = 0.f;
#pragma unroll
    for (int m = 0; m < 3; m++) {
        float s0 = accum[m * 3 + 0], s1 = accum[m * 3 + 1], sc = accum[m * 3 + 2];
        float c = sc / (fmaxf(sqrtf(s0), 1e-12f) * fmaxf(sqrtf(s1), 1e-12f));
        total += 0.01f * 2.f * c * c;
    }
    out_scalar[0] = total;
}

// ---------------- launch ----------------
extern "C" void kernel_launch(void* const* d_in, const int* in_sizes, int n_in,
                              void* d_out, int out_size, void* d_ws, size_t ws_size,
                              hipStream_t stream) {
    const int* edge_list = (const int*)d_in[0];
    const int* edge_type = (const int*)d_in[1];
    const int* batch     = (const int*)d_in[2];
    const int* nhop      = (const int*)d_in[3];
    const float* ent_emb = (const float*)d_in[4];
    const float* rel_emb = (const float*)d_in[5];
    const float* W_ent   = (const float*)d_in[6];
    const float* W_rel   = (const float*)d_in[7];
    const float* att_a   = (const float*)d_in[8];
    const float* att_a2  = (const float*)d_in[9];
    const float* out_a   = (const float*)d_in[10];
    const float* out_a2  = (const float*)d_in[11];
    float* out = (float*)d_out;
    const int* tgt_el = edge_list;
    const int* src_el = edge_list + E0;

    char* ws = (char*)d_ws;
    size_t o = 0;
    auto alloc = [&](size_t nbytes) -> char* {
        char* p = ws + o;
        o += (nbytes + 255) & ~(size_t)255;
        return p;
    };
    unsigned short* ent_bf  = (unsigned short*)alloc((size_t)N_NODES * KP1 * 2);
    unsigned short* x_bf    = (unsigned short*)alloc((size_t)N_NODES * KP2 * 2);
    unsigned short* Pcat    = (unsigned short*)alloc((size_t)N_NODES * LD1 * 2);
    unsigned short* Qcat    = (unsigned short*)alloc((size_t)N_NODES * LD2 * 2);
    unsigned short* Wcat1   = (unsigned short*)alloc((size_t)NPAD1 * KP1 * 2);
    unsigned short* Wcat2   = (unsigned short*)alloc((size_t)NPAD2 * KP2 * 2);
    float* uvecs = (float*)alloc(800 * 4);
    float* R1i   = (float*)alloc(474u * 200 * 4);
    float* R2    = (float*)alloc(474u * 200 * 4);
    float* dR10  = (float*)alloc(474u * 4);
    float* dR11  = (float*)alloc(474u * 4);
    float* dR2   = (float*)alloc(474u * 4);
    float2* wpair = (float2*)alloc((size_t)NE * 8);
    float* w2    = (float*)alloc((size_t)NE * 4);
    int* rowptr  = (int*)alloc((N_NODES + 1) * 4);
    int* cursor  = (int*)alloc(N_NODES * 4);
    int* tgts    = (int*)alloc((size_t)NE * 4);
    int* srcs    = (int*)alloc((size_t)NE * 4);
    int2* relpk  = (int2*)alloc((size_t)NE * 8);
    float* mask  = (float*)alloc(N_NODES * 4);
    int* scanloc = (int*)alloc(N_NODES * 4);
    int* bsums   = (int*)alloc(260 * 4);
    float* oacc  = (float*)alloc(9 * 4);

    const int TPB = 256;
    int wave_blocks_40000 = (N_NODES * 64 + TPB - 1) / TPB;   // 10000
    int wave_blocks_474   = (N_RELS * 64 + TPB - 1) / TPB;    // 119
    int edge_blocks       = (NE + TPB - 1) / TPB;
    int scan_blocks       = (N_NODES + 255) / 256;            // 157

    hipMemsetAsync(cursor, 0, N_NODES * 4, stream);
    hipMemsetAsync(mask, 0, N_NODES * 4, stream);
    hipMemsetAsync(oacc, 0, 9 * 4, stream);

    // 1) normalize entities -> bf16 padded
    k_l2norm_bf16<<<wave_blocks_40000, TPB, 0, stream>>>(ent_emb, ent_bf);

    // 2) CSR by target, payloads in CSR order
    k_hist<<<edge_blocks, TPB, 0, stream>>>(tgt_el, nhop, cursor);
    k_scan1<<<scan_blocks, 256, 0, stream>>>(cursor, scanloc, bsums, N_NODES);
    k_scan2<<<1, 256, 0, stream>>>(bsums, scan_blocks);
    k_scan3<<<(N_NODES + 1 + 255) / 256, 256, 0, stream>>>(scanloc, bsums, rowptr, cursor, N_NODES, scan_blocks);
    k_scatter<<<edge_blocks, TPB, 0, stream>>>(tgt_el, src_el, edge_type, nhop, cursor,
                                               tgts, srcs, relpk);

    // 3) pack fused B matrices (fragment order)
    k_uvec<<<4, 256, 0, stream>>>(att_a, att_a2, out_a, out_a2, uvecs);
    k_pack1<<<(NPAD1 * KP1 + 255) / 256, 256, 0, stream>>>(att_a, W_ent, uvecs, Wcat1);
    k_pack2<<<(NPAD2 * KP2 + 255) / 256, 256, 0, stream>>>(out_a, uvecs, Wcat2);

    // 4) fused layer-1 GEMM
    k_gemm_mfma<KP1><<<dim3(625, 2), 256, 0, stream>>>(ent_bf, Wcat1, Pcat, LD1, 608, 5);

    // 5) relation-side projections + dots
    k_relproj1<<<wave_blocks_474, TPB, 0, stream>>>(rel_emb, att_a, R1i);
    k_dR1<<<wave_blocks_474, TPB, 0, stream>>>(R1i, att_a2, dR10, dR11);

    // 6) layer-1 edge weights + aggregation -> x_bf
    k_edge1<<<edge_blocks, TPB, 0, stream>>>(tgts, srcs, relpk, Pcat, dR10, dR11, wpair);
    k_node1<<<wave_blocks_40000, TPB, 0, stream>>>(rowptr, srcs, relpk, wpair, Pcat, R1i, x_bf);

    // 7) fused layer-2 GEMM
    k_gemm_mfma<KP2><<<dim3(625, 2), 256, 0, stream>>>(x_bf, Wcat2, Qcat, LD2, 416, 4);

    // 8) out_relation_1; R2; dR2
    dim3 gor((200 + 63) / 64, (N_RELS + 63) / 64);
    k_mm<false><<<gor, TPB, 0, stream>>>(rel_emb, 100, W_rel, 200, out + 8000000, 200, N_RELS, 200, 100);
    k_mm<true><<<gor, TPB, 0, stream>>>(out + 8000000, 200, out_a + 400, 600, R2, 200, N_RELS, 200, 200);
    k_dotv<<<wave_blocks_474, TPB, 0, stream>>>(R2, out_a2, dR2, N_RELS, 200);

    // 9) layer-2 edge weights, mask, aggregation + final fuse
    k_edge2<<<edge_blocks, TPB, 0, stream>>>(tgts, srcs, relpk, Qcat, dR2, w2);
    k_mask<<<(NB + TPB - 1) / TPB, TPB, 0, stream>>>(batch, mask);
    k_node2<<<wave_blocks_40000, TPB, 0, stream>>>(rowptr, srcs, relpk, w2, Qcat, Pcat, R2, mask, out);

    // 10) ortho scalar
    k_ortho_part<<<128, 256, 0, stream>>>(att_a, out_a, oacc);
    k_ortho_fin<<<1, 64, 0, stream>>>(oacc, out + 8094800);
}